// Round 8
// baseline (201.216 us; speedup 1.0000x reference)
//
#include <hip/hip_runtime.h>

#define BB 48
#define NN 256
#define EE 1024
#define DD 256
#define CIN 256

typedef __attribute__((ext_vector_type(4))) float f32x4;
typedef __attribute__((ext_vector_type(8))) _Float16 f16x8;
typedef __attribute__((ext_vector_type(4))) _Float16 f16x4;

__device__ __forceinline__ float lrelu(float t) { return t >= 0.0f ? t : 0.2f * t; }

__device__ __forceinline__ void gload16(const void* g, void* l) {
  __builtin_amdgcn_global_load_lds((const __attribute__((address_space(1))) void*)g,
                                   (__attribute__((address_space(3))) void*)l, 16, 0, 0);
}

// incT[e,n] = inc[n,e]  (fp16, exact 0/1)
__global__ __launch_bounds__(256) void k_incT(const float* __restrict__ inc, _Float16* __restrict__ incT) {
  __shared__ float tile[64][65];
  int e0 = blockIdx.x * 64, n0 = blockIdx.y * 64;
  int t = threadIdx.x, c = t & 63, r = t >> 6;
#pragma unroll
  for (int i = 0; i < 16; ++i) tile[r + i * 4][c] = inc[(size_t)(n0 + r + i * 4) * EE + e0 + c];
  __syncthreads();
#pragma unroll
  for (int i = 0; i < 16; ++i) {
    int row = r + i * 4;
    incT[(size_t)(e0 + row) * NN + n0 + c] = (_Float16)tile[c][row];
  }
}

// w2t[e,f] = fp16(W2[f,e])
__global__ __launch_bounds__(256) void k_w2t(const float* __restrict__ W2, _Float16* __restrict__ hi) {
  __shared__ float tile[64][65];
  int f0 = blockIdx.x * 64, e0 = blockIdx.y * 64;
  int t = threadIdx.x, c = t & 63, r = t >> 6;
#pragma unroll
  for (int i = 0; i < 16; ++i) tile[r + i * 4][c] = W2[(size_t)(f0 + r + i * 4) * EE + e0 + c];
  __syncthreads();
#pragma unroll
  for (int i = 0; i < 16; ++i) {
    int row = r + i * 4;
    hi[(size_t)(e0 + row) * EE + f0 + c] = (_Float16)tile[c][row];
  }
}

// wt16[d,c] = fp16(W[c,d])
__global__ __launch_bounds__(256) void k_wt16(const float* __restrict__ W, _Float16* __restrict__ wt) {
  __shared__ float tile[64][65];
  int c0 = blockIdx.x * 64, d0 = blockIdx.y * 64;
  int t = threadIdx.x, c = t & 63, r = t >> 6;
#pragma unroll
  for (int i = 0; i < 16; ++i) tile[r + i * 4][c] = W[(size_t)(c0 + r + i * 4) * DD + d0 + c];
  __syncthreads();
#pragma unroll
  for (int i = 0; i < 16; ++i) {
    int row = r + i * 4;
    wt[(size_t)(d0 + row) * CIN + c0 + c] = (_Float16)tile[c][row];
  }
}

// xt16[b,n,c] = fp16(x_in[b,c,n])
__global__ __launch_bounds__(256) void k_xt(const float* __restrict__ x, const float* __restrict__ m,
                                            const float* __restrict__ hid, _Float16* __restrict__ xt) {
  __shared__ float tile[64][65];
  int c0 = blockIdx.x * 64, n0 = blockIdx.y * 64, b = blockIdx.z;
  int t = threadIdx.x, c = t & 63, r = t >> 6;
#pragma unroll
  for (int i = 0; i < 16; ++i) {
    int ch = c0 + r + i * 4;
    const float* row;
    if (ch < 96) row = x + ((size_t)b * 96 + ch) * NN;
    else if (ch < 192) row = m + ((size_t)b * 96 + (ch - 96)) * NN;
    else row = hid + ((size_t)b * 64 + (ch - 192)) * NN;
    tile[r + i * 4][c] = row[n0 + c];
  }
  __syncthreads();
#pragma unroll
  for (int i = 0; i < 16; ++i) {
    int row = r + i * 4;
    xt[((size_t)b * NN + n0 + row) * CIN + c0 + c] = (_Float16)tile[c][row];
  }
}

// wa[c]=sum_d W[c,d]*a[d]; wa[256+c]=..a[D+d]; wa[512+c]=..a2[d]; wa[768..770]=sum(a[:D]),sum(a[D:]),sum(a2[:D])
__global__ __launch_bounds__(256) void k_wa(const float* __restrict__ W, const float* __restrict__ a,
                                            const float* __restrict__ a2, float* __restrict__ wa) {
  __shared__ float red[3][4];
  int c = blockIdx.x, t = threadIdx.x;
  int l = t & 63, wv = t >> 6;
  float w = W[(size_t)c * DD + t];
  float p0 = w * a[t], p1 = w * a[DD + t], p2 = w * a2[t];
#pragma unroll
  for (int off = 32; off > 0; off >>= 1) {
    p0 += __shfl_down(p0, off);
    p1 += __shfl_down(p1, off);
    p2 += __shfl_down(p2, off);
  }
  if (l == 0) {
    red[0][wv] = p0;
    red[1][wv] = p1;
    red[2][wv] = p2;
  }
  __syncthreads();
  if (t == 0) wa[c] = red[0][0] + red[0][1] + red[0][2] + red[0][3];
  if (t == 1) wa[256 + c] = red[1][0] + red[1][1] + red[1][2] + red[1][3];
  if (t == 2) wa[512 + c] = red[2][0] + red[2][1] + red[2][2] + red[2][3];
  if (blockIdx.x == 0) {
    __syncthreads();
    float q0 = a[t], q1 = a[DD + t], q2 = a2[t];
#pragma unroll
    for (int off = 32; off > 0; off >>= 1) {
      q0 += __shfl_down(q0, off);
      q1 += __shfl_down(q1, off);
      q2 += __shfl_down(q2, off);
    }
    if (l == 0) {
      red[0][wv] = q0;
      red[1][wv] = q1;
      red[2][wv] = q2;
    }
    __syncthreads();
    if (t == 0) wa[768] = red[0][0] + red[0][1] + red[0][2] + red[0][3];
    if (t == 1) wa[769] = red[1][0] + red[1][1] + red[1][2] + red[1][3];
    if (t == 2) wa[770] = red[2][0] + red[2][1] + red[2][2] + red[2][3];
  }
}

// node_sc/g1/g2[b,n] directly from x_in (exact fp32); one block per b, thread t = n
__global__ __launch_bounds__(256) void k_ns2(const float* __restrict__ x, const float* __restrict__ m,
                                             const float* __restrict__ hid, const float* __restrict__ wa,
                                             const float* __restrict__ bias, float* __restrict__ node_sc,
                                             float* __restrict__ g1, float* __restrict__ g2) {
  __shared__ float s0a[256], s1a[256], s2a[256];
  int b = blockIdx.x, t = threadIdx.x;
  s0a[t] = wa[t];
  s1a[t] = wa[256 + t];
  s2a[t] = wa[512 + t];
  __syncthreads();
  float s0 = 0.f, s1 = 0.f, s2 = 0.f;
#pragma unroll 4
  for (int c = 0; c < 256; ++c) {
    const float* row;
    if (c < 96) row = x + ((size_t)b * 96 + c) * NN;
    else if (c < 192) row = m + ((size_t)b * 96 + (c - 96)) * NN;
    else row = hid + ((size_t)b * 64 + (c - 192)) * NN;
    float v = row[t];
    s0 += v * s0a[c];
    s1 += v * s1a[c];
    s2 += v * s2a[c];
  }
  float bv = bias[t];
  int idx = b * NN + t;
  node_sc[idx] = s0 + bv * wa[768];
  g1[idx] = s1 + bv * wa[769];
  g2[idx] = s2 + bv * wa[770];
}

// hThi[b,d,n] = fp16(sum_c xt16[b,n,c]*wt16[d,c] + bias[n]); fp16 MFMA 64x64, 2-phase dbuf
__global__ __launch_bounds__(256) void k_h16(const _Float16* __restrict__ xt, const _Float16* __restrict__ wt,
                                             const float* __restrict__ bias, _Float16* __restrict__ hThi) {
  __shared__ _Float16 smA[2][64 * 64];
  __shared__ _Float16 smB[2][64 * 64];
  int bid = blockIdx.x;
  int xcd = bid & 7, il = bid >> 3;  // 96 per XCD
  int ntile = il & 3, dtile = (il >> 2) & 3, bl = il >> 4;
  int b = xcd * 6 + bl;
  int n0 = ntile * 64, d0 = dtile * 64;
  int t = threadIdx.x, w = t >> 6, l = t & 63;
  int wm = w >> 1, wn = w & 1;
  int lr = l & 15;
  const _Float16* A = xt + ((size_t)b * NN + n0) * CIN;
  const _Float16* Bp = wt + (size_t)d0 * CIN;
  int lrow = l >> 3;
  int scol = 8 * ((l & 7) ^ (lrow & 7));
  auto stage = [&](int buf, int kk) {
#pragma unroll
    for (int q = 0; q < 2; ++q) {
      int row = q * 32 + w * 8 + lrow;
      int lb = (q * 32 + w * 8) * 64;
      gload16(A + (size_t)row * CIN + kk + scol, &smA[buf][lb]);
      gload16(Bp + (size_t)row * CIN + kk + scol, &smB[buf][lb]);
    }
  };
  f32x4 acc[2][2];
  f32x4 z = {0.f, 0.f, 0.f, 0.f};
#pragma unroll
  for (int i = 0; i < 2; ++i)
#pragma unroll
    for (int j = 0; j < 2; ++j) acc[i][j] = z;
  stage(0, 0);
  asm volatile("s_waitcnt vmcnt(0)" ::: "memory");
  __builtin_amdgcn_s_barrier();
  int cur = 0;
  for (int kk = 0; kk < CIN; kk += 64) {
    if (kk + 64 < CIN) stage(cur ^ 1, kk + 64);
    f16x8 af[2][2], bf[2][2];
#pragma unroll
    for (int i = 0; i < 2; ++i)
#pragma unroll
      for (int ks = 0; ks < 2; ++ks) {
        int ra = wm * 32 + i * 16 + lr;
        af[i][ks] = *(const f16x8*)&smA[cur][ra * 64 + ((ks * 32 + (l >> 4) * 8) ^ ((ra & 7) << 3))];
        int rb = wn * 32 + i * 16 + lr;
        bf[i][ks] = *(const f16x8*)&smB[cur][rb * 64 + ((ks * 32 + (l >> 4) * 8) ^ ((rb & 7) << 3))];
      }
#pragma unroll
    for (int ks = 0; ks < 2; ++ks)
#pragma unroll
      for (int i = 0; i < 2; ++i)
#pragma unroll
        for (int j = 0; j < 2; ++j)
          acc[i][j] = __builtin_amdgcn_mfma_f32_16x16x32_f16(af[i][ks], bf[j][ks], acc[i][j], 0, 0, 0);
    asm volatile("s_waitcnt vmcnt(0)" ::: "memory");
    __builtin_amdgcn_s_barrier();
    cur ^= 1;
  }
#pragma unroll
  for (int i = 0; i < 2; ++i)
#pragma unroll
    for (int j = 0; j < 2; ++j) {
      int nb = n0 + wm * 32 + i * 16 + (l >> 4) * 4;
      int d = d0 + wn * 32 + j * 16 + lr;
      float4 bv = *(const float4*)&bias[nb];
      f16x4 vh;
      vh[0] = (_Float16)(acc[i][j][0] + bv.x);
      vh[1] = (_Float16)(acc[i][j][1] + bv.y);
      vh[2] = (_Float16)(acc[i][j][2] + bv.z);
      vh[3] = (_Float16)(acc[i][j][3] + bv.w);
      *(f16x4*)&hThi[((size_t)b * DD + d) * NN + nb] = vh;
    }
}

// u1[b,f] = invdeg[f]*sum_n incT[f,n]*g1[b,n]; u2 same with g2; deg computed inline (b==0 writes invdeg)
__global__ __launch_bounds__(256) void k_uu(const _Float16* __restrict__ incT, const float* __restrict__ g1,
                                            const float* __restrict__ g2, float* __restrict__ invdeg,
                                            float* __restrict__ u1, float* __restrict__ u2) {
  __shared__ float sg1[NN], sg2[NN];
  __shared__ float r0[4][64], r1[4][64], r2[4][64];
  int b = blockIdx.y;
  int f0 = blockIdx.x * 64;
  int t = threadIdx.x;
  sg1[t] = g1[b * NN + t];
  sg2[t] = g2[b * NN + t];
  __syncthreads();
  int fl = t & 63, ng = t >> 6;
  int f = f0 + fl;
  float s0 = 0.f, s1 = 0.f, s2 = 0.f;
  const _Float16* row = incT + (size_t)f * NN + ng * 64;
  for (int i = 0; i < 64; i += 8) {
    f16x8 ic = *(const f16x8*)&row[i];
#pragma unroll
    for (int j = 0; j < 8; ++j) {
      float icf = (float)ic[j];
      int n = ng * 64 + i + j;
      s0 += icf;
      s1 += icf * sg1[n];
      s2 += icf * sg2[n];
    }
  }
  r0[ng][fl] = s0;
  r1[ng][fl] = s1;
  r2[ng][fl] = s2;
  __syncthreads();
  if (t < 64) {
    float dg = r0[0][t] + r0[1][t] + r0[2][t] + r0[3][t];
    float iv = 1.0f / dg;
    if (b == 0) invdeg[f0 + t] = iv;
    u1[(size_t)b * EE + f0 + t] = (r1[0][t] + r1[1][t] + r1[2][t] + r1[3][t]) * iv;
    u2[(size_t)b * EE + f0 + t] = (r2[0][t] + r2[1][t] + r2[2][t] + r2[3][t]) * iv;
  }
}

// edge_sc[b,e] = sum_f W2[f,e]*u1[b,f];  time_e = lrelu(... + pri_e*a2[D]); 6 b per block
__global__ __launch_bounds__(256) void k_esc(const float* __restrict__ W2, const float* __restrict__ u1,
                                             const float* __restrict__ u2, const float* __restrict__ pri_e,
                                             const float* __restrict__ a2, float* __restrict__ edge_sc,
                                             float* __restrict__ time_e) {
  __shared__ float su1[6 * 1024];
  __shared__ float su2[6 * 1024];
  __shared__ float rr[2][4][6][64];
  int e0 = blockIdx.x * 64, b0 = blockIdx.y * 6;
  int t = threadIdx.x;
#pragma unroll
  for (int i = 0; i < 6; ++i) {
    *(float4*)&su1[i * 1024 + t * 4] = *(const float4*)&u1[(size_t)(b0 + i) * EE + t * 4];
    *(float4*)&su2[i * 1024 + t * 4] = *(const float4*)&u2[(size_t)(b0 + i) * EE + t * 4];
  }
  __syncthreads();
  int el = t & 63, fg = t >> 6;
  int e = e0 + el;
  float s1[6] = {}, s2[6] = {};
  for (int i = 0; i < 256; i += 4) {
    int f = fg * 256 + i;
    float w0 = W2[(size_t)f * EE + e];
    float w1 = W2[(size_t)(f + 1) * EE + e];
    float w2v = W2[(size_t)(f + 2) * EE + e];
    float w3 = W2[(size_t)(f + 3) * EE + e];
#pragma unroll
    for (int bl = 0; bl < 6; ++bl) {
      f32x4 va = *(const f32x4*)&su1[bl * 1024 + f];
      f32x4 vb = *(const f32x4*)&su2[bl * 1024 + f];
      s1[bl] += w0 * va[0] + w1 * va[1] + w2v * va[2] + w3 * va[3];
      s2[bl] += w0 * vb[0] + w1 * vb[1] + w2v * vb[2] + w3 * vb[3];
    }
  }
#pragma unroll
  for (int bl = 0; bl < 6; ++bl) {
    rr[0][fg][bl][el] = s1[bl];
    rr[1][fg][bl][el] = s2[bl];
  }
  __syncthreads();
  for (int bl = t >> 6; bl < 6; bl += 4) {
    int ee = t & 63;
    int row = (b0 + bl) * EE + e0 + ee;
    float v1 = rr[0][0][bl][ee] + rr[0][1][bl][ee] + rr[0][2][bl][ee] + rr[0][3][bl][ee];
    float v2 = rr[1][0][bl][ee] + rr[1][1][bl][ee] + rr[1][2][bl][ee] + rr[1][3][bl][ee];
    edge_sc[row] = v1;
    time_e[row] = lrelu(v2 + pri_e[row] * a2[DD]);
  }
}

// softmax stats over n per (b,e)
__global__ __launch_bounds__(256) void k_d3(const _Float16* __restrict__ incT, const float* __restrict__ node_sc,
                                            const float* __restrict__ edge_sc, const float* __restrict__ time_e,
                                            const float* __restrict__ a3, float* __restrict__ rmax,
                                            float* __restrict__ rinv) {
  int t = threadIdx.x;
  int w = t >> 6, l = t & 63;
  int row = blockIdx.x * 4 + w;
  int b = row >> 10;
  int e = row & (EE - 1);
  float a30 = a3[0], a31 = a3[1];
  float esc = edge_sc[row], te = time_e[row];
  float s2v[4];
  bool msk[4];
  float vmax = -3.0e38f;
#pragma unroll
  for (int q = 0; q < 4; ++q) {
    int n = l + q * 64;
    float ic = (float)incT[(size_t)e * NN + n];
    float s1 = lrelu(node_sc[(size_t)b * NN + n] + esc);
    float s2 = lrelu(te * a30 + s1 * a31);
    msk[q] = ic > 0.f;
    s2v[q] = s2;
    if (msk[q]) vmax = fmaxf(vmax, s2);
  }
#pragma unroll
  for (int off = 32; off > 0; off >>= 1) vmax = fmaxf(vmax, __shfl_xor(vmax, off));
  float ss = 0.f;
#pragma unroll
  for (int q = 0; q < 4; ++q)
    if (msk[q]) ss += __expf(s2v[q] - vmax);
#pragma unroll
  for (int off = 32; off > 0; off >>= 1) ss += __shfl_xor(ss, off);
  if (l == 0) {
    rmax[row] = vmax;
    rinv[row] = 1.0f / ss;
  }
}

// e1[b,d,e] = (sum_n hT[d,n]*incT[e,n]) * invdeg[e]; 128e x 64d, BK=64, 2-phase dbuf; b-pinned XCD
__global__ __launch_bounds__(256) void k_edge1(const _Float16* __restrict__ incT, const _Float16* __restrict__ hThi,
                                               const float* __restrict__ invdeg, _Float16* __restrict__ e1) {
  __shared__ _Float16 smA[2][128 * 64];
  __shared__ _Float16 smB[2][64 * 64];
  int bid = blockIdx.x;
  int xcd = bid & 7, il = bid >> 3;  // 192 per XCD
  int ep = il & 7, dblk = (il >> 3) & 3, bl = il >> 5;
  int b = xcd * 6 + bl;
  int m0 = ep * 128;   // e
  int n0 = dblk * 64;  // d
  int t = threadIdx.x, w = t >> 6, l = t & 63;
  int wm = w >> 1, wn = w & 1;
  int lr = l & 15, lg = l >> 4;
  int srow = l >> 3, sgrp = l & 7;
  int sc = (sgrp ^ srow) * 8;
  const _Float16* A = incT + (size_t)m0 * NN;
  const _Float16* Bp = hThi + ((size_t)b * DD + n0) * NN;
  auto stage = [&](int buf, int kk) {
#pragma unroll
    for (int q = 0; q < 4; ++q) {
      int c = w * 4 + q;
      int r = c * 8 + srow;
      gload16(A + (size_t)r * NN + kk + sc, &smA[buf][c * 512]);
    }
#pragma unroll
    for (int q = 0; q < 2; ++q) {
      int c = w * 2 + q;
      int r = c * 8 + srow;
      gload16(Bp + (size_t)r * NN + kk + sc, &smB[buf][c * 512]);
    }
  };
  f32x4 acc[4][2];
  f32x4 z = {0.f, 0.f, 0.f, 0.f};
#pragma unroll
  for (int i = 0; i < 4; ++i)
#pragma unroll
    for (int j = 0; j < 2; ++j) acc[i][j] = z;
  stage(0, 0);
  asm volatile("s_waitcnt vmcnt(0)" ::: "memory");
  __builtin_amdgcn_s_barrier();
  int cur = 0;
  for (int kk = 0; kk < NN; kk += 64) {
    if (kk + 64 < NN) stage(cur ^ 1, kk + 64);
    f16x8 ah[4][2], bh[2][2];
#pragma unroll
    for (int i = 0; i < 4; ++i) {
      int ra = wm * 64 + i * 16 + lr;
#pragma unroll
      for (int ks = 0; ks < 2; ++ks)
        ah[i][ks] = *(const f16x8*)&smA[cur][ra * 64 + (((ks * 4 + lg) ^ (ra & 7)) * 8)];
    }
#pragma unroll
    for (int j = 0; j < 2; ++j) {
      int rb = wn * 32 + j * 16 + lr;
#pragma unroll
      for (int ks = 0; ks < 2; ++ks)
        bh[j][ks] = *(const f16x8*)&smB[cur][rb * 64 + (((ks * 4 + lg) ^ (rb & 7)) * 8)];
    }
#pragma unroll
    for (int ks = 0; ks < 2; ++ks)
#pragma unroll
      for (int i = 0; i < 4; ++i)
#pragma unroll
        for (int j = 0; j < 2; ++j)
          acc[i][j] = __builtin_amdgcn_mfma_f32_16x16x32_f16(ah[i][ks], bh[j][ks], acc[i][j], 0, 0, 0);
    asm volatile("s_waitcnt vmcnt(0)" ::: "memory");
    __builtin_amdgcn_s_barrier();
    cur ^= 1;
  }
#pragma unroll
  for (int i = 0; i < 4; ++i)
#pragma unroll
    for (int j = 0; j < 2; ++j) {
      int e = m0 + wm * 64 + i * 16 + lg * 4;
      int d = n0 + wn * 32 + j * 16 + lr;
      f16x4 vh;
#pragma unroll
      for (int r = 0; r < 4; ++r) vh[r] = (_Float16)(acc[i][j][r] * invdeg[e + r]);
      *(f16x4*)&e1[((size_t)b * DD + d) * EE + e] = vh;
    }
}

// out1[b,e,d] = sum_f w2t[e,f]*e1[d,f]; 128e x 64d, BK=64, 2-phase dbuf; b-pinned XCD; emits out1T16
__global__ __launch_bounds__(256) void k_out1(const _Float16* __restrict__ w2t, const _Float16* __restrict__ e1,
                                              float* __restrict__ out1, _Float16* __restrict__ out1T) {
  __shared__ _Float16 smA[2][128 * 64];
  __shared__ _Float16 smB[2][64 * 64];
  int bid = blockIdx.x;
  int xcd = bid & 7, il = bid >> 3;  // 192 per XCD
  int ep = il & 7, dblk = (il >> 3) & 3, bl = il >> 5;
  int b = xcd * 6 + bl;
  int m0 = ep * 128;   // e
  int n0 = dblk * 64;  // d
  int t = threadIdx.x, w = t >> 6, l = t & 63;
  int wm = w >> 1, wn = w & 1;
  int lr = l & 15, lg = l >> 4;
  int srow = l >> 3, sgrp = l & 7;
  int sc = (sgrp ^ srow) * 8;
  const _Float16* A = w2t + (size_t)m0 * EE;
  const _Float16* Bp = e1 + ((size_t)b * DD + n0) * EE;
  auto stage = [&](int buf, int kk) {
#pragma unroll
    for (int q = 0; q < 4; ++q) {
      int c = w * 4 + q;
      int r = c * 8 + srow;
      gload16(A + (size_t)r * EE + kk + sc, &smA[buf][c * 512]);
    }
#pragma unroll
    for (int q = 0; q < 2; ++q) {
      int c = w * 2 + q;
      int r = c * 8 + srow;
      gload16(Bp + (size_t)r * EE + kk + sc, &smB[buf][c * 512]);
    }
  };
  f32x4 acc[4][2];
  f32x4 z = {0.f, 0.f, 0.f, 0.f};
#pragma unroll
  for (int i = 0; i < 4; ++i)
#pragma unroll
    for (int j = 0; j < 2; ++j) acc[i][j] = z;
  stage(0, 0);
  asm volatile("s_waitcnt vmcnt(0)" ::: "memory");
  __builtin_amdgcn_s_barrier();
  int cur = 0;
  for (int kk = 0; kk < EE; kk += 64) {
    if (kk + 64 < EE) stage(cur ^ 1, kk + 64);
    f16x8 ah[4][2], bh[2][2];
#pragma unroll
    for (int i = 0; i < 4; ++i) {
      int ra = wm * 64 + i * 16 + lr;
#pragma unroll
      for (int ks = 0; ks < 2; ++ks)
        ah[i][ks] = *(const f16x8*)&smA[cur][ra * 64 + (((ks * 4 + lg) ^ (ra & 7)) * 8)];
    }
#pragma unroll
    for (int j = 0; j < 2; ++j) {
      int rb = wn * 32 + j * 16 + lr;
#pragma unroll
      for (int ks = 0; ks < 2; ++ks)
        bh[j][ks] = *(const f16x8*)&smB[cur][rb * 64 + (((ks * 4 + lg) ^ (rb & 7)) * 8)];
    }
#pragma unroll
    for (int ks = 0; ks < 2; ++ks)
#pragma unroll
      for (int i = 0; i < 4; ++i)
#pragma unroll
        for (int j = 0; j < 2; ++j)
          acc[i][j] = __builtin_amdgcn_mfma_f32_16x16x32_f16(ah[i][ks], bh[j][ks], acc[i][j], 0, 0, 0);
    asm volatile("s_waitcnt vmcnt(0)" ::: "memory");
    __builtin_amdgcn_s_barrier();
    cur ^= 1;
  }
#pragma unroll
  for (int i = 0; i < 4; ++i)
#pragma unroll
    for (int j = 0; j < 2; ++j) {
      int e = m0 + wm * 64 + i * 16 + lg * 4;
      int d = n0 + wn * 32 + j * 16 + lr;
      f16x4 v16;
#pragma unroll
      for (int r = 0; r < 4; ++r) {
        out1[((size_t)b * EE + e + r) * DD + d] = acc[i][j][r];
        v16[r] = (_Float16)acc[i][j][r];
      }
      *(f16x4*)&out1T[((size_t)b * DD + d) * EE + e] = v16;
    }
}

// att16[b,n,e] = softmax coefficient (fp16)
__global__ __launch_bounds__(256) void k_att(const float* __restrict__ inc, const float* __restrict__ node_sc,
                                             const float* __restrict__ edge_sc, const float* __restrict__ time_e,
                                             const float* __restrict__ rmax, const float* __restrict__ rinv,
                                             const float* __restrict__ a3, _Float16* __restrict__ att16) {
  int n = blockIdx.x, b = blockIdx.y;
  int e = threadIdx.x * 4;
  float a30 = a3[0], a31 = a3[1];
  float ns = node_sc[b * NN + n];
  float4 icv = *(const float4*)&inc[(size_t)n * EE + e];
  int be = b * EE + e;
  float4 esc = *(const float4*)&edge_sc[be];
  float4 te = *(const float4*)&time_e[be];
  float4 rm = *(const float4*)&rmax[be];
  float4 ri = *(const float4*)&rinv[be];
  float ica[4] = {icv.x, icv.y, icv.z, icv.w};
  float ea[4] = {esc.x, esc.y, esc.z, esc.w};
  float ta[4] = {te.x, te.y, te.z, te.w};
  float ma[4] = {rm.x, rm.y, rm.z, rm.w};
  float ra[4] = {ri.x, ri.y, ri.z, ri.w};
  f16x4 o;
#pragma unroll
  for (int q = 0; q < 4; ++q) {
    float att = 0.f;
    if (ica[q] > 0.f) {
      float s1 = lrelu(ns + ea[q]);
      float s2 = lrelu(ta[q] * a30 + s1 * a31);
      att = __expf(s2 - ma[q]) * ra[q];
    }
    o[q] = (_Float16)att;
  }
  *(f16x4*)&att16[((size_t)b * NN + n) * EE + e] = o;
}

// out0[b,d,n] = sum_e att16[n,e]*out1T16[d,e]; 64x64, BK=64, 2-phase dbuf; b-pinned XCD
__global__ __launch_bounds__(256) void k_fgemm(const _Float16* __restrict__ att16, const _Float16* __restrict__ out1T,
                                               float* __restrict__ out0) {
  __shared__ _Float16 smA[2][64 * 64];
  __shared__ _Float16 smB[2][64 * 64];
  int bid = blockIdx.x;
  int xcd = bid & 7, il = bid >> 3;  // 96 per XCD
  int ntile = il & 3, dtile = (il >> 2) & 3, bl = il >> 4;
  int b = xcd * 6 + bl;
  int n0 = ntile * 64, d0 = dtile * 64;
  int t = threadIdx.x, w = t >> 6, l = t & 63;
  int wm = w >> 1, wn = w & 1;
  int lr = l & 15;
  const _Float16* A = att16 + ((size_t)b * NN + n0) * EE;
  const _Float16* Bp = out1T + ((size_t)b * DD + d0) * EE;
  int lrow = l >> 3;
  int scol = 8 * ((l & 7) ^ (lrow & 7));
  auto stage = [&](int buf, int kk) {
#pragma unroll
    for (int q = 0; q < 2; ++q) {
      int row = q * 32 + w * 8 + lrow;
      int lb = (q * 32 + w * 8) * 64;
      gload16(A + (size_t)row * EE + kk + scol, &smA[buf][lb]);
      gload16(Bp + (size_t)row * EE + kk + scol, &smB[buf][lb]);
    }
  };
  f32x4 acc[2][2];
  f32x4 z = {0.f, 0.f, 0.f, 0.f};
#pragma unroll
  for (int i = 0; i < 2; ++i)
#pragma unroll
    for (int j = 0; j < 2; ++j) acc[i][j] = z;
  stage(0, 0);
  asm volatile("s_waitcnt vmcnt(0)" ::: "memory");
  __builtin_amdgcn_s_barrier();
  int cur = 0;
  for (int kk = 0; kk < EE; kk += 64) {
    if (kk + 64 < EE) stage(cur ^ 1, kk + 64);
    f16x8 af[2][2], bf[2][2];
#pragma unroll
    for (int i = 0; i < 2; ++i)
#pragma unroll
      for (int ks = 0; ks < 2; ++ks) {
        int ra = wm * 32 + i * 16 + lr;
        af[i][ks] = *(const f16x8*)&smA[cur][ra * 64 + ((ks * 32 + (l >> 4) * 8) ^ ((ra & 7) << 3))];
        int rb = wn * 32 + i * 16 + lr;
        bf[i][ks] = *(const f16x8*)&smB[cur][rb * 64 + ((ks * 32 + (l >> 4) * 8) ^ ((rb & 7) << 3))];
      }
#pragma unroll
    for (int ks = 0; ks < 2; ++ks)
#pragma unroll
      for (int i = 0; i < 2; ++i)
#pragma unroll
        for (int j = 0; j < 2; ++j)
          acc[i][j] = __builtin_amdgcn_mfma_f32_16x16x32_f16(af[i][ks], bf[j][ks], acc[i][j], 0, 0, 0);
    asm volatile("s_waitcnt vmcnt(0)" ::: "memory");
    __builtin_amdgcn_s_barrier();
    cur ^= 1;
  }
  float* ob = out0 + (size_t)b * DD * NN;
#pragma unroll
  for (int i = 0; i < 2; ++i)
#pragma unroll
    for (int j = 0; j < 2; ++j) {
      int n = n0 + wm * 32 + i * 16 + (l >> 4) * 4;
      int d = d0 + wn * 32 + j * 16 + lr;
      *(float4*)&ob[(size_t)d * NN + n] =
          make_float4(acc[i][j][0], acc[i][j][1], acc[i][j][2], acc[i][j][3]);
    }
}

extern "C" void kernel_launch(void* const* d_in, const int* in_sizes, int n_in, void* d_out, int out_size,
                              void* d_ws, size_t ws_size, hipStream_t stream) {
  (void)in_sizes;
  (void)n_in;
  (void)out_size;
  (void)ws_size;
  const float* x = (const float*)d_in[0];
  const float* m = (const float*)d_in[1];
  const float* hid = (const float*)d_in[2];
  const float* pri_e = (const float*)d_in[3];
  const float* inc = (const float*)d_in[5];
  const float* W = (const float*)d_in[6];
  const float* bias = (const float*)d_in[7];
  const float* W2 = (const float*)d_in[8];
  const float* a = (const float*)d_in[9];
  const float* a2 = (const float*)d_in[10];
  const float* a3 = (const float*)d_in[11];

  float* out0 = (float*)d_out;                // [B,D,N]
  float* out1 = out0 + (size_t)BB * DD * NN;  // [B,E,D] fp32
  _Float16* hThi = (_Float16*)out1;           // [B,D,N] fp16 (dead before k_out1 writes out1)
  _Float16* xt16 = hThi + (size_t)BB * DD * NN;  // [B,N,CIN] fp16 (also inside out1 region)

  _Float16* e1 = (_Float16*)d_ws;  // [B,D,E] fp16; att16 aliases after k_out1
  _Float16* att16 = e1;
  _Float16* out1T16 = e1 + (size_t)BB * DD * EE;      // [B,D,E] fp16
  _Float16* incT = out1T16 + (size_t)BB * DD * EE;    // [E,N]
  _Float16* w2thi = incT + (size_t)EE * NN;           // [E,E]
  float* invdeg = (float*)(w2thi + (size_t)EE * EE);  // E
  float* node_sc = invdeg + EE;                       // B*N
  float* g1 = node_sc + (size_t)BB * NN;              // B*N
  float* g2 = g1 + (size_t)BB * NN;                   // B*N
  float* edge_sc = g2 + (size_t)BB * NN;              // B*E
  float* time_e = edge_sc + (size_t)BB * EE;          // B*E
  float* rmax = time_e + (size_t)BB * EE;             // B*E
  float* rinv = rmax + (size_t)BB * EE;               // B*E
  float* u1 = rinv + (size_t)BB * EE;                 // B*E
  float* u2 = u1 + (size_t)BB * EE;                   // B*E
  float* wa = u2 + (size_t)BB * EE;                   // 1024
  _Float16* wt16 = (_Float16*)(wa + 1024);            // [D,CIN]

  k_incT<<<dim3(EE / 64, NN / 64), 256, 0, stream>>>(inc, incT);
  k_w2t<<<dim3(EE / 64, EE / 64), 256, 0, stream>>>(W2, w2thi);
  k_wt16<<<dim3(CIN / 64, DD / 64), 256, 0, stream>>>(W, wt16);
  k_xt<<<dim3(CIN / 64, NN / 64, BB), 256, 0, stream>>>(x, m, hid, xt16);
  k_wa<<<dim3(CIN), 256, 0, stream>>>(W, a, a2, wa);
  k_h16<<<dim3(8 * 96), 256, 0, stream>>>(xt16, wt16, bias, hThi);
  k_ns2<<<dim3(BB), 256, 0, stream>>>(x, m, hid, wa, bias, node_sc, g1, g2);
  k_uu<<<dim3(EE / 64, BB), 256, 0, stream>>>(incT, g1, g2, invdeg, u1, u2);
  k_esc<<<dim3(EE / 64, BB / 6), 256, 0, stream>>>(W2, u1, u2, pri_e, a2, edge_sc, time_e);
  k_d3<<<dim3((BB * EE) / 4), 256, 0, stream>>>(incT, node_sc, edge_sc, time_e, a3, rmax, rinv);
  k_edge1<<<dim3(8 * 192), 256, 0, stream>>>(incT, hThi, invdeg, e1);
  k_out1<<<dim3(8 * 192), 256, 0, stream>>>(w2thi, e1, out1, out1T16);
  k_att<<<dim3(NN, BB), 256, 0, stream>>>(inc, node_sc, edge_sc, time_e, rmax, rinv, a3, att16);
  k_fgemm<<<dim3(8 * 96), 256, 0, stream>>>(att16, out1T16, out0);
}

// Round 9
// 172.399 us; speedup vs baseline: 1.1671x; 1.1671x over previous
//
#include <hip/hip_runtime.h>

#define BB 48
#define NN 256
#define EE 1024
#define DD 256
#define CIN 256

typedef __attribute__((ext_vector_type(4))) float f32x4;
typedef __attribute__((ext_vector_type(8))) _Float16 f16x8;
typedef __attribute__((ext_vector_type(4))) _Float16 f16x4;

__device__ __forceinline__ float lrelu(float t) { return t >= 0.0f ? t : 0.2f * t; }

__device__ __forceinline__ void gload16(const void* g, void* l) {
  __builtin_amdgcn_global_load_lds((const __attribute__((address_space(1))) void*)g,
                                   (__attribute__((address_space(3))) void*)l, 16, 0, 0);
}

// incT[e,n] = inc[n,e]  (fp16, exact 0/1)
__global__ __launch_bounds__(256) void k_incT(const float* __restrict__ inc, _Float16* __restrict__ incT) {
  __shared__ float tile[64][65];
  int e0 = blockIdx.x * 64, n0 = blockIdx.y * 64;
  int t = threadIdx.x, c = t & 63, r = t >> 6;
#pragma unroll
  for (int i = 0; i < 16; ++i) tile[r + i * 4][c] = inc[(size_t)(n0 + r + i * 4) * EE + e0 + c];
  __syncthreads();
#pragma unroll
  for (int i = 0; i < 16; ++i) {
    int row = r + i * 4;
    incT[(size_t)(e0 + row) * NN + n0 + c] = (_Float16)tile[c][row];
  }
}

// w2t[e,f] = fp16(W2[f,e])
__global__ __launch_bounds__(256) void k_w2t(const float* __restrict__ W2, _Float16* __restrict__ hi) {
  __shared__ float tile[64][65];
  int f0 = blockIdx.x * 64, e0 = blockIdx.y * 64;
  int t = threadIdx.x, c = t & 63, r = t >> 6;
#pragma unroll
  for (int i = 0; i < 16; ++i) tile[r + i * 4][c] = W2[(size_t)(f0 + r + i * 4) * EE + e0 + c];
  __syncthreads();
#pragma unroll
  for (int i = 0; i < 16; ++i) {
    int row = r + i * 4;
    hi[(size_t)(e0 + row) * EE + f0 + c] = (_Float16)tile[c][row];
  }
}

// wt16[d,c] = fp16(W[c,d])
__global__ __launch_bounds__(256) void k_wt16(const float* __restrict__ W, _Float16* __restrict__ wt) {
  __shared__ float tile[64][65];
  int c0 = blockIdx.x * 64, d0 = blockIdx.y * 64;
  int t = threadIdx.x, c = t & 63, r = t >> 6;
#pragma unroll
  for (int i = 0; i < 16; ++i) tile[r + i * 4][c] = W[(size_t)(c0 + r + i * 4) * DD + d0 + c];
  __syncthreads();
#pragma unroll
  for (int i = 0; i < 16; ++i) {
    int row = r + i * 4;
    wt[(size_t)(d0 + row) * CIN + c0 + c] = (_Float16)tile[c][row];
  }
}

// xt16[b,n,c] = fp16(x_in[b,c,n])
__global__ __launch_bounds__(256) void k_xt(const float* __restrict__ x, const float* __restrict__ m,
                                            const float* __restrict__ hid, _Float16* __restrict__ xt) {
  __shared__ float tile[64][65];
  int c0 = blockIdx.x * 64, n0 = blockIdx.y * 64, b = blockIdx.z;
  int t = threadIdx.x, c = t & 63, r = t >> 6;
#pragma unroll
  for (int i = 0; i < 16; ++i) {
    int ch = c0 + r + i * 4;
    const float* row;
    if (ch < 96) row = x + ((size_t)b * 96 + ch) * NN;
    else if (ch < 192) row = m + ((size_t)b * 96 + (ch - 96)) * NN;
    else row = hid + ((size_t)b * 64 + (ch - 192)) * NN;
    tile[r + i * 4][c] = row[n0 + c];
  }
  __syncthreads();
#pragma unroll
  for (int i = 0; i < 16; ++i) {
    int row = r + i * 4;
    xt[((size_t)b * NN + n0 + row) * CIN + c0 + c] = (_Float16)tile[c][row];
  }
}

// wa[c]=sum_d W[c,d]*a[d]; wa[256+c]=..a[D+d]; wa[512+c]=..a2[d]; wa[768..770]=sum(a[:D]),sum(a[D:]),sum(a2[:D])
__global__ __launch_bounds__(256) void k_wa(const float* __restrict__ W, const float* __restrict__ a,
                                            const float* __restrict__ a2, float* __restrict__ wa) {
  __shared__ float red[3][4];
  int c = blockIdx.x, t = threadIdx.x;
  int l = t & 63, wv = t >> 6;
  float w = W[(size_t)c * DD + t];
  float p0 = w * a[t], p1 = w * a[DD + t], p2 = w * a2[t];
#pragma unroll
  for (int off = 32; off > 0; off >>= 1) {
    p0 += __shfl_down(p0, off);
    p1 += __shfl_down(p1, off);
    p2 += __shfl_down(p2, off);
  }
  if (l == 0) {
    red[0][wv] = p0;
    red[1][wv] = p1;
    red[2][wv] = p2;
  }
  __syncthreads();
  if (t == 0) wa[c] = red[0][0] + red[0][1] + red[0][2] + red[0][3];
  if (t == 1) wa[256 + c] = red[1][0] + red[1][1] + red[1][2] + red[1][3];
  if (t == 2) wa[512 + c] = red[2][0] + red[2][1] + red[2][2] + red[2][3];
  if (blockIdx.x == 0) {
    __syncthreads();
    float q0 = a[t], q1 = a[DD + t], q2 = a2[t];
#pragma unroll
    for (int off = 32; off > 0; off >>= 1) {
      q0 += __shfl_down(q0, off);
      q1 += __shfl_down(q1, off);
      q2 += __shfl_down(q2, off);
    }
    if (l == 0) {
      red[0][wv] = q0;
      red[1][wv] = q1;
      red[2][wv] = q2;
    }
    __syncthreads();
    if (t == 0) wa[768] = red[0][0] + red[0][1] + red[0][2] + red[0][3];
    if (t == 1) wa[769] = red[1][0] + red[1][1] + red[1][2] + red[1][3];
    if (t == 2) wa[770] = red[2][0] + red[2][1] + red[2][2] + red[2][3];
  }
}

// incs16[n,f] = fp16(inc[n,f] * invdeg[f]); deg computed internally (column sums)
__global__ __launch_bounds__(256) void k_incs(const float* __restrict__ inc, _Float16* __restrict__ incs16) {
  __shared__ float red[4][64];
  __shared__ float siv[64];
  int f0 = blockIdx.x * 64;
  int t = threadIdx.x;
  int fl = t & 63, rg = t >> 6;
  float s = 0.f;
  for (int i = 0; i < 64; ++i) s += inc[(size_t)(rg * 64 + i) * EE + f0 + fl];
  red[rg][fl] = s;
  __syncthreads();
  if (t < 64) siv[t] = 1.0f / (red[0][t] + red[1][t] + red[2][t] + red[3][t]);
  __syncthreads();
  float iv = siv[fl];
  for (int i = 0; i < 64; ++i) {
    int n = rg + i * 4;
    incs16[(size_t)n * EE + f0 + fl] = (_Float16)(inc[(size_t)n * EE + f0 + fl] * iv);
  }
}

// node_sc/g1/g2[b,n] directly from x_in (exact fp32); one block per b, thread t = n
__global__ __launch_bounds__(256) void k_ns2(const float* __restrict__ x, const float* __restrict__ m,
                                             const float* __restrict__ hid, const float* __restrict__ wa,
                                             const float* __restrict__ bias, float* __restrict__ node_sc,
                                             float* __restrict__ g1, float* __restrict__ g2) {
  __shared__ float s0a[256], s1a[256], s2a[256];
  int b = blockIdx.x, t = threadIdx.x;
  s0a[t] = wa[t];
  s1a[t] = wa[256 + t];
  s2a[t] = wa[512 + t];
  __syncthreads();
  float s0 = 0.f, s1 = 0.f, s2 = 0.f;
#pragma unroll 4
  for (int c = 0; c < 256; ++c) {
    const float* row;
    if (c < 96) row = x + ((size_t)b * 96 + c) * NN;
    else if (c < 192) row = m + ((size_t)b * 96 + (c - 96)) * NN;
    else row = hid + ((size_t)b * 64 + (c - 192)) * NN;
    float v = row[t];
    s0 += v * s0a[c];
    s1 += v * s1a[c];
    s2 += v * s2a[c];
  }
  float bv = bias[t];
  int idx = b * NN + t;
  node_sc[idx] = s0 + bv * wa[768];
  g1[idx] = s1 + bv * wa[769];
  g2[idx] = s2 + bv * wa[770];
}

// hThi[b,d,n] = fp16(sum_c xt16[b,n,c]*wt16[d,c] + bias[n]); fp16 MFMA 64x64, single-buffer
__global__ __launch_bounds__(256) void k_h16(const _Float16* __restrict__ xt, const _Float16* __restrict__ wt,
                                             const float* __restrict__ bias, _Float16* __restrict__ hThi) {
  __shared__ _Float16 smA[64 * 64];
  __shared__ _Float16 smB[64 * 64];
  int bid = blockIdx.x;
  int xcd = bid & 7, il = bid >> 3;  // 96 per XCD
  int ntile = il & 3, dtile = (il >> 2) & 3, bl = il >> 4;
  int b = xcd * 6 + bl;
  int n0 = ntile * 64, d0 = dtile * 64;
  int t = threadIdx.x, w = t >> 6, l = t & 63;
  int wm = w >> 1, wn = w & 1;
  int lr = l & 15;
  const _Float16* A = xt + ((size_t)b * NN + n0) * CIN;
  const _Float16* Bp = wt + (size_t)d0 * CIN;
  int lrow = l >> 3;
  int scol = 8 * ((l & 7) ^ (lrow & 7));
  f32x4 acc[2][2];
  f32x4 z = {0.f, 0.f, 0.f, 0.f};
#pragma unroll
  for (int i = 0; i < 2; ++i)
#pragma unroll
    for (int j = 0; j < 2; ++j) acc[i][j] = z;
  for (int kk = 0; kk < CIN; kk += 64) {
#pragma unroll
    for (int q = 0; q < 2; ++q) {
      int row = q * 32 + w * 8 + lrow;
      int lb = (q * 32 + w * 8) * 64;
      gload16(A + (size_t)row * CIN + kk + scol, smA + lb);
      gload16(Bp + (size_t)row * CIN + kk + scol, smB + lb);
    }
    __syncthreads();
    f16x8 af[2][2], bf[2][2];
#pragma unroll
    for (int i = 0; i < 2; ++i)
#pragma unroll
      for (int ks = 0; ks < 2; ++ks) {
        int ra = wm * 32 + i * 16 + lr;
        af[i][ks] = *(const f16x8*)&smA[ra * 64 + ((ks * 32 + (l >> 4) * 8) ^ ((ra & 7) << 3))];
        int rb = wn * 32 + i * 16 + lr;
        bf[i][ks] = *(const f16x8*)&smB[rb * 64 + ((ks * 32 + (l >> 4) * 8) ^ ((rb & 7) << 3))];
      }
#pragma unroll
    for (int ks = 0; ks < 2; ++ks)
#pragma unroll
      for (int i = 0; i < 2; ++i)
#pragma unroll
        for (int j = 0; j < 2; ++j)
          acc[i][j] = __builtin_amdgcn_mfma_f32_16x16x32_f16(af[i][ks], bf[j][ks], acc[i][j], 0, 0, 0);
    __syncthreads();
  }
#pragma unroll
  for (int i = 0; i < 2; ++i)
#pragma unroll
    for (int j = 0; j < 2; ++j) {
      int nb = n0 + wm * 32 + i * 16 + (l >> 4) * 4;
      int d = d0 + wn * 32 + j * 16 + lr;
      float4 bv = *(const float4*)&bias[nb];
      f16x4 vh;
      vh[0] = (_Float16)(acc[i][j][0] + bv.x);
      vh[1] = (_Float16)(acc[i][j][1] + bv.y);
      vh[2] = (_Float16)(acc[i][j][2] + bv.z);
      vh[3] = (_Float16)(acc[i][j][3] + bv.w);
      *(f16x4*)&hThi[((size_t)b * DD + d) * NN + nb] = vh;
    }
}

// u1[b,f] = invdeg[f]*sum_n incT[f,n]*g1[b,n]; u2 same with g2; deg computed inline
__global__ __launch_bounds__(256) void k_uu(const _Float16* __restrict__ incT, const float* __restrict__ g1,
                                            const float* __restrict__ g2, float* __restrict__ u1,
                                            float* __restrict__ u2) {
  __shared__ float sg1[NN], sg2[NN];
  __shared__ float r0[4][64], r1[4][64], r2[4][64];
  int b = blockIdx.y;
  int f0 = blockIdx.x * 64;
  int t = threadIdx.x;
  sg1[t] = g1[b * NN + t];
  sg2[t] = g2[b * NN + t];
  __syncthreads();
  int fl = t & 63, ng = t >> 6;
  int f = f0 + fl;
  float s0 = 0.f, s1 = 0.f, s2 = 0.f;
  const _Float16* row = incT + (size_t)f * NN + ng * 64;
  for (int i = 0; i < 64; i += 8) {
    f16x8 ic = *(const f16x8*)&row[i];
#pragma unroll
    for (int j = 0; j < 8; ++j) {
      float icf = (float)ic[j];
      int n = ng * 64 + i + j;
      s0 += icf;
      s1 += icf * sg1[n];
      s2 += icf * sg2[n];
    }
  }
  r0[ng][fl] = s0;
  r1[ng][fl] = s1;
  r2[ng][fl] = s2;
  __syncthreads();
  if (t < 64) {
    float dg = r0[0][t] + r0[1][t] + r0[2][t] + r0[3][t];
    float iv = 1.0f / dg;
    u1[(size_t)b * EE + f0 + t] = (r1[0][t] + r1[1][t] + r1[2][t] + r1[3][t]) * iv;
    u2[(size_t)b * EE + f0 + t] = (r2[0][t] + r2[1][t] + r2[2][t] + r2[3][t]) * iv;
  }
}

// edge_sc[b,e] = sum_f W2[f,e]*u1[b,f];  time_e = lrelu(... + pri_e*a2[D]); 6 b per block
__global__ __launch_bounds__(256) void k_esc(const float* __restrict__ W2, const float* __restrict__ u1,
                                             const float* __restrict__ u2, const float* __restrict__ pri_e,
                                             const float* __restrict__ a2, float* __restrict__ edge_sc,
                                             float* __restrict__ time_e) {
  __shared__ float su1[6 * 1024];
  __shared__ float su2[6 * 1024];
  __shared__ float rr[2][4][6][64];
  int e0 = blockIdx.x * 64, b0 = blockIdx.y * 6;
  int t = threadIdx.x;
#pragma unroll
  for (int i = 0; i < 6; ++i) {
    *(float4*)&su1[i * 1024 + t * 4] = *(const float4*)&u1[(size_t)(b0 + i) * EE + t * 4];
    *(float4*)&su2[i * 1024 + t * 4] = *(const float4*)&u2[(size_t)(b0 + i) * EE + t * 4];
  }
  __syncthreads();
  int el = t & 63, fg = t >> 6;
  int e = e0 + el;
  float s1[6] = {}, s2[6] = {};
  for (int i = 0; i < 256; i += 4) {
    int f = fg * 256 + i;
    float w0 = W2[(size_t)f * EE + e];
    float w1 = W2[(size_t)(f + 1) * EE + e];
    float w2v = W2[(size_t)(f + 2) * EE + e];
    float w3 = W2[(size_t)(f + 3) * EE + e];
#pragma unroll
    for (int bl = 0; bl < 6; ++bl) {
      f32x4 va = *(const f32x4*)&su1[bl * 1024 + f];
      f32x4 vb = *(const f32x4*)&su2[bl * 1024 + f];
      s1[bl] += w0 * va[0] + w1 * va[1] + w2v * va[2] + w3 * va[3];
      s2[bl] += w0 * vb[0] + w1 * vb[1] + w2v * vb[2] + w3 * vb[3];
    }
  }
#pragma unroll
  for (int bl = 0; bl < 6; ++bl) {
    rr[0][fg][bl][el] = s1[bl];
    rr[1][fg][bl][el] = s2[bl];
  }
  __syncthreads();
  for (int bl = t >> 6; bl < 6; bl += 4) {
    int ee = t & 63;
    int row = (b0 + bl) * EE + e0 + ee;
    float v1 = rr[0][0][bl][ee] + rr[0][1][bl][ee] + rr[0][2][bl][ee] + rr[0][3][bl][ee];
    float v2 = rr[1][0][bl][ee] + rr[1][1][bl][ee] + rr[1][2][bl][ee] + rr[1][3][bl][ee];
    edge_sc[row] = v1;
    time_e[row] = lrelu(v2 + pri_e[row] * a2[DD]);
  }
}

// softmax stats over n per (b,e)
__global__ __launch_bounds__(256) void k_d3(const _Float16* __restrict__ incT, const float* __restrict__ node_sc,
                                            const float* __restrict__ edge_sc, const float* __restrict__ time_e,
                                            const float* __restrict__ a3, float* __restrict__ rmax,
                                            float* __restrict__ rinv) {
  int t = threadIdx.x;
  int w = t >> 6, l = t & 63;
  int row = blockIdx.x * 4 + w;
  int b = row >> 10;
  int e = row & (EE - 1);
  float a30 = a3[0], a31 = a3[1];
  float esc = edge_sc[row], te = time_e[row];
  float s2v[4];
  bool msk[4];
  float vmax = -3.0e38f;
#pragma unroll
  for (int q = 0; q < 4; ++q) {
    int n = l + q * 64;
    float ic = (float)incT[(size_t)e * NN + n];
    float s1 = lrelu(node_sc[(size_t)b * NN + n] + esc);
    float s2 = lrelu(te * a30 + s1 * a31);
    msk[q] = ic > 0.f;
    s2v[q] = s2;
    if (msk[q]) vmax = fmaxf(vmax, s2);
  }
#pragma unroll
  for (int off = 32; off > 0; off >>= 1) vmax = fmaxf(vmax, __shfl_xor(vmax, off));
  float ss = 0.f;
#pragma unroll
  for (int q = 0; q < 4; ++q)
    if (msk[q]) ss += __expf(s2v[q] - vmax);
#pragma unroll
  for (int off = 32; off > 0; off >>= 1) ss += __shfl_xor(ss, off);
  if (l == 0) {
    rmax[row] = vmax;
    rinv[row] = 1.0f / ss;
  }
}

// M16[e,n] = sum_f incs16[n,f]*w2t[e,f]; 128n x 64e tiles, BK=64; batch-independent (0.27 G MAC)
__global__ __launch_bounds__(256) void k_M(const _Float16* __restrict__ incs, const _Float16* __restrict__ w2t,
                                           _Float16* __restrict__ M16) {
  __shared__ _Float16 smA[128 * 64];
  __shared__ _Float16 smB[64 * 64];
  int bid = blockIdx.x;
  int np = bid & 1, ep = bid >> 1;
  int m0 = np * 128;  // n rows
  int n0 = ep * 64;   // e cols
  int t = threadIdx.x, w = t >> 6, l = t & 63;
  int wm = w >> 1, wn = w & 1;
  int lr = l & 15, lg = l >> 4;
  int srow = l >> 3, sgrp = l & 7;
  int sc = (sgrp ^ srow) * 8;
  const _Float16* A = incs + (size_t)m0 * EE;
  const _Float16* Bp = w2t + (size_t)n0 * EE;
  f32x4 acc[4][2];
  f32x4 z = {0.f, 0.f, 0.f, 0.f};
#pragma unroll
  for (int i = 0; i < 4; ++i)
#pragma unroll
    for (int j = 0; j < 2; ++j) acc[i][j] = z;
  for (int kk = 0; kk < EE; kk += 64) {
#pragma unroll
    for (int q = 0; q < 4; ++q) {
      int c = w * 4 + q;
      int r = c * 8 + srow;
      gload16(A + (size_t)r * EE + kk + sc, smA + c * 512);
    }
#pragma unroll
    for (int q = 0; q < 2; ++q) {
      int c = w * 2 + q;
      int r = c * 8 + srow;
      gload16(Bp + (size_t)r * EE + kk + sc, smB + c * 512);
    }
    __syncthreads();
    f16x8 ah[4][2], bh[2][2];
#pragma unroll
    for (int i = 0; i < 4; ++i) {
      int ra = wm * 64 + i * 16 + lr;
#pragma unroll
      for (int ks = 0; ks < 2; ++ks)
        ah[i][ks] = *(const f16x8*)&smA[ra * 64 + (((ks * 4 + lg) ^ (ra & 7)) * 8)];
    }
#pragma unroll
    for (int j = 0; j < 2; ++j) {
      int rb = wn * 32 + j * 16 + lr;
#pragma unroll
      for (int ks = 0; ks < 2; ++ks)
        bh[j][ks] = *(const f16x8*)&smB[rb * 64 + (((ks * 4 + lg) ^ (rb & 7)) * 8)];
    }
#pragma unroll
    for (int ks = 0; ks < 2; ++ks)
#pragma unroll
      for (int i = 0; i < 4; ++i)
#pragma unroll
        for (int j = 0; j < 2; ++j)
          acc[i][j] = __builtin_amdgcn_mfma_f32_16x16x32_f16(ah[i][ks], bh[j][ks], acc[i][j], 0, 0, 0);
    __syncthreads();
  }
#pragma unroll
  for (int i = 0; i < 4; ++i)
#pragma unroll
    for (int j = 0; j < 2; ++j) {
      int n = m0 + wm * 64 + i * 16 + lg * 4;  // row quad
      int e = n0 + wn * 32 + j * 16 + lr;      // col
      f16x4 v;
#pragma unroll
      for (int r = 0; r < 4; ++r) v[r] = (_Float16)acc[i][j][r];
      *(f16x4*)&M16[(size_t)e * NN + n] = v;
    }
}

// out1[b,e,d] = sum_n M16[e,n]*hThi[b,d,n]; 128e x 64d, BK=64, K=256; b-pinned XCD; emits out1T16
__global__ __launch_bounds__(256) void k_out1n(const _Float16* __restrict__ M16, const _Float16* __restrict__ hThi,
                                               float* __restrict__ out1, _Float16* __restrict__ out1T) {
  __shared__ _Float16 smA[128 * 64];
  __shared__ _Float16 smB[64 * 64];
  int bid = blockIdx.x;
  int xcd = bid & 7, il = bid >> 3;  // 192 per XCD
  int ep = il & 7, dblk = (il >> 3) & 3, bl = il >> 5;
  int b = xcd * 6 + bl;
  int m0 = ep * 128;   // e
  int n0 = dblk * 64;  // d
  int t = threadIdx.x, w = t >> 6, l = t & 63;
  int wm = w >> 1, wn = w & 1;
  int lr = l & 15, lg = l >> 4;
  int srow = l >> 3, sgrp = l & 7;
  int sc = (sgrp ^ srow) * 8;
  const _Float16* A = M16 + (size_t)m0 * NN;
  const _Float16* Bp = hThi + ((size_t)b * DD + n0) * NN;
  f32x4 acc[4][2];
  f32x4 z = {0.f, 0.f, 0.f, 0.f};
#pragma unroll
  for (int i = 0; i < 4; ++i)
#pragma unroll
    for (int j = 0; j < 2; ++j) acc[i][j] = z;
  for (int kk = 0; kk < NN; kk += 64) {
#pragma unroll
    for (int q = 0; q < 4; ++q) {
      int c = w * 4 + q;
      int r = c * 8 + srow;
      gload16(A + (size_t)r * NN + kk + sc, smA + c * 512);
    }
#pragma unroll
    for (int q = 0; q < 2; ++q) {
      int c = w * 2 + q;
      int r = c * 8 + srow;
      gload16(Bp + (size_t)r * NN + kk + sc, smB + c * 512);
    }
    __syncthreads();
    f16x8 ah[4][2], bh[2][2];
#pragma unroll
    for (int i = 0; i < 4; ++i) {
      int ra = wm * 64 + i * 16 + lr;
#pragma unroll
      for (int ks = 0; ks < 2; ++ks)
        ah[i][ks] = *(const f16x8*)&smA[ra * 64 + (((ks * 4 + lg) ^ (ra & 7)) * 8)];
    }
#pragma unroll
    for (int j = 0; j < 2; ++j) {
      int rb = wn * 32 + j * 16 + lr;
#pragma unroll
      for (int ks = 0; ks < 2; ++ks)
        bh[j][ks] = *(const f16x8*)&smB[rb * 64 + (((ks * 4 + lg) ^ (rb & 7)) * 8)];
    }
#pragma unroll
    for (int ks = 0; ks < 2; ++ks)
#pragma unroll
      for (int i = 0; i < 4; ++i)
#pragma unroll
        for (int j = 0; j < 2; ++j)
          acc[i][j] = __builtin_amdgcn_mfma_f32_16x16x32_f16(ah[i][ks], bh[j][ks], acc[i][j], 0, 0, 0);
    __syncthreads();
  }
#pragma unroll
  for (int i = 0; i < 4; ++i)
#pragma unroll
    for (int j = 0; j < 2; ++j) {
      int e = m0 + wm * 64 + i * 16 + lg * 4;
      int d = n0 + wn * 32 + j * 16 + lr;
      f16x4 v16;
#pragma unroll
      for (int r = 0; r < 4; ++r) {
        out1[((size_t)b * EE + e + r) * DD + d] = acc[i][j][r];
        v16[r] = (_Float16)acc[i][j][r];
      }
      *(f16x4*)&out1T[((size_t)b * DD + d) * EE + e] = v16;
    }
}

// att16[b,n,e] = softmax coefficient (fp16)
__global__ __launch_bounds__(256) void k_att(const float* __restrict__ inc, const float* __restrict__ node_sc,
                                             const float* __restrict__ edge_sc, const float* __restrict__ time_e,
                                             const float* __restrict__ rmax, const float* __restrict__ rinv,
                                             const float* __restrict__ a3, _Float16* __restrict__ att16) {
  int n = blockIdx.x, b = blockIdx.y;
  int e = threadIdx.x * 4;
  float a30 = a3[0], a31 = a3[1];
  float ns = node_sc[b * NN + n];
  float4 icv = *(const float4*)&inc[(size_t)n * EE + e];
  int be = b * EE + e;
  float4 esc = *(const float4*)&edge_sc[be];
  float4 te = *(const float4*)&time_e[be];
  float4 rm = *(const float4*)&rmax[be];
  float4 ri = *(const float4*)&rinv[be];
  float ica[4] = {icv.x, icv.y, icv.z, icv.w};
  float ea[4] = {esc.x, esc.y, esc.z, esc.w};
  float ta[4] = {te.x, te.y, te.z, te.w};
  float ma[4] = {rm.x, rm.y, rm.z, rm.w};
  float ra[4] = {ri.x, ri.y, ri.z, ri.w};
  f16x4 o;
#pragma unroll
  for (int q = 0; q < 4; ++q) {
    float att = 0.f;
    if (ica[q] > 0.f) {
      float s1 = lrelu(ns + ea[q]);
      float s2 = lrelu(ta[q] * a30 + s1 * a31);
      att = __expf(s2 - ma[q]) * ra[q];
    }
    o[q] = (_Float16)att;
  }
  *(f16x4*)&att16[((size_t)b * NN + n) * EE + e] = o;
}

// out0[b,d,n] = sum_e att16[n,e]*out1T16[d,e]; 64x64, single-buffer; b-pinned XCD
__global__ __launch_bounds__(256) void k_fgemm(const _Float16* __restrict__ att16, const _Float16* __restrict__ out1T,
                                               float* __restrict__ out0) {
  __shared__ _Float16 smA[64 * 64];
  __shared__ _Float16 smB[64 * 64];
  int bid = blockIdx.x;
  int xcd = bid & 7, il = bid >> 3;  // 96 per XCD
  int ntile = il & 3, dtile = (il >> 2) & 3, bl = il >> 4;
  int b = xcd * 6 + bl;
  int n0 = ntile * 64, d0 = dtile * 64;
  int t = threadIdx.x, w = t >> 6, l = t & 63;
  int wm = w >> 1, wn = w & 1;
  int lr = l & 15;
  const _Float16* A = att16 + ((size_t)b * NN + n0) * EE;
  const _Float16* Bp = out1T + ((size_t)b * DD + d0) * EE;
  int lrow = l >> 3;
  int scol = 8 * ((l & 7) ^ (lrow & 7));
  f32x4 acc[2][2];
  f32x4 z = {0.f, 0.f, 0.f, 0.f};
#pragma unroll
  for (int i = 0; i < 2; ++i)
#pragma unroll
    for (int j = 0; j < 2; ++j) acc[i][j] = z;
  for (int kk = 0; kk < EE; kk += 64) {
#pragma unroll
    for (int q = 0; q < 2; ++q) {
      int row = q * 32 + w * 8 + lrow;
      int lb = (q * 32 + w * 8) * 64;
      gload16(A + (size_t)row * EE + kk + scol, smA + lb);
      gload16(Bp + (size_t)row * EE + kk + scol, smB + lb);
    }
    __syncthreads();
    f16x8 af[2][2], bf[2][2];
#pragma unroll
    for (int i = 0; i < 2; ++i)
#pragma unroll
      for (int ks = 0; ks < 2; ++ks) {
        int ra = wm * 32 + i * 16 + lr;
        af[i][ks] = *(const f16x8*)&smA[ra * 64 + ((ks * 32 + (l >> 4) * 8) ^ ((ra & 7) << 3))];
        int rb = wn * 32 + i * 16 + lr;
        bf[i][ks] = *(const f16x8*)&smB[rb * 64 + ((ks * 32 + (l >> 4) * 8) ^ ((rb & 7) << 3))];
      }
#pragma unroll
    for (int ks = 0; ks < 2; ++ks)
#pragma unroll
      for (int i = 0; i < 2; ++i)
#pragma unroll
        for (int j = 0; j < 2; ++j)
          acc[i][j] = __builtin_amdgcn_mfma_f32_16x16x32_f16(af[i][ks], bf[j][ks], acc[i][j], 0, 0, 0);
    __syncthreads();
  }
  float* ob = out0 + (size_t)b * DD * NN;
#pragma unroll
  for (int i = 0; i < 2; ++i)
#pragma unroll
    for (int j = 0; j < 2; ++j) {
      int n = n0 + wm * 32 + i * 16 + (l >> 4) * 4;
      int d = d0 + wn * 32 + j * 16 + lr;
      *(float4*)&ob[(size_t)d * NN + n] =
          make_float4(acc[i][j][0], acc[i][j][1], acc[i][j][2], acc[i][j][3]);
    }
}

extern "C" void kernel_launch(void* const* d_in, const int* in_sizes, int n_in, void* d_out, int out_size,
                              void* d_ws, size_t ws_size, hipStream_t stream) {
  (void)in_sizes;
  (void)n_in;
  (void)out_size;
  (void)ws_size;
  const float* x = (const float*)d_in[0];
  const float* m = (const float*)d_in[1];
  const float* hid = (const float*)d_in[2];
  const float* pri_e = (const float*)d_in[3];
  const float* inc = (const float*)d_in[5];
  const float* W = (const float*)d_in[6];
  const float* bias = (const float*)d_in[7];
  const float* W2 = (const float*)d_in[8];
  const float* a = (const float*)d_in[9];
  const float* a2 = (const float*)d_in[10];
  const float* a3 = (const float*)d_in[11];

  float* out0 = (float*)d_out;                // [B,D,N]
  float* out1 = out0 + (size_t)BB * DD * NN;  // [B,E,D] fp32 (written by k_out1n)
  _Float16* xt16 = (_Float16*)out1;           // [B,N,CIN] fp16 — dead after k_h16, before out1 written

  _Float16* att16 = (_Float16*)d_ws;                    // [B,N,E]
  _Float16* out1T16 = att16 + (size_t)BB * NN * EE;     // [B,D,E]
  _Float16* hThi = out1T16 + (size_t)BB * DD * EE;      // [B,D,N]
  _Float16* incT = hThi + (size_t)BB * DD * NN;         // [E,N]
  _Float16* w2thi = incT + (size_t)EE * NN;             // [E,E]
  _Float16* incs16 = w2thi + (size_t)EE * EE;           // [N,E]
  _Float16* M16 = incs16 + (size_t)NN * EE;             // [E,N]
  _Float16* wt16 = M16 + (size_t)EE * NN;               // [D,CIN]
  float* node_sc = (float*)(wt16 + (size_t)DD * CIN);   // B*N
  float* g1 = node_sc + (size_t)BB * NN;                // B*N
  float* g2 = g1 + (size_t)BB * NN;                     // B*N
  float* edge_sc = g2 + (size_t)BB * NN;                // B*E
  float* time_e = edge_sc + (size_t)BB * EE;            // B*E
  float* rmax = time_e + (size_t)BB * EE;               // B*E
  float* rinv = rmax + (size_t)BB * EE;                 // B*E
  float* u1 = rinv + (size_t)BB * EE;                   // B*E
  float* u2 = u1 + (size_t)BB * EE;                     // B*E
  float* wa = u2 + (size_t)BB * EE;                     // 1024

  k_incT<<<dim3(EE / 64, NN / 64), 256, 0, stream>>>(inc, incT);
  k_w2t<<<dim3(EE / 64, EE / 64), 256, 0, stream>>>(W2, w2thi);
  k_wt16<<<dim3(CIN / 64, DD / 64), 256, 0, stream>>>(W, wt16);
  k_xt<<<dim3(CIN / 64, NN / 64, BB), 256, 0, stream>>>(x, m, hid, xt16);
  k_wa<<<dim3(CIN), 256, 0, stream>>>(W, a, a2, wa);
  k_incs<<<dim3(EE / 64), 256, 0, stream>>>(inc, incs16);
  k_h16<<<dim3(8 * 96), 256, 0, stream>>>(xt16, wt16, bias, hThi);
  k_ns2<<<dim3(BB), 256, 0, stream>>>(x, m, hid, wa, bias, node_sc, g1, g2);
  k_uu<<<dim3(EE / 64, BB), 256, 0, stream>>>(incT, g1, g2, u1, u2);
  k_esc<<<dim3(EE / 64, BB / 6), 256, 0, stream>>>(W2, u1, u2, pri_e, a2, edge_sc, time_e);
  k_d3<<<dim3((BB * EE) / 4), 256, 0, stream>>>(incT, node_sc, edge_sc, time_e, a3, rmax, rinv);
  k_M<<<dim3(2 * 16), 256, 0, stream>>>(incs16, w2thi, M16);
  k_out1n<<<dim3(8 * 192), 256, 0, stream>>>(M16, hThi, out1, out1T16);
  k_att<<<dim3(NN, BB), 256, 0, stream>>>(inc, node_sc, edge_sc, time_e, rmax, rinv, a3, att16);
  k_fgemm<<<dim3(8 * 96), 256, 0, stream>>>(att16, out1T16, out0);
}

// Round 10
// 155.253 us; speedup vs baseline: 1.2960x; 1.1104x over previous
//
#include <hip/hip_runtime.h>

#define BB 48
#define NN 256
#define EE 1024
#define DD 256
#define CIN 256

typedef __attribute__((ext_vector_type(4))) float f32x4;
typedef __attribute__((ext_vector_type(8))) _Float16 f16x8;
typedef __attribute__((ext_vector_type(4))) _Float16 f16x4;

__device__ __forceinline__ float lrelu(float t) { return t >= 0.0f ? t : 0.2f * t; }

__device__ __forceinline__ void gload16(const void* g, void* l) {
  __builtin_amdgcn_global_load_lds((const __attribute__((address_space(1))) void*)g,
                                   (__attribute__((address_space(3))) void*)l, 16, 0, 0);
}

// ---------------- k_prep: incT, w2t, wt16, incs, wa, xt (all input-only) ----------------
__global__ __launch_bounds__(256) void k_prep(const float* __restrict__ inc, const float* __restrict__ W2,
                                              const float* __restrict__ W, const float* __restrict__ x,
                                              const float* __restrict__ m, const float* __restrict__ hid,
                                              const float* __restrict__ a, const float* __restrict__ a2,
                                              _Float16* __restrict__ incT, _Float16* __restrict__ w2t,
                                              _Float16* __restrict__ wt16, _Float16* __restrict__ incs16,
                                              float* __restrict__ wa, _Float16* __restrict__ xt) {
  __shared__ float tile[64][65];
  __shared__ float aux[4][64];
  __shared__ float aux2[64];
  int bid = blockIdx.x;
  int t = threadIdx.x;
  if (bid < 256) {  // w2t[e,f] = fp16(W2[f,e]); grid 16x16
    int s = bid;
    int f0 = (s & 15) * 64, e0 = (s >> 4) * 64;
    int c = t & 63, r = t >> 6;
#pragma unroll
    for (int i = 0; i < 16; ++i) tile[r + i * 4][c] = W2[(size_t)(f0 + r + i * 4) * EE + e0 + c];
    __syncthreads();
#pragma unroll
    for (int i = 0; i < 16; ++i) {
      int row = r + i * 4;
      w2t[(size_t)(e0 + row) * EE + f0 + c] = (_Float16)tile[c][row];
    }
  } else if (bid < 320) {  // incT[e,n] = inc[n,e]
    int s = bid - 256;
    int e0 = (s & 15) * 64, n0 = (s >> 4) * 64;
    int c = t & 63, r = t >> 6;
#pragma unroll
    for (int i = 0; i < 16; ++i) tile[r + i * 4][c] = inc[(size_t)(n0 + r + i * 4) * EE + e0 + c];
    __syncthreads();
#pragma unroll
    for (int i = 0; i < 16; ++i) {
      int row = r + i * 4;
      incT[(size_t)(e0 + row) * NN + n0 + c] = (_Float16)tile[c][row];
    }
  } else if (bid < 336) {  // wt16[d,c] = fp16(W[c,d])
    int s = bid - 320;
    int c0 = (s & 3) * 64, d0 = (s >> 2) * 64;
    int c = t & 63, r = t >> 6;
#pragma unroll
    for (int i = 0; i < 16; ++i) tile[r + i * 4][c] = W[(size_t)(c0 + r + i * 4) * DD + d0 + c];
    __syncthreads();
#pragma unroll
    for (int i = 0; i < 16; ++i) {
      int row = r + i * 4;
      wt16[(size_t)(d0 + row) * CIN + c0 + c] = (_Float16)tile[c][row];
    }
  } else if (bid < 352) {  // incs16[n,f] = fp16(inc[n,f]*invdeg[f])
    int f0 = (bid - 336) * 64;
    int fl = t & 63, rg = t >> 6;
    float s = 0.f;
    for (int i = 0; i < 64; ++i) s += inc[(size_t)(rg * 64 + i) * EE + f0 + fl];
    aux[rg][fl] = s;
    __syncthreads();
    if (t < 64) aux2[t] = 1.0f / (aux[0][t] + aux[1][t] + aux[2][t] + aux[3][t]);
    __syncthreads();
    float iv = aux2[fl];
    for (int i = 0; i < 64; ++i) {
      int n = rg + i * 4;
      incs16[(size_t)n * EE + f0 + fl] = (_Float16)(inc[(size_t)n * EE + f0 + fl] * iv);
    }
  } else if (bid < 608) {  // wa
    float(*red)[4] = (float(*)[4])aux;
    int c = bid - 352;
    int l = t & 63, wv = t >> 6;
    float w = W[(size_t)c * DD + t];
    float p0 = w * a[t], p1 = w * a[DD + t], p2 = w * a2[t];
#pragma unroll
    for (int off = 32; off > 0; off >>= 1) {
      p0 += __shfl_down(p0, off);
      p1 += __shfl_down(p1, off);
      p2 += __shfl_down(p2, off);
    }
    if (l == 0) {
      red[0][wv] = p0;
      red[1][wv] = p1;
      red[2][wv] = p2;
    }
    __syncthreads();
    if (t == 0) wa[c] = red[0][0] + red[0][1] + red[0][2] + red[0][3];
    if (t == 1) wa[256 + c] = red[1][0] + red[1][1] + red[1][2] + red[1][3];
    if (t == 2) wa[512 + c] = red[2][0] + red[2][1] + red[2][2] + red[2][3];
    if (c == 0) {
      __syncthreads();
      float q0 = a[t], q1 = a[DD + t], q2 = a2[t];
#pragma unroll
      for (int off = 32; off > 0; off >>= 1) {
        q0 += __shfl_down(q0, off);
        q1 += __shfl_down(q1, off);
        q2 += __shfl_down(q2, off);
      }
      if (l == 0) {
        red[0][wv] = q0;
        red[1][wv] = q1;
        red[2][wv] = q2;
      }
      __syncthreads();
      if (t == 0) wa[768] = red[0][0] + red[0][1] + red[0][2] + red[0][3];
      if (t == 1) wa[769] = red[1][0] + red[1][1] + red[1][2] + red[1][3];
      if (t == 2) wa[770] = red[2][0] + red[2][1] + red[2][2] + red[2][3];
    }
  } else {  // xt16[b,n,c] = fp16(x_in[b,c,n]); 768 blocks
    int s = bid - 608;
    int c0 = (s & 3) * 64, n0 = ((s >> 2) & 3) * 64, b = s >> 4;
    int c = t & 63, r = t >> 6;
#pragma unroll
    for (int i = 0; i < 16; ++i) {
      int ch = c0 + r + i * 4;
      const float* row;
      if (ch < 96) row = x + ((size_t)b * 96 + ch) * NN;
      else if (ch < 192) row = m + ((size_t)b * 96 + (ch - 96)) * NN;
      else row = hid + ((size_t)b * 64 + (ch - 192)) * NN;
      tile[r + i * 4][c] = row[n0 + c];
    }
    __syncthreads();
#pragma unroll
    for (int i = 0; i < 16; ++i) {
      int row = r + i * 4;
      xt[((size_t)b * NN + n0 + row) * CIN + c0 + c] = (_Float16)tile[c][row];
    }
  }
}

// ---------------- k_mid: h16 (768) + M (32) + ns2 (48) ----------------
__global__ __launch_bounds__(256) void k_mid(const _Float16* __restrict__ xt, const _Float16* __restrict__ wt,
                                             const float* __restrict__ bias, _Float16* __restrict__ hThi,
                                             const _Float16* __restrict__ incs, const _Float16* __restrict__ w2t,
                                             _Float16* __restrict__ M16, const float* __restrict__ x,
                                             const float* __restrict__ m, const float* __restrict__ hid,
                                             const float* __restrict__ wa, float* __restrict__ node_sc,
                                             float* __restrict__ g1, float* __restrict__ g2) {
  __shared__ _Float16 smA[128 * 64];
  __shared__ _Float16 smB[64 * 64];
  int bid = blockIdx.x;
  int t = threadIdx.x;
  if (bid < 768) {  // h16
    int xcd = bid & 7, il = bid >> 3;
    int ntile = il & 3, dtile = (il >> 2) & 3, bl = il >> 4;
    int b = xcd * 6 + bl;
    int n0 = ntile * 64, d0 = dtile * 64;
    int w = t >> 6, l = t & 63;
    int wm = w >> 1, wn = w & 1;
    int lr = l & 15;
    const _Float16* A = xt + ((size_t)b * NN + n0) * CIN;
    const _Float16* Bp = wt + (size_t)d0 * CIN;
    int lrow = l >> 3;
    int scol = 8 * ((l & 7) ^ (lrow & 7));
    f32x4 acc[2][2];
    f32x4 z = {0.f, 0.f, 0.f, 0.f};
#pragma unroll
    for (int i = 0; i < 2; ++i)
#pragma unroll
      for (int j = 0; j < 2; ++j) acc[i][j] = z;
    for (int kk = 0; kk < CIN; kk += 64) {
#pragma unroll
      for (int q = 0; q < 2; ++q) {
        int row = q * 32 + w * 8 + lrow;
        int lb = (q * 32 + w * 8) * 64;
        gload16(A + (size_t)row * CIN + kk + scol, smA + lb);
        gload16(Bp + (size_t)row * CIN + kk + scol, smB + lb);
      }
      __syncthreads();
      f16x8 af[2][2], bf[2][2];
#pragma unroll
      for (int i = 0; i < 2; ++i)
#pragma unroll
        for (int ks = 0; ks < 2; ++ks) {
          int ra = wm * 32 + i * 16 + lr;
          af[i][ks] = *(const f16x8*)&smA[ra * 64 + ((ks * 32 + (l >> 4) * 8) ^ ((ra & 7) << 3))];
          int rb = wn * 32 + i * 16 + lr;
          bf[i][ks] = *(const f16x8*)&smB[rb * 64 + ((ks * 32 + (l >> 4) * 8) ^ ((rb & 7) << 3))];
        }
#pragma unroll
      for (int ks = 0; ks < 2; ++ks)
#pragma unroll
        for (int i = 0; i < 2; ++i)
#pragma unroll
          for (int j = 0; j < 2; ++j)
            acc[i][j] = __builtin_amdgcn_mfma_f32_16x16x32_f16(af[i][ks], bf[j][ks], acc[i][j], 0, 0, 0);
      __syncthreads();
    }
#pragma unroll
    for (int i = 0; i < 2; ++i)
#pragma unroll
      for (int j = 0; j < 2; ++j) {
        int nb = n0 + wm * 32 + i * 16 + (l >> 4) * 4;
        int d = d0 + wn * 32 + j * 16 + lr;
        float4 bv = *(const float4*)&bias[nb];
        f16x4 vh;
        vh[0] = (_Float16)(acc[i][j][0] + bv.x);
        vh[1] = (_Float16)(acc[i][j][1] + bv.y);
        vh[2] = (_Float16)(acc[i][j][2] + bv.z);
        vh[3] = (_Float16)(acc[i][j][3] + bv.w);
        *(f16x4*)&hThi[((size_t)b * DD + d) * NN + nb] = vh;
      }
  } else if (bid < 800) {  // M16[e,n] = sum_f incs[n,f]*w2t[e,f]
    int mb = bid - 768;
    int np = mb & 1, ep = mb >> 1;
    int m0 = np * 128, n0 = ep * 64;
    int w = t >> 6, l = t & 63;
    int wm = w >> 1, wn = w & 1;
    int lr = l & 15, lg = l >> 4;
    int srow = l >> 3, sgrp = l & 7;
    int sc = (sgrp ^ srow) * 8;
    const _Float16* A = incs + (size_t)m0 * EE;
    const _Float16* Bp = w2t + (size_t)n0 * EE;
    f32x4 acc[4][2];
    f32x4 z = {0.f, 0.f, 0.f, 0.f};
#pragma unroll
    for (int i = 0; i < 4; ++i)
#pragma unroll
      for (int j = 0; j < 2; ++j) acc[i][j] = z;
    for (int kk = 0; kk < EE; kk += 64) {
#pragma unroll
      for (int q = 0; q < 4; ++q) {
        int c = w * 4 + q;
        int r = c * 8 + srow;
        gload16(A + (size_t)r * EE + kk + sc, smA + c * 512);
      }
#pragma unroll
      for (int q = 0; q < 2; ++q) {
        int c = w * 2 + q;
        int r = c * 8 + srow;
        gload16(Bp + (size_t)r * EE + kk + sc, smB + c * 512);
      }
      __syncthreads();
      f16x8 ah[4][2], bh[2][2];
#pragma unroll
      for (int i = 0; i < 4; ++i) {
        int ra = wm * 64 + i * 16 + lr;
#pragma unroll
        for (int ks = 0; ks < 2; ++ks)
          ah[i][ks] = *(const f16x8*)&smA[ra * 64 + (((ks * 4 + lg) ^ (ra & 7)) * 8)];
      }
#pragma unroll
      for (int j = 0; j < 2; ++j) {
        int rb = wn * 32 + j * 16 + lr;
#pragma unroll
        for (int ks = 0; ks < 2; ++ks)
          bh[j][ks] = *(const f16x8*)&smB[rb * 64 + (((ks * 4 + lg) ^ (rb & 7)) * 8)];
      }
#pragma unroll
      for (int ks = 0; ks < 2; ++ks)
#pragma unroll
        for (int i = 0; i < 4; ++i)
#pragma unroll
          for (int j = 0; j < 2; ++j)
            acc[i][j] = __builtin_amdgcn_mfma_f32_16x16x32_f16(ah[i][ks], bh[j][ks], acc[i][j], 0, 0, 0);
      __syncthreads();
    }
#pragma unroll
    for (int i = 0; i < 4; ++i)
#pragma unroll
      for (int j = 0; j < 2; ++j) {
        int n = m0 + wm * 64 + i * 16 + lg * 4;
        int e = n0 + wn * 32 + j * 16 + lr;
        f16x4 v;
#pragma unroll
        for (int r = 0; r < 4; ++r) v[r] = (_Float16)acc[i][j][r];
        *(f16x4*)&M16[(size_t)e * NN + n] = v;
      }
  } else {  // ns2: b = bid - 800
    float* s0a = (float*)smA;
    float* s1a = s0a + 256;
    float* s2a = s0a + 512;
    int b = bid - 800;
    s0a[t] = wa[t];
    s1a[t] = wa[256 + t];
    s2a[t] = wa[512 + t];
    __syncthreads();
    float s0 = 0.f, s1 = 0.f, s2 = 0.f;
#pragma unroll 4
    for (int c = 0; c < 256; ++c) {
      const float* row;
      if (c < 96) row = x + ((size_t)b * 96 + c) * NN;
      else if (c < 192) row = m + ((size_t)b * 96 + (c - 96)) * NN;
      else row = hid + ((size_t)b * 64 + (c - 192)) * NN;
      float v = row[t];
      s0 += v * s0a[c];
      s1 += v * s1a[c];
      s2 += v * s2a[c];
    }
    float bv = bias[t];
    int idx = b * NN + t;
    node_sc[idx] = s0 + bv * wa[768];
    g1[idx] = s1 + bv * wa[769];
    g2[idx] = s2 + bv * wa[770];
  }
}

// u1[b,f] = invdeg[f]*sum_n incT[f,n]*g1[b,n]; u2 same with g2; deg inline
__global__ __launch_bounds__(256) void k_uu(const _Float16* __restrict__ incT, const float* __restrict__ g1,
                                            const float* __restrict__ g2, float* __restrict__ u1,
                                            float* __restrict__ u2) {
  __shared__ float sg1[NN], sg2[NN];
  __shared__ float r0[4][64], r1[4][64], r2[4][64];
  int b = blockIdx.y;
  int f0 = blockIdx.x * 64;
  int t = threadIdx.x;
  sg1[t] = g1[b * NN + t];
  sg2[t] = g2[b * NN + t];
  __syncthreads();
  int fl = t & 63, ng = t >> 6;
  int f = f0 + fl;
  float s0 = 0.f, s1 = 0.f, s2 = 0.f;
  const _Float16* row = incT + (size_t)f * NN + ng * 64;
  for (int i = 0; i < 64; i += 8) {
    f16x8 ic = *(const f16x8*)&row[i];
#pragma unroll
    for (int j = 0; j < 8; ++j) {
      float icf = (float)ic[j];
      int n = ng * 64 + i + j;
      s0 += icf;
      s1 += icf * sg1[n];
      s2 += icf * sg2[n];
    }
  }
  r0[ng][fl] = s0;
  r1[ng][fl] = s1;
  r2[ng][fl] = s2;
  __syncthreads();
  if (t < 64) {
    float dg = r0[0][t] + r0[1][t] + r0[2][t] + r0[3][t];
    float iv = 1.0f / dg;
    u1[(size_t)b * EE + f0 + t] = (r1[0][t] + r1[1][t] + r1[2][t] + r1[3][t]) * iv;
    u2[(size_t)b * EE + f0 + t] = (r2[0][t] + r2[1][t] + r2[2][t] + r2[3][t]) * iv;
  }
}

// edge_sc / time_e; 6 b per block
__global__ __launch_bounds__(256) void k_esc(const float* __restrict__ W2, const float* __restrict__ u1,
                                             const float* __restrict__ u2, const float* __restrict__ pri_e,
                                             const float* __restrict__ a2, float* __restrict__ edge_sc,
                                             float* __restrict__ time_e) {
  __shared__ float su1[6 * 1024];
  __shared__ float su2[6 * 1024];
  __shared__ float rr[2][4][6][64];
  int e0 = blockIdx.x * 64, b0 = blockIdx.y * 6;
  int t = threadIdx.x;
#pragma unroll
  for (int i = 0; i < 6; ++i) {
    *(float4*)&su1[i * 1024 + t * 4] = *(const float4*)&u1[(size_t)(b0 + i) * EE + t * 4];
    *(float4*)&su2[i * 1024 + t * 4] = *(const float4*)&u2[(size_t)(b0 + i) * EE + t * 4];
  }
  __syncthreads();
  int el = t & 63, fg = t >> 6;
  int e = e0 + el;
  float s1[6] = {}, s2[6] = {};
  for (int i = 0; i < 256; i += 4) {
    int f = fg * 256 + i;
    float w0 = W2[(size_t)f * EE + e];
    float w1 = W2[(size_t)(f + 1) * EE + e];
    float w2v = W2[(size_t)(f + 2) * EE + e];
    float w3 = W2[(size_t)(f + 3) * EE + e];
#pragma unroll
    for (int bl = 0; bl < 6; ++bl) {
      f32x4 va = *(const f32x4*)&su1[bl * 1024 + f];
      f32x4 vb = *(const f32x4*)&su2[bl * 1024 + f];
      s1[bl] += w0 * va[0] + w1 * va[1] + w2v * va[2] + w3 * va[3];
      s2[bl] += w0 * vb[0] + w1 * vb[1] + w2v * vb[2] + w3 * vb[3];
    }
  }
#pragma unroll
  for (int bl = 0; bl < 6; ++bl) {
    rr[0][fg][bl][el] = s1[bl];
    rr[1][fg][bl][el] = s2[bl];
  }
  __syncthreads();
  for (int bl = t >> 6; bl < 6; bl += 4) {
    int ee = t & 63;
    int row = (b0 + bl) * EE + e0 + ee;
    float v1 = rr[0][0][bl][ee] + rr[0][1][bl][ee] + rr[0][2][bl][ee] + rr[0][3][bl][ee];
    float v2 = rr[1][0][bl][ee] + rr[1][1][bl][ee] + rr[1][2][bl][ee] + rr[1][3][bl][ee];
    edge_sc[row] = v1;
    time_e[row] = lrelu(v2 + pri_e[row] * a2[DD]);
  }
}

// softmax stats over n per (b,e)
__global__ __launch_bounds__(256) void k_d3(const _Float16* __restrict__ incT, const float* __restrict__ node_sc,
                                            const float* __restrict__ edge_sc, const float* __restrict__ time_e,
                                            const float* __restrict__ a3, float* __restrict__ rmax,
                                            float* __restrict__ rinv) {
  int t = threadIdx.x;
  int w = t >> 6, l = t & 63;
  int row = blockIdx.x * 4 + w;
  int b = row >> 10;
  int e = row & (EE - 1);
  float a30 = a3[0], a31 = a3[1];
  float esc = edge_sc[row], te = time_e[row];
  float s2v[4];
  bool msk[4];
  float vmax = -3.0e38f;
#pragma unroll
  for (int q = 0; q < 4; ++q) {
    int n = l + q * 64;
    float ic = (float)incT[(size_t)e * NN + n];
    float s1 = lrelu(node_sc[(size_t)b * NN + n] + esc);
    float s2 = lrelu(te * a30 + s1 * a31);
    msk[q] = ic > 0.f;
    s2v[q] = s2;
    if (msk[q]) vmax = fmaxf(vmax, s2);
  }
#pragma unroll
  for (int off = 32; off > 0; off >>= 1) vmax = fmaxf(vmax, __shfl_xor(vmax, off));
  float ss = 0.f;
#pragma unroll
  for (int q = 0; q < 4; ++q)
    if (msk[q]) ss += __expf(s2v[q] - vmax);
#pragma unroll
  for (int off = 32; off > 0; off >>= 1) ss += __shfl_xor(ss, off);
  if (l == 0) {
    rmax[row] = vmax;
    rinv[row] = 1.0f / ss;
  }
}

// out1[b,e,d] = sum_n M16[e,n]*hThi[b,d,n]; 128e x 64d, BK=64; b-pinned XCD; emits out1T16
__global__ __launch_bounds__(256) void k_out1n(const _Float16* __restrict__ M16, const _Float16* __restrict__ hThi,
                                               float* __restrict__ out1, _Float16* __restrict__ out1T) {
  __shared__ _Float16 smA[128 * 64];
  __shared__ _Float16 smB[64 * 64];
  int bid = blockIdx.x;
  int xcd = bid & 7, il = bid >> 3;
  int ep = il & 7, dblk = (il >> 3) & 3, bl = il >> 5;
  int b = xcd * 6 + bl;
  int m0 = ep * 128;
  int n0 = dblk * 64;
  int t = threadIdx.x, w = t >> 6, l = t & 63;
  int wm = w >> 1, wn = w & 1;
  int lr = l & 15, lg = l >> 4;
  int srow = l >> 3, sgrp = l & 7;
  int sc = (sgrp ^ srow) * 8;
  const _Float16* A = M16 + (size_t)m0 * NN;
  const _Float16* Bp = hThi + ((size_t)b * DD + n0) * NN;
  f32x4 acc[4][2];
  f32x4 z = {0.f, 0.f, 0.f, 0.f};
#pragma unroll
  for (int i = 0; i < 4; ++i)
#pragma unroll
    for (int j = 0; j < 2; ++j) acc[i][j] = z;
  for (int kk = 0; kk < NN; kk += 64) {
#pragma unroll
    for (int q = 0; q < 4; ++q) {
      int c = w * 4 + q;
      int r = c * 8 + srow;
      gload16(A + (size_t)r * NN + kk + sc, smA + c * 512);
    }
#pragma unroll
    for (int q = 0; q < 2; ++q) {
      int c = w * 2 + q;
      int r = c * 8 + srow;
      gload16(Bp + (size_t)r * NN + kk + sc, smB + c * 512);
    }
    __syncthreads();
    f16x8 ah[4][2], bh[2][2];
#pragma unroll
    for (int i = 0; i < 4; ++i) {
      int ra = wm * 64 + i * 16 + lr;
#pragma unroll
      for (int ks = 0; ks < 2; ++ks)
        ah[i][ks] = *(const f16x8*)&smA[ra * 64 + (((ks * 4 + lg) ^ (ra & 7)) * 8)];
    }
#pragma unroll
    for (int j = 0; j < 2; ++j) {
      int rb = wn * 32 + j * 16 + lr;
#pragma unroll
      for (int ks = 0; ks < 2; ++ks)
        bh[j][ks] = *(const f16x8*)&smB[rb * 64 + (((ks * 4 + lg) ^ (rb & 7)) * 8)];
    }
#pragma unroll
    for (int ks = 0; ks < 2; ++ks)
#pragma unroll
      for (int i = 0; i < 4; ++i)
#pragma unroll
        for (int j = 0; j < 2; ++j)
          acc[i][j] = __builtin_amdgcn_mfma_f32_16x16x32_f16(ah[i][ks], bh[j][ks], acc[i][j], 0, 0, 0);
    __syncthreads();
  }
#pragma unroll
  for (int i = 0; i < 4; ++i)
#pragma unroll
    for (int j = 0; j < 2; ++j) {
      int e = m0 + wm * 64 + i * 16 + lg * 4;
      int d = n0 + wn * 32 + j * 16 + lr;
      f16x4 v16;
#pragma unroll
      for (int r = 0; r < 4; ++r) {
        out1[((size_t)b * EE + e + r) * DD + d] = acc[i][j][r];
        v16[r] = (_Float16)acc[i][j][r];
      }
      *(f16x4*)&out1T[((size_t)b * DD + d) * EE + e] = v16;
    }
}

// out0[b,d,n] = sum_e att[n,e]*out1T16[d,e]; att computed in-kernel from stats; b-pinned XCD
__global__ __launch_bounds__(256) void k_fg2(const _Float16* __restrict__ out1T, const float* __restrict__ inc,
                                             const float* __restrict__ node_sc, const float* __restrict__ edge_sc,
                                             const float* __restrict__ time_e, const float* __restrict__ rmax,
                                             const float* __restrict__ rinv, const float* __restrict__ a3,
                                             float* __restrict__ out0) {
  __shared__ _Float16 smA[64 * 64];
  __shared__ _Float16 smB[64 * 64];
  __shared__ float sE[4][1024];
  __shared__ float snc[64];
  int bid = blockIdx.x;
  int xcd = bid & 7, il = bid >> 3;
  int ntile = il & 3, dtile = (il >> 2) & 3, bl = il >> 4;
  int b = xcd * 6 + bl;
  int n0 = ntile * 64, d0 = dtile * 64;
  int t = threadIdx.x, w = t >> 6, l = t & 63;
  int wm = w >> 1, wn = w & 1;
  int lr = l & 15;
  float a30 = a3[0], a31 = a3[1];
  {  // stats prologue
    int be = b * EE + t * 4;
    float4 e4 = *(const float4*)&edge_sc[be];
    float4 t4 = *(const float4*)&time_e[be];
    float4 m4 = *(const float4*)&rmax[be];
    float4 r4 = *(const float4*)&rinv[be];
    *(float4*)&sE[0][t * 4] = e4;
    *(float4*)&sE[1][t * 4] = make_float4(t4.x * a30, t4.y * a30, t4.z * a30, t4.w * a30);
    *(float4*)&sE[2][t * 4] = m4;
    *(float4*)&sE[3][t * 4] = r4;
    if (t < 64) snc[t] = node_sc[b * NN + n0 + t];
  }
  const _Float16* Bp = out1T + ((size_t)b * DD + d0) * EE;
  int lrow = l >> 3;
  int scol = 8 * ((l & 7) ^ (lrow & 7));
  int eq = t & 15, nq = t >> 4;  // att mapping: 4 e's x 4 n's per thread
  f32x4 acc[2][2];
  f32x4 z = {0.f, 0.f, 0.f, 0.f};
#pragma unroll
  for (int i = 0; i < 2; ++i)
#pragma unroll
    for (int j = 0; j < 2; ++j) acc[i][j] = z;
  __syncthreads();  // sE/snc visible
  for (int kk = 0; kk < EE; kk += 64) {
#pragma unroll
    for (int q = 0; q < 2; ++q) {  // stage B
      int row = q * 32 + w * 8 + lrow;
      int lb = (q * 32 + w * 8) * 64;
      gload16(Bp + (size_t)row * EE + kk + scol, smB + lb);
    }
    {  // compute att tile -> smA (swizzled layout)
      int e0 = eq * 4;
      f32x4 esc = *(const f32x4*)&sE[0][kk + e0];
      f32x4 tea = *(const f32x4*)&sE[1][kk + e0];
      f32x4 rmx = *(const f32x4*)&sE[2][kk + e0];
      f32x4 riv = *(const f32x4*)&sE[3][kk + e0];
#pragma unroll
      for (int i = 0; i < 4; ++i) {
        int n = nq * 4 + i;
        float ns = snc[n];
        float4 icv = *(const float4*)&inc[(size_t)(n0 + n) * EE + kk + e0];
        float ica[4] = {icv.x, icv.y, icv.z, icv.w};
        f16x4 o;
#pragma unroll
        for (int q = 0; q < 4; ++q) {
          float att = 0.f;
          if (ica[q] > 0.f) {
            float s1 = lrelu(ns + esc[q]);
            float s2 = lrelu(tea[q] + s1 * a31);
            att = __expf(s2 - rmx[q]) * riv[q];
          }
          o[q] = (_Float16)att;
        }
        int addr = n * 64 + (((e0 & ~7) ^ ((n & 7) << 3)) | (e0 & 7));
        *(f16x4*)&smA[addr] = o;
      }
    }
    __syncthreads();
    f16x8 af[2][2], bf[2][2];
#pragma unroll
    for (int i = 0; i < 2; ++i)
#pragma unroll
      for (int ks = 0; ks < 2; ++ks) {
        int ra = wm * 32 + i * 16 + lr;
        af[i][ks] = *(const f16x8*)&smA[ra * 64 + ((ks * 32 + (l >> 4) * 8) ^ ((ra & 7) << 3))];
        int rb = wn * 32 + i * 16 + lr;
        bf[i][ks] = *(const f16x8*)&smB[rb * 64 + ((ks * 32 + (l >> 4) * 8) ^ ((rb & 7) << 3))];
      }
#pragma unroll
    for (int ks = 0; ks < 2; ++ks)
#pragma unroll
      for (int i = 0; i < 2; ++i)
#pragma unroll
        for (int j = 0; j < 2; ++j)
          acc[i][j] = __builtin_amdgcn_mfma_f32_16x16x32_f16(af[i][ks], bf[j][ks], acc[i][j], 0, 0, 0);
    __syncthreads();
  }
  float* ob = out0 + (size_t)b * DD * NN;
#pragma unroll
  for (int i = 0; i < 2; ++i)
#pragma unroll
    for (int j = 0; j < 2; ++j) {
      int n = n0 + wm * 32 + i * 16 + (l >> 4) * 4;
      int d = d0 + wn * 32 + j * 16 + lr;
      *(float4*)&ob[(size_t)d * NN + n] =
          make_float4(acc[i][j][0], acc[i][j][1], acc[i][j][2], acc[i][j][3]);
    }
}

extern "C" void kernel_launch(void* const* d_in, const int* in_sizes, int n_in, void* d_out, int out_size,
                              void* d_ws, size_t ws_size, hipStream_t stream) {
  (void)in_sizes;
  (void)n_in;
  (void)out_size;
  (void)ws_size;
  const float* x = (const float*)d_in[0];
  const float* m = (const float*)d_in[1];
  const float* hid = (const float*)d_in[2];
  const float* pri_e = (const float*)d_in[3];
  const float* inc = (const float*)d_in[5];
  const float* W = (const float*)d_in[6];
  const float* bias = (const float*)d_in[7];
  const float* W2 = (const float*)d_in[8];
  const float* a = (const float*)d_in[9];
  const float* a2 = (const float*)d_in[10];
  const float* a3 = (const float*)d_in[11];

  float* out0 = (float*)d_out;                // [B,D,N]
  float* out1 = out0 + (size_t)BB * DD * NN;  // [B,E,D] fp32 (written by k_out1n)
  _Float16* xt16 = (_Float16*)out1;           // [B,N,CIN] fp16 — dead after k_mid, before out1 written

  _Float16* out1T16 = (_Float16*)d_ws;                 // [B,D,E]
  _Float16* hThi = out1T16 + (size_t)BB * DD * EE;     // [B,D,N]
  _Float16* incT = hThi + (size_t)BB * DD * NN;        // [E,N]
  _Float16* w2thi = incT + (size_t)EE * NN;            // [E,E]
  _Float16* incs16 = w2thi + (size_t)EE * EE;          // [N,E]
  _Float16* M16 = incs16 + (size_t)NN * EE;            // [E,N]
  _Float16* wt16 = M16 + (size_t)EE * NN;              // [D,CIN]
  float* node_sc = (float*)(wt16 + (size_t)DD * CIN);  // B*N
  float* g1 = node_sc + (size_t)BB * NN;               // B*N
  float* g2 = g1 + (size_t)BB * NN;                    // B*N
  float* edge_sc = g2 + (size_t)BB * NN;               // B*E
  float* time_e = edge_sc + (size_t)BB * EE;           // B*E
  float* rmax = time_e + (size_t)BB * EE;              // B*E
  float* rinv = rmax + (size_t)BB * EE;                // B*E
  float* u1 = rinv + (size_t)BB * EE;                  // B*E
  float* u2 = u1 + (size_t)BB * EE;                    // B*E
  float* wa = u2 + (size_t)BB * EE;                    // 1024

  k_prep<<<dim3(1376), 256, 0, stream>>>(inc, W2, W, x, m, hid, a, a2, incT, w2thi, wt16, incs16, wa, xt16);
  k_mid<<<dim3(848), 256, 0, stream>>>(xt16, wt16, bias, hThi, incs16, w2thi, M16, x, m, hid, wa, node_sc, g1, g2);
  k_uu<<<dim3(EE / 64, BB), 256, 0, stream>>>(incT, g1, g2, u1, u2);
  k_esc<<<dim3(EE / 64, BB / 6), 256, 0, stream>>>(W2, u1, u2, pri_e, a2, edge_sc, time_e);
  k_d3<<<dim3((BB * EE) / 4), 256, 0, stream>>>(incT, node_sc, edge_sc, time_e, a3, rmax, rinv);
  k_out1n<<<dim3(8 * 192), 256, 0, stream>>>(M16, hThi, out1, out1T16);
  k_fg2<<<dim3(8 * 96), 256, 0, stream>>>(out1T16, inc, node_sc, edge_sc, time_e, rmax, rinv, a3, out0);
}

// Round 11
// 134.630 us; speedup vs baseline: 1.4946x; 1.1532x over previous
//
#include <hip/hip_runtime.h>

#define BB 48
#define NN 256
#define EE 1024
#define DD 256
#define CIN 256

typedef __attribute__((ext_vector_type(4))) float f32x4;
typedef __attribute__((ext_vector_type(8))) _Float16 f16x8;
typedef __attribute__((ext_vector_type(4))) _Float16 f16x4;

__device__ __forceinline__ float lrelu(float t) { return t >= 0.0f ? t : 0.2f * t; }

__device__ __forceinline__ void gload16(const void* g, void* l) {
  __builtin_amdgcn_global_load_lds((const __attribute__((address_space(1))) void*)g,
                                   (__attribute__((address_space(3))) void*)l, 16, 0, 0);
}

// ---- k_prep: w2s hi/lo, incT, wt16, inc16, wa, xt (all input-only) ----
__global__ __launch_bounds__(256) void k_prep(const float* __restrict__ inc, const float* __restrict__ W2,
                                              const float* __restrict__ W, const float* __restrict__ x,
                                              const float* __restrict__ m, const float* __restrict__ hid,
                                              const float* __restrict__ a, const float* __restrict__ a2,
                                              _Float16* __restrict__ incT, _Float16* __restrict__ w2shi,
                                              _Float16* __restrict__ w2slo, _Float16* __restrict__ wt16,
                                              _Float16* __restrict__ inc16, float* __restrict__ wa,
                                              _Float16* __restrict__ xt) {
  __shared__ float tile[64][65];
  __shared__ float aux[4][64];
  __shared__ float aux2[64];
  int bid = blockIdx.x;
  int t = threadIdx.x;
  if (bid < 256) {  // w2s[e,f] = W2[f,e]*invdeg[f], hi/lo fp16 split
    int f0 = (bid & 15) * 64, e0 = (bid >> 4) * 64;
    int c = t & 63, r = t >> 6;
    {  // invdeg[f0..f0+63] (redundant per e0-panel)
      float s = 0.f;
      for (int i = 0; i < 64; ++i) s += inc[(size_t)(r * 64 + i) * EE + f0 + c];
      aux[r][c] = s;
    }
#pragma unroll
    for (int i = 0; i < 16; ++i) tile[r + i * 4][c] = W2[(size_t)(f0 + r + i * 4) * EE + e0 + c];
    __syncthreads();
    if (t < 64) aux2[t] = 1.0f / (aux[0][t] + aux[1][t] + aux[2][t] + aux[3][t]);
    __syncthreads();
#pragma unroll
    for (int i = 0; i < 16; ++i) {
      int row = r + i * 4;  // e-rel
      float v = tile[c][row] * aux2[c];  // W2[f0+c][e0+row] * invdeg[f0+c]
      _Float16 hh = (_Float16)v;
      w2shi[(size_t)(e0 + row) * EE + f0 + c] = hh;
      w2slo[(size_t)(e0 + row) * EE + f0 + c] = (_Float16)(v - (float)hh);
    }
  } else if (bid < 320) {  // incT[e,n] = inc[n,e]
    int s = bid - 256;
    int e0 = (s & 15) * 64, n0 = (s >> 4) * 64;
    int c = t & 63, r = t >> 6;
#pragma unroll
    for (int i = 0; i < 16; ++i) tile[r + i * 4][c] = inc[(size_t)(n0 + r + i * 4) * EE + e0 + c];
    __syncthreads();
#pragma unroll
    for (int i = 0; i < 16; ++i) {
      int row = r + i * 4;
      incT[(size_t)(e0 + row) * NN + n0 + c] = (_Float16)tile[c][row];
    }
  } else if (bid < 336) {  // wt16[d,c] = fp16(W[c,d])
    int s = bid - 320;
    int c0 = (s & 3) * 64, d0 = (s >> 2) * 64;
    int c = t & 63, r = t >> 6;
#pragma unroll
    for (int i = 0; i < 16; ++i) tile[r + i * 4][c] = W[(size_t)(c0 + r + i * 4) * DD + d0 + c];
    __syncthreads();
#pragma unroll
    for (int i = 0; i < 16; ++i) {
      int row = r + i * 4;
      wt16[(size_t)(d0 + row) * CIN + c0 + c] = (_Float16)tile[c][row];
    }
  } else if (bid < 352) {  // inc16[n,f] = fp16(inc) (exact 0/1)
    int s = bid - 336;
    size_t base = ((size_t)s * 256 + t) * 64;
#pragma unroll
    for (int i = 0; i < 16; ++i) {
      f32x4 v = *(const f32x4*)&inc[base + i * 4];
      f16x4 o;
      o[0] = (_Float16)v[0];
      o[1] = (_Float16)v[1];
      o[2] = (_Float16)v[2];
      o[3] = (_Float16)v[3];
      *(f16x4*)&inc16[base + i * 4] = o;
    }
  } else if (bid < 608) {  // wa
    float(*red)[4] = (float(*)[4])aux;
    int c = bid - 352;
    int l = t & 63, wv = t >> 6;
    float w = W[(size_t)c * DD + t];
    float p0 = w * a[t], p1 = w * a[DD + t], p2 = w * a2[t];
#pragma unroll
    for (int off = 32; off > 0; off >>= 1) {
      p0 += __shfl_down(p0, off);
      p1 += __shfl_down(p1, off);
      p2 += __shfl_down(p2, off);
    }
    if (l == 0) {
      red[0][wv] = p0;
      red[1][wv] = p1;
      red[2][wv] = p2;
    }
    __syncthreads();
    if (t == 0) wa[c] = red[0][0] + red[0][1] + red[0][2] + red[0][3];
    if (t == 1) wa[256 + c] = red[1][0] + red[1][1] + red[1][2] + red[1][3];
    if (t == 2) wa[512 + c] = red[2][0] + red[2][1] + red[2][2] + red[2][3];
    if (c == 0) {
      __syncthreads();
      float q0 = a[t], q1 = a[DD + t], q2 = a2[t];
#pragma unroll
      for (int off = 32; off > 0; off >>= 1) {
        q0 += __shfl_down(q0, off);
        q1 += __shfl_down(q1, off);
        q2 += __shfl_down(q2, off);
      }
      if (l == 0) {
        red[0][wv] = q0;
        red[1][wv] = q1;
        red[2][wv] = q2;
      }
      __syncthreads();
      if (t == 0) wa[768] = red[0][0] + red[0][1] + red[0][2] + red[0][3];
      if (t == 1) wa[769] = red[1][0] + red[1][1] + red[1][2] + red[1][3];
      if (t == 2) wa[770] = red[2][0] + red[2][1] + red[2][2] + red[2][3];
    }
  } else {  // xt16[b,n,c] = fp16(x_in[b,c,n]); 768 blocks
    int s = bid - 608;
    int c0 = (s & 3) * 64, n0 = ((s >> 2) & 3) * 64, b = s >> 4;
    int c = t & 63, r = t >> 6;
#pragma unroll
    for (int i = 0; i < 16; ++i) {
      int ch = c0 + r + i * 4;
      const float* row;
      if (ch < 96) row = x + ((size_t)b * 96 + ch) * NN;
      else if (ch < 192) row = m + ((size_t)b * 96 + (ch - 96)) * NN;
      else row = hid + ((size_t)b * 64 + (ch - 192)) * NN;
      tile[r + i * 4][c] = row[n0 + c];
    }
    __syncthreads();
#pragma unroll
    for (int i = 0; i < 16; ++i) {
      int row = r + i * 4;
      xt[((size_t)b * NN + n0 + row) * CIN + c0 + c] = (_Float16)tile[c][row];
    }
  }
}

// ---- k_mid: h16 (768) + M32/M16 2-term split MFMA (64) + ns2 (48) ----
__global__ __launch_bounds__(256) void k_mid(const _Float16* __restrict__ xt, const _Float16* __restrict__ wt,
                                             const float* __restrict__ bias, _Float16* __restrict__ hThi,
                                             const _Float16* __restrict__ inc16, const _Float16* __restrict__ w2shi,
                                             const _Float16* __restrict__ w2slo, float* __restrict__ M32,
                                             _Float16* __restrict__ M16, const float* __restrict__ x,
                                             const float* __restrict__ m, const float* __restrict__ hid,
                                             const float* __restrict__ wa, float* __restrict__ node_sc,
                                             float* __restrict__ g1, float* __restrict__ g2) {
  __shared__ _Float16 smA[64 * 64];
  __shared__ _Float16 smB[64 * 64];
  __shared__ _Float16 smB2[64 * 64];
  int bid = blockIdx.x;
  int t = threadIdx.x;
  if (bid < 768) {  // h16
    int xcd = bid & 7, il = bid >> 3;
    int ntile = il & 3, dtile = (il >> 2) & 3, bl = il >> 4;
    int b = xcd * 6 + bl;
    int n0 = ntile * 64, d0 = dtile * 64;
    int w = t >> 6, l = t & 63;
    int wm = w >> 1, wn = w & 1;
    int lr = l & 15;
    const _Float16* A = xt + ((size_t)b * NN + n0) * CIN;
    const _Float16* Bp = wt + (size_t)d0 * CIN;
    int lrow = l >> 3;
    int scol = 8 * ((l & 7) ^ (lrow & 7));
    f32x4 acc[2][2];
    f32x4 z = {0.f, 0.f, 0.f, 0.f};
#pragma unroll
    for (int i = 0; i < 2; ++i)
#pragma unroll
      for (int j = 0; j < 2; ++j) acc[i][j] = z;
    for (int kk = 0; kk < CIN; kk += 64) {
#pragma unroll
      for (int q = 0; q < 2; ++q) {
        int row = q * 32 + w * 8 + lrow;
        int lb = (q * 32 + w * 8) * 64;
        gload16(A + (size_t)row * CIN + kk + scol, smA + lb);
        gload16(Bp + (size_t)row * CIN + kk + scol, smB + lb);
      }
      __syncthreads();
      f16x8 af[2][2], bf[2][2];
#pragma unroll
      for (int i = 0; i < 2; ++i)
#pragma unroll
        for (int ks = 0; ks < 2; ++ks) {
          int ra = wm * 32 + i * 16 + lr;
          af[i][ks] = *(const f16x8*)&smA[ra * 64 + ((ks * 32 + (l >> 4) * 8) ^ ((ra & 7) << 3))];
          int rb = wn * 32 + i * 16 + lr;
          bf[i][ks] = *(const f16x8*)&smB[rb * 64 + ((ks * 32 + (l >> 4) * 8) ^ ((rb & 7) << 3))];
        }
#pragma unroll
      for (int ks = 0; ks < 2; ++ks)
#pragma unroll
        for (int i = 0; i < 2; ++i)
#pragma unroll
          for (int j = 0; j < 2; ++j)
            acc[i][j] = __builtin_amdgcn_mfma_f32_16x16x32_f16(af[i][ks], bf[j][ks], acc[i][j], 0, 0, 0);
      __syncthreads();
    }
#pragma unroll
    for (int i = 0; i < 2; ++i)
#pragma unroll
      for (int j = 0; j < 2; ++j) {
        int nb = n0 + wm * 32 + i * 16 + (l >> 4) * 4;
        int d = d0 + wn * 32 + j * 16 + lr;
        float4 bv = *(const float4*)&bias[nb];
        f16x4 vh;
        vh[0] = (_Float16)(acc[i][j][0] + bv.x);
        vh[1] = (_Float16)(acc[i][j][1] + bv.y);
        vh[2] = (_Float16)(acc[i][j][2] + bv.z);
        vh[3] = (_Float16)(acc[i][j][3] + bv.w);
        *(f16x4*)&hThi[((size_t)b * DD + d) * NN + nb] = vh;
      }
  } else if (bid < 832) {  // M32/M16[e,n] = sum_f inc16[n,f]*(w2shi+w2slo)[e,f]; 64 blocks
    int mb = bid - 768;
    int np = mb & 3, ep = mb >> 2;
    int m0 = np * 64;  // n rows
    int n0 = ep * 64;  // e cols
    int w = t >> 6, l = t & 63;
    int wm = w >> 1, wn = w & 1;
    int lr = l & 15;
    const _Float16* A = inc16 + (size_t)m0 * EE;
    const _Float16* Bh = w2shi + (size_t)n0 * EE;
    const _Float16* Bl = w2slo + (size_t)n0 * EE;
    int lrow = l >> 3;
    int scol = 8 * ((l & 7) ^ (lrow & 7));
    f32x4 acc[2][2];
    f32x4 z = {0.f, 0.f, 0.f, 0.f};
#pragma unroll
    for (int i = 0; i < 2; ++i)
#pragma unroll
      for (int j = 0; j < 2; ++j) acc[i][j] = z;
    for (int kk = 0; kk < EE; kk += 64) {
#pragma unroll
      for (int q = 0; q < 2; ++q) {
        int row = q * 32 + w * 8 + lrow;
        int lb = (q * 32 + w * 8) * 64;
        gload16(A + (size_t)row * EE + kk + scol, smA + lb);
        gload16(Bh + (size_t)row * EE + kk + scol, smB + lb);
        gload16(Bl + (size_t)row * EE + kk + scol, smB2 + lb);
      }
      __syncthreads();
      f16x8 af[2][2], bfh[2][2], bfl[2][2];
#pragma unroll
      for (int i = 0; i < 2; ++i)
#pragma unroll
        for (int ks = 0; ks < 2; ++ks) {
          int ra = wm * 32 + i * 16 + lr;
          int off_a = ra * 64 + ((ks * 32 + (l >> 4) * 8) ^ ((ra & 7) << 3));
          af[i][ks] = *(const f16x8*)&smA[off_a];
          int rb = wn * 32 + i * 16 + lr;
          int off_b = rb * 64 + ((ks * 32 + (l >> 4) * 8) ^ ((rb & 7) << 3));
          bfh[i][ks] = *(const f16x8*)&smB[off_b];
          bfl[i][ks] = *(const f16x8*)&smB2[off_b];
        }
#pragma unroll
      for (int ks = 0; ks < 2; ++ks)
#pragma unroll
        for (int i = 0; i < 2; ++i)
#pragma unroll
          for (int j = 0; j < 2; ++j) {
            acc[i][j] = __builtin_amdgcn_mfma_f32_16x16x32_f16(af[i][ks], bfh[j][ks], acc[i][j], 0, 0, 0);
            acc[i][j] = __builtin_amdgcn_mfma_f32_16x16x32_f16(af[i][ks], bfl[j][ks], acc[i][j], 0, 0, 0);
          }
      __syncthreads();
    }
#pragma unroll
    for (int i = 0; i < 2; ++i)
#pragma unroll
      for (int j = 0; j < 2; ++j) {
        int n = m0 + wm * 32 + i * 16 + (l >> 4) * 4;
        int e = n0 + wn * 32 + j * 16 + lr;
        *(f32x4*)&M32[(size_t)e * NN + n] = acc[i][j];
        f16x4 v;
#pragma unroll
        for (int r = 0; r < 4; ++r) v[r] = (_Float16)acc[i][j][r];
        *(f16x4*)&M16[(size_t)e * NN + n] = v;
      }
  } else {  // ns2: b = bid - 832
    float* s0a = (float*)smA;
    float* s1a = s0a + 256;
    float* s2a = s0a + 512;
    int b = bid - 832;
    s0a[t] = wa[t];
    s1a[t] = wa[256 + t];
    s2a[t] = wa[512 + t];
    __syncthreads();
    float s0 = 0.f, s1 = 0.f, s2 = 0.f;
#pragma unroll 4
    for (int c = 0; c < 256; ++c) {
      const float* row;
      if (c < 96) row = x + ((size_t)b * 96 + c) * NN;
      else if (c < 192) row = m + ((size_t)b * 96 + (c - 96)) * NN;
      else row = hid + ((size_t)b * 64 + (c - 192)) * NN;
      float v = row[t];
      s0 += v * s0a[c];
      s1 += v * s1a[c];
      s2 += v * s2a[c];
    }
    float bv = bias[t];
    int idx = b * NN + t;
    node_sc[idx] = s0 + bv * wa[768];
    g1[idx] = s1 + bv * wa[769];
    g2[idx] = s2 + bv * wa[770];
  }
}

// ---- k_score: edge_sc/time_e from M32 (fp32-exact), then masked softmax stats ----
__global__ __launch_bounds__(256) void k_score(const float* __restrict__ M32, const float* __restrict__ g1,
                                               const float* __restrict__ g2, const float* __restrict__ node_sc,
                                               const float* __restrict__ pri_e, const float* __restrict__ a2,
                                               const float* __restrict__ a3, const _Float16* __restrict__ incT,
                                               float* __restrict__ edge_sc, float* __restrict__ time_e,
                                               float* __restrict__ rmax, float* __restrict__ rinv) {
  __shared__ float sg1[NN], sg2[NN], snc[NN];
  __shared__ float r1[64][4], r2[64][4];
  __shared__ float sesc[64], steA[64];
  int e0 = blockIdx.x * 64, b = blockIdx.y;
  int t = threadIdx.x;
  float a30 = a3[0], a31 = a3[1];
  sg1[t] = g1[b * NN + t];
  sg2[t] = g2[b * NN + t];
  snc[t] = node_sc[b * NN + t];
  __syncthreads();
  {  // phase 1: esc/te for 64 e's
    int ei = t >> 2, part = t & 3;
    const float* Mr = M32 + (size_t)(e0 + ei) * NN + part * 64;
    const float* pg1 = sg1 + part * 64;
    const float* pg2 = sg2 + part * 64;
    float s1 = 0.f, s2 = 0.f;
    for (int i = 0; i < 64; i += 4) {
      f32x4 mv = *(const f32x4*)&Mr[i];
      f32x4 v1 = *(const f32x4*)&pg1[i];
      f32x4 v2 = *(const f32x4*)&pg2[i];
      s1 += mv[0] * v1[0] + mv[1] * v1[1] + mv[2] * v1[2] + mv[3] * v1[3];
      s2 += mv[0] * v2[0] + mv[1] * v2[1] + mv[2] * v2[2] + mv[3] * v2[3];
    }
    r1[ei][part] = s1;
    r2[ei][part] = s2;
  }
  __syncthreads();
  if (t < 64) {
    int row = b * EE + e0 + t;
    float es = r1[t][0] + r1[t][1] + r1[t][2] + r1[t][3];
    float te = lrelu(r2[t][0] + r2[t][1] + r2[t][2] + r2[t][3] + pri_e[row] * a2[DD]);
    edge_sc[row] = es;
    time_e[row] = te;
    sesc[t] = es;
    steA[t] = te * a30;
  }
  __syncthreads();
  // phase 2: wave-per-row masked max + exp-sum (d3 logic)
  int w = t >> 6, l = t & 63;
  for (int rr = 0; rr < 16; ++rr) {
    int er = w * 16 + rr;
    int e = e0 + er;
    float es = sesc[er], ta = steA[er];
    f16x4 ic = *(const f16x4*)&incT[(size_t)e * NN + l * 4];
    float s2v[4];
    bool msk[4];
    float vmax = -3.0e38f;
#pragma unroll
    for (int q = 0; q < 4; ++q) {
      float s1 = lrelu(snc[l * 4 + q] + es);
      float s2 = lrelu(ta + s1 * a31);
      msk[q] = (float)ic[q] > 0.f;
      s2v[q] = s2;
      if (msk[q]) vmax = fmaxf(vmax, s2);
    }
#pragma unroll
    for (int off = 32; off > 0; off >>= 1) vmax = fmaxf(vmax, __shfl_xor(vmax, off));
    float ss = 0.f;
#pragma unroll
    for (int q = 0; q < 4; ++q)
      if (msk[q]) ss += __expf(s2v[q] - vmax);
#pragma unroll
    for (int off = 32; off > 0; off >>= 1) ss += __shfl_xor(ss, off);
    if (l == 0) {
      int row = b * EE + e;
      rmax[row] = vmax;
      rinv[row] = 1.0f / ss;
    }
  }
}

// out1[b,e,d] = sum_n M16[e,n]*hThi[b,d,n]; 128e x 64d, BK=64; b-pinned XCD; emits out1T16
__global__ __launch_bounds__(256) void k_out1n(const _Float16* __restrict__ M16, const _Float16* __restrict__ hThi,
                                               float* __restrict__ out1, _Float16* __restrict__ out1T) {
  __shared__ _Float16 smA[128 * 64];
  __shared__ _Float16 smB[64 * 64];
  int bid = blockIdx.x;
  int xcd = bid & 7, il = bid >> 3;
  int ep = il & 7, dblk = (il >> 3) & 3, bl = il >> 5;
  int b = xcd * 6 + bl;
  int m0 = ep * 128;
  int n0 = dblk * 64;
  int t = threadIdx.x, w = t >> 6, l = t & 63;
  int wm = w >> 1, wn = w & 1;
  int lr = l & 15, lg = l >> 4;
  int srow = l >> 3, sgrp = l & 7;
  int sc = (sgrp ^ srow) * 8;
  const _Float16* A = M16 + (size_t)m0 * NN;
  const _Float16* Bp = hThi + ((size_t)b * DD + n0) * NN;
  f32x4 acc[4][2];
  f32x4 z = {0.f, 0.f, 0.f, 0.f};
#pragma unroll
  for (int i = 0; i < 4; ++i)
#pragma unroll
    for (int j = 0; j < 2; ++j) acc[i][j] = z;
  for (int kk = 0; kk < NN; kk += 64) {
#pragma unroll
    for (int q = 0; q < 4; ++q) {
      int c = w * 4 + q;
      int r = c * 8 + srow;
      gload16(A + (size_t)r * NN + kk + sc, smA + c * 512);
    }
#pragma unroll
    for (int q = 0; q < 2; ++q) {
      int c = w * 2 + q;
      int r = c * 8 + srow;
      gload16(Bp + (size_t)r * NN + kk + sc, smB + c * 512);
    }
    __syncthreads();
    f16x8 ah[4][2], bh[2][2];
#pragma unroll
    for (int i = 0; i < 4; ++i) {
      int ra = wm * 64 + i * 16 + lr;
#pragma unroll
      for (int ks = 0; ks < 2; ++ks)
        ah[i][ks] = *(const f16x8*)&smA[ra * 64 + (((ks * 4 + lg) ^ (ra & 7)) * 8)];
    }
#pragma unroll
    for (int j = 0; j < 2; ++j) {
      int rb = wn * 32 + j * 16 + lr;
#pragma unroll
      for (int ks = 0; ks < 2; ++ks)
        bh[j][ks] = *(const f16x8*)&smB[rb * 64 + (((ks * 4 + lg) ^ (rb & 7)) * 8)];
    }
#pragma unroll
    for (int ks = 0; ks < 2; ++ks)
#pragma unroll
      for (int i = 0; i < 4; ++i)
#pragma unroll
        for (int j = 0; j < 2; ++j)
          acc[i][j] = __builtin_amdgcn_mfma_f32_16x16x32_f16(ah[i][ks], bh[j][ks], acc[i][j], 0, 0, 0);
    __syncthreads();
  }
#pragma unroll
  for (int i = 0; i < 4; ++i)
#pragma unroll
    for (int j = 0; j < 2; ++j) {
      int e = m0 + wm * 64 + i * 16 + lg * 4;
      int d = n0 + wn * 32 + j * 16 + lr;
      f16x4 v16;
#pragma unroll
      for (int r = 0; r < 4; ++r) {
        out1[((size_t)b * EE + e + r) * DD + d] = acc[i][j][r];
        v16[r] = (_Float16)acc[i][j][r];
      }
      *(f16x4*)&out1T[((size_t)b * DD + d) * EE + e] = v16;
    }
}

// out0[b,d,n] = sum_e att[n,e]*out1T16[d,e]; att computed in-kernel; b-pinned XCD
__global__ __launch_bounds__(256) void k_fg2(const _Float16* __restrict__ out1T, const float* __restrict__ inc,
                                             const float* __restrict__ node_sc, const float* __restrict__ edge_sc,
                                             const float* __restrict__ time_e, const float* __restrict__ rmax,
                                             const float* __restrict__ rinv, const float* __restrict__ a3,
                                             float* __restrict__ out0) {
  __shared__ _Float16 smA[64 * 64];
  __shared__ _Float16 smB[64 * 64];
  __shared__ float sE[4][1024];
  __shared__ float snc[64];
  int bid = blockIdx.x;
  int xcd = bid & 7, il = bid >> 3;
  int ntile = il & 3, dtile = (il >> 2) & 3, bl = il >> 4;
  int b = xcd * 6 + bl;
  int n0 = ntile * 64, d0 = dtile * 64;
  int t = threadIdx.x, w = t >> 6, l = t & 63;
  int wm = w >> 1, wn = w & 1;
  int lr = l & 15;
  float a30 = a3[0], a31 = a3[1];
  {
    int be = b * EE + t * 4;
    float4 e4 = *(const float4*)&edge_sc[be];
    float4 t4 = *(const float4*)&time_e[be];
    float4 m4 = *(const float4*)&rmax[be];
    float4 r4 = *(const float4*)&rinv[be];
    *(float4*)&sE[0][t * 4] = e4;
    *(float4*)&sE[1][t * 4] = make_float4(t4.x * a30, t4.y * a30, t4.z * a30, t4.w * a30);
    *(float4*)&sE[2][t * 4] = m4;
    *(float4*)&sE[3][t * 4] = r4;
    if (t < 64) snc[t] = node_sc[b * NN + n0 + t];
  }
  const _Float16* Bp = out1T + ((size_t)b * DD + d0) * EE;
  int lrow = l >> 3;
  int scol = 8 * ((l & 7) ^ (lrow & 7));
  int eq = t & 15, nq = t >> 4;
  f32x4 acc[2][2];
  f32x4 z = {0.f, 0.f, 0.f, 0.f};
#pragma unroll
  for (int i = 0; i < 2; ++i)
#pragma unroll
    for (int j = 0; j < 2; ++j) acc[i][j] = z;
  __syncthreads();
  for (int kk = 0; kk < EE; kk += 64) {
#pragma unroll
    for (int q = 0; q < 2; ++q) {
      int row = q * 32 + w * 8 + lrow;
      int lb = (q * 32 + w * 8) * 64;
      gload16(Bp + (size_t)row * EE + kk + scol, smB + lb);
    }
    {
      int e0 = eq * 4;
      f32x4 esc = *(const f32x4*)&sE[0][kk + e0];
      f32x4 tea = *(const f32x4*)&sE[1][kk + e0];
      f32x4 rmx = *(const f32x4*)&sE[2][kk + e0];
      f32x4 riv = *(const f32x4*)&sE[3][kk + e0];
#pragma unroll
      for (int i = 0; i < 4; ++i) {
        int n = nq * 4 + i;
        float ns = snc[n];
        float4 icv = *(const float4*)&inc[(size_t)(n0 + n) * EE + kk + e0];
        float ica[4] = {icv.x, icv.y, icv.z, icv.w};
        f16x4 o;
#pragma unroll
        for (int q = 0; q < 4; ++q) {
          float att = 0.f;
          if (ica[q] > 0.f) {
            float s1 = lrelu(ns + esc[q]);
            float s2 = lrelu(tea[q] + s1 * a31);
            att = __expf(s2 - rmx[q]) * riv[q];
          }
          o[q] = (_Float16)att;
        }
        int addr = n * 64 + (((e0 & ~7) ^ ((n & 7) << 3)) | (e0 & 7));
        *(f16x4*)&smA[addr] = o;
      }
    }
    __syncthreads();
    f16x8 af[2][2], bf[2][2];
#pragma unroll
    for (int i = 0; i < 2; ++i)
#pragma unroll
      for (int ks = 0; ks < 2; ++ks) {
        int ra = wm * 32 + i * 16 + lr;
        af[i][ks] = *(const f16x8*)&smA[ra * 64 + ((ks * 32 + (l >> 4) * 8) ^ ((ra & 7) << 3))];
        int rb = wn * 32 + i * 16 + lr;
        bf[i][ks] = *(const f16x8*)&smB[rb * 64 + ((ks * 32 + (l >> 4) * 8) ^ ((rb & 7) << 3))];
      }
#pragma unroll
    for (int ks = 0; ks < 2; ++ks)
#pragma unroll
      for (int i = 0; i < 2; ++i)
#pragma unroll
        for (int j = 0; j < 2; ++j)
          acc[i][j] = __builtin_amdgcn_mfma_f32_16x16x32_f16(af[i][ks], bf[j][ks], acc[i][j], 0, 0, 0);
    __syncthreads();
  }
  float* ob = out0 + (size_t)b * DD * NN;
#pragma unroll
  for (int i = 0; i < 2; ++i)
#pragma unroll
    for (int j = 0; j < 2; ++j) {
      int n = n0 + wm * 32 + i * 16 + (l >> 4) * 4;
      int d = d0 + wn * 32 + j * 16 + lr;
      *(float4*)&ob[(size_t)d * NN + n] =
          make_float4(acc[i][j][0], acc[i][j][1], acc[i][j][2], acc[i][j][3]);
    }
}

extern "C" void kernel_launch(void* const* d_in, const int* in_sizes, int n_in, void* d_out, int out_size,
                              void* d_ws, size_t ws_size, hipStream_t stream) {
  (void)in_sizes;
  (void)n_in;
  (void)out_size;
  (void)ws_size;
  const float* x = (const float*)d_in[0];
  const float* m = (const float*)d_in[1];
  const float* hid = (const float*)d_in[2];
  const float* pri_e = (const float*)d_in[3];
  const float* inc = (const float*)d_in[5];
  const float* W = (const float*)d_in[6];
  const float* bias = (const float*)d_in[7];
  const float* W2 = (const float*)d_in[8];
  const float* a = (const float*)d_in[9];
  const float* a2 = (const float*)d_in[10];
  const float* a3 = (const float*)d_in[11];

  float* out0 = (float*)d_out;                // [B,D,N]
  float* out1 = out0 + (size_t)BB * DD * NN;  // [B,E,D] fp32 (written by k_out1n)
  _Float16* xt16 = (_Float16*)out1;           // [B,N,CIN] fp16 — dead after k_mid, before out1 written

  _Float16* out1T16 = (_Float16*)d_ws;                 // [B,D,E]
  _Float16* hThi = out1T16 + (size_t)BB * DD * EE;     // [B,D,N]
  _Float16* incT = hThi + (size_t)BB * DD * NN;        // [E,N]
  _Float16* w2shi = incT + (size_t)EE * NN;            // [E,E]
  _Float16* w2slo = w2shi + (size_t)EE * EE;           // [E,E]
  _Float16* inc16 = w2slo + (size_t)EE * EE;           // [N,E]
  _Float16* M16 = inc16 + (size_t)NN * EE;             // [E,N]
  _Float16* wt16 = M16 + (size_t)EE * NN;              // [D,CIN]
  float* M32 = (float*)(wt16 + (size_t)DD * CIN);      // [E,N] fp32
  float* node_sc = M32 + (size_t)EE * NN;              // B*N
  float* g1 = node_sc + (size_t)BB * NN;               // B*N
  float* g2 = g1 + (size_t)BB * NN;                    // B*N
  float* edge_sc = g2 + (size_t)BB * NN;               // B*E
  float* time_e = edge_sc + (size_t)BB * EE;           // B*E
  float* rmax = time_e + (size_t)BB * EE;              // B*E
  float* rinv = rmax + (size_t)BB * EE;                // B*E
  float* wa = rinv + (size_t)BB * EE;                  // 1024

  k_prep<<<dim3(1376), 256, 0, stream>>>(inc, W2, W, x, m, hid, a, a2, incT, w2shi, w2slo, wt16, inc16, wa, xt16);
  k_mid<<<dim3(880), 256, 0, stream>>>(xt16, wt16, bias, hThi, inc16, w2shi, w2slo, M32, M16, x, m, hid, wa,
                                       node_sc, g1, g2);
  k_score<<<dim3(16, BB), 256, 0, stream>>>(M32, g1, g2, node_sc, pri_e, a2, a3, incT, edge_sc, time_e, rmax, rinv);
  k_out1n<<<dim3(8 * 192), 256, 0, stream>>>(M16, hThi, out1, out1T16);
  k_fg2<<<dim3(8 * 96), 256, 0, stream>>>(out1T16, inc, node_sc, edge_sc, time_e, rmax, rinv, a3, out0);
}

// Round 12
// 132.925 us; speedup vs baseline: 1.5138x; 1.0128x over previous
//
#include <hip/hip_runtime.h>

#define BB 48
#define NN 256
#define EE 1024
#define DD 256
#define CIN 256

typedef __attribute__((ext_vector_type(4))) float f32x4;
typedef __attribute__((ext_vector_type(8))) _Float16 f16x8;
typedef __attribute__((ext_vector_type(4))) _Float16 f16x4;

__device__ __forceinline__ float lrelu(float t) { return t >= 0.0f ? t : 0.2f * t; }

__device__ __forceinline__ void gload16(const void* g, void* l) {
  __builtin_amdgcn_global_load_lds((const __attribute__((address_space(1))) void*)g,
                                   (__attribute__((address_space(3))) void*)l, 16, 0, 0);
}

// ---- k_prep: w2s hi/lo, incT, wt16, inc16, wa, xt (all input-only) ----
__global__ __launch_bounds__(256) void k_prep(const float* __restrict__ inc, const float* __restrict__ W2,
                                              const float* __restrict__ W, const float* __restrict__ x,
                                              const float* __restrict__ m, const float* __restrict__ hid,
                                              const float* __restrict__ a, const float* __restrict__ a2,
                                              _Float16* __restrict__ incT, _Float16* __restrict__ w2shi,
                                              _Float16* __restrict__ w2slo, _Float16* __restrict__ wt16,
                                              _Float16* __restrict__ inc16, float* __restrict__ wa,
                                              _Float16* __restrict__ xt) {
  __shared__ float tile[64][65];
  __shared__ float aux[4][64];
  __shared__ float aux2[64];
  int bid = blockIdx.x;
  int t = threadIdx.x;
  if (bid < 256) {  // w2s[e,f] = W2[f,e]*invdeg[f], hi/lo fp16 split
    int f0 = (bid & 15) * 64, e0 = (bid >> 4) * 64;
    int c = t & 63, r = t >> 6;
    {  // invdeg[f0..f0+63] (redundant per e0-panel)
      float s = 0.f;
      for (int i = 0; i < 64; ++i) s += inc[(size_t)(r * 64 + i) * EE + f0 + c];
      aux[r][c] = s;
    }
#pragma unroll
    for (int i = 0; i < 16; ++i) tile[r + i * 4][c] = W2[(size_t)(f0 + r + i * 4) * EE + e0 + c];
    __syncthreads();
    if (t < 64) aux2[t] = 1.0f / (aux[0][t] + aux[1][t] + aux[2][t] + aux[3][t]);
    __syncthreads();
#pragma unroll
    for (int i = 0; i < 16; ++i) {
      int row = r + i * 4;           // e-rel
      float v = tile[c][row] * aux2[c];  // W2[f0+c][e0+row] * invdeg[f0+c]
      _Float16 hh = (_Float16)v;
      w2shi[(size_t)(e0 + row) * EE + f0 + c] = hh;
      w2slo[(size_t)(e0 + row) * EE + f0 + c] = (_Float16)(v - (float)hh);
    }
  } else if (bid < 320) {  // incT[e,n] = inc[n,e]
    int s = bid - 256;
    int e0 = (s & 15) * 64, n0 = (s >> 4) * 64;
    int c = t & 63, r = t >> 6;
#pragma unroll
    for (int i = 0; i < 16; ++i) tile[r + i * 4][c] = inc[(size_t)(n0 + r + i * 4) * EE + e0 + c];
    __syncthreads();
#pragma unroll
    for (int i = 0; i < 16; ++i) {
      int row = r + i * 4;
      incT[(size_t)(e0 + row) * NN + n0 + c] = (_Float16)tile[c][row];
    }
  } else if (bid < 336) {  // wt16[d,c] = fp16(W[c,d])
    int s = bid - 320;
    int c0 = (s & 3) * 64, d0 = (s >> 2) * 64;
    int c = t & 63, r = t >> 6;
#pragma unroll
    for (int i = 0; i < 16; ++i) tile[r + i * 4][c] = W[(size_t)(c0 + r + i * 4) * DD + d0 + c];
    __syncthreads();
#pragma unroll
    for (int i = 0; i < 16; ++i) {
      int row = r + i * 4;
      wt16[(size_t)(d0 + row) * CIN + c0 + c] = (_Float16)tile[c][row];
    }
  } else if (bid < 352) {  // inc16[n,f] = fp16(inc) (exact 0/1)
    int s = bid - 336;
    size_t base = ((size_t)s * 256 + t) * 64;
#pragma unroll
    for (int i = 0; i < 16; ++i) {
      f32x4 v = *(const f32x4*)&inc[base + i * 4];
      f16x4 o;
      o[0] = (_Float16)v[0];
      o[1] = (_Float16)v[1];
      o[2] = (_Float16)v[2];
      o[3] = (_Float16)v[3];
      *(f16x4*)&inc16[base + i * 4] = o;
    }
  } else if (bid < 608) {  // wa
    float(*red)[4] = (float(*)[4])aux;
    int c = bid - 352;
    int l = t & 63, wv = t >> 6;
    float w = W[(size_t)c * DD + t];
    float p0 = w * a[t], p1 = w * a[DD + t], p2 = w * a2[t];
#pragma unroll
    for (int off = 32; off > 0; off >>= 1) {
      p0 += __shfl_down(p0, off);
      p1 += __shfl_down(p1, off);
      p2 += __shfl_down(p2, off);
    }
    if (l == 0) {
      red[0][wv] = p0;
      red[1][wv] = p1;
      red[2][wv] = p2;
    }
    __syncthreads();
    if (t == 0) wa[c] = red[0][0] + red[0][1] + red[0][2] + red[0][3];
    if (t == 1) wa[256 + c] = red[1][0] + red[1][1] + red[1][2] + red[1][3];
    if (t == 2) wa[512 + c] = red[2][0] + red[2][1] + red[2][2] + red[2][3];
    if (c == 0) {
      __syncthreads();
      float q0 = a[t], q1 = a[DD + t], q2 = a2[t];
#pragma unroll
      for (int off = 32; off > 0; off >>= 1) {
        q0 += __shfl_down(q0, off);
        q1 += __shfl_down(q1, off);
        q2 += __shfl_down(q2, off);
      }
      if (l == 0) {
        red[0][wv] = q0;
        red[1][wv] = q1;
        red[2][wv] = q2;
      }
      __syncthreads();
      if (t == 0) wa[768] = red[0][0] + red[0][1] + red[0][2] + red[0][3];
      if (t == 1) wa[769] = red[1][0] + red[1][1] + red[1][2] + red[1][3];
      if (t == 2) wa[770] = red[2][0] + red[2][1] + red[2][2] + red[2][3];
    }
  } else {  // xt16[b,n,c] = fp16(x_in[b,c,n]); 768 blocks
    int s = bid - 608;
    int c0 = (s & 3) * 64, n0 = ((s >> 2) & 3) * 64, b = s >> 4;
    int c = t & 63, r = t >> 6;
#pragma unroll
    for (int i = 0; i < 16; ++i) {
      int ch = c0 + r + i * 4;
      const float* row;
      if (ch < 96) row = x + ((size_t)b * 96 + ch) * NN;
      else if (ch < 192) row = m + ((size_t)b * 96 + (ch - 96)) * NN;
      else row = hid + ((size_t)b * 64 + (ch - 192)) * NN;
      tile[r + i * 4][c] = row[n0 + c];
    }
    __syncthreads();
#pragma unroll
    for (int i = 0; i < 16; ++i) {
      int row = r + i * 4;
      xt[((size_t)b * NN + n0 + row) * CIN + c0 + c] = (_Float16)tile[c][row];
    }
  }
}

// ---- k_mid: h16 (768) + M32/M16 2-term split MFMA (64) + ns2 (48) ----
__global__ __launch_bounds__(256) void k_mid(const _Float16* __restrict__ xt, const _Float16* __restrict__ wt,
                                             const float* __restrict__ bias, _Float16* __restrict__ hThi,
                                             const _Float16* __restrict__ inc16, const _Float16* __restrict__ w2shi,
                                             const _Float16* __restrict__ w2slo, float* __restrict__ M32,
                                             _Float16* __restrict__ M16, const float* __restrict__ x,
                                             const float* __restrict__ m, const float* __restrict__ hid,
                                             const float* __restrict__ wa, float* __restrict__ node_sc,
                                             float* __restrict__ g1, float* __restrict__ g2) {
  __shared__ _Float16 smA[64 * 64];
  __shared__ _Float16 smB[64 * 64];
  __shared__ _Float16 smB2[64 * 64];
  int bid = blockIdx.x;
  int t = threadIdx.x;
  if (bid < 768) {  // h16
    int xcd = bid & 7, il = bid >> 3;
    int ntile = il & 3, dtile = (il >> 2) & 3, bl = il >> 4;
    int b = xcd * 6 + bl;
    int n0 = ntile * 64, d0 = dtile * 64;
    int w = t >> 6, l = t & 63;
    int wm = w >> 1, wn = w & 1;
    int lr = l & 15;
    const _Float16* A = xt + ((size_t)b * NN + n0) * CIN;
    const _Float16* Bp = wt + (size_t)d0 * CIN;
    int lrow = l >> 3;
    int scol = 8 * ((l & 7) ^ (lrow & 7));
    f32x4 acc[2][2];
    f32x4 z = {0.f, 0.f, 0.f, 0.f};
#pragma unroll
    for (int i = 0; i < 2; ++i)
#pragma unroll
      for (int j = 0; j < 2; ++j) acc[i][j] = z;
    for (int kk = 0; kk < CIN; kk += 64) {
#pragma unroll
      for (int q = 0; q < 2; ++q) {
        int row = q * 32 + w * 8 + lrow;
        int lb = (q * 32 + w * 8) * 64;
        gload16(A + (size_t)row * CIN + kk + scol, smA + lb);
        gload16(Bp + (size_t)row * CIN + kk + scol, smB + lb);
      }
      __syncthreads();
      f16x8 af[2][2], bf[2][2];
#pragma unroll
      for (int i = 0; i < 2; ++i)
#pragma unroll
        for (int ks = 0; ks < 2; ++ks) {
          int ra = wm * 32 + i * 16 + lr;
          af[i][ks] = *(const f16x8*)&smA[ra * 64 + ((ks * 32 + (l >> 4) * 8) ^ ((ra & 7) << 3))];
          int rb = wn * 32 + i * 16 + lr;
          bf[i][ks] = *(const f16x8*)&smB[rb * 64 + ((ks * 32 + (l >> 4) * 8) ^ ((rb & 7) << 3))];
        }
#pragma unroll
      for (int ks = 0; ks < 2; ++ks)
#pragma unroll
        for (int i = 0; i < 2; ++i)
#pragma unroll
          for (int j = 0; j < 2; ++j)
            acc[i][j] = __builtin_amdgcn_mfma_f32_16x16x32_f16(af[i][ks], bf[j][ks], acc[i][j], 0, 0, 0);
      __syncthreads();
    }
#pragma unroll
    for (int i = 0; i < 2; ++i)
#pragma unroll
      for (int j = 0; j < 2; ++j) {
        int nb = n0 + wm * 32 + i * 16 + (l >> 4) * 4;
        int d = d0 + wn * 32 + j * 16 + lr;
        float4 bv = *(const float4*)&bias[nb];
        f16x4 vh;
        vh[0] = (_Float16)(acc[i][j][0] + bv.x);
        vh[1] = (_Float16)(acc[i][j][1] + bv.y);
        vh[2] = (_Float16)(acc[i][j][2] + bv.z);
        vh[3] = (_Float16)(acc[i][j][3] + bv.w);
        *(f16x4*)&hThi[((size_t)b * DD + d) * NN + nb] = vh;
      }
  } else if (bid < 832) {  // M32/M16[e,n] = sum_f inc16[n,f]*(w2shi+w2slo)[e,f]; 64 blocks
    int mb = bid - 768;
    int np = mb & 3, ep = mb >> 2;
    int m0 = np * 64;  // n rows
    int n0 = ep * 64;  // e cols
    int w = t >> 6, l = t & 63;
    int wm = w >> 1, wn = w & 1;
    int lr = l & 15;
    const _Float16* A = inc16 + (size_t)m0 * EE;
    const _Float16* Bh = w2shi + (size_t)n0 * EE;
    const _Float16* Bl = w2slo + (size_t)n0 * EE;
    int lrow = l >> 3;
    int scol = 8 * ((l & 7) ^ (lrow & 7));
    f32x4 acc[2][2];
    f32x4 z = {0.f, 0.f, 0.f, 0.f};
#pragma unroll
    for (int i = 0; i < 2; ++i)
#pragma unroll
      for (int j = 0; j < 2; ++j) acc[i][j] = z;
    for (int kk = 0; kk < EE; kk += 64) {
#pragma unroll
      for (int q = 0; q < 2; ++q) {
        int row = q * 32 + w * 8 + lrow;
        int lb = (q * 32 + w * 8) * 64;
        gload16(A + (size_t)row * EE + kk + scol, smA + lb);
        gload16(Bh + (size_t)row * EE + kk + scol, smB + lb);
        gload16(Bl + (size_t)row * EE + kk + scol, smB2 + lb);
      }
      __syncthreads();
      f16x8 af[2][2], bfh[2][2], bfl[2][2];
#pragma unroll
      for (int i = 0; i < 2; ++i)
#pragma unroll
        for (int ks = 0; ks < 2; ++ks) {
          int ra = wm * 32 + i * 16 + lr;
          int off_a = ra * 64 + ((ks * 32 + (l >> 4) * 8) ^ ((ra & 7) << 3));
          af[i][ks] = *(const f16x8*)&smA[off_a];
          int rb = wn * 32 + i * 16 + lr;
          int off_b = rb * 64 + ((ks * 32 + (l >> 4) * 8) ^ ((rb & 7) << 3));
          bfh[i][ks] = *(const f16x8*)&smB[off_b];
          bfl[i][ks] = *(const f16x8*)&smB2[off_b];
        }
#pragma unroll
      for (int ks = 0; ks < 2; ++ks)
#pragma unroll
        for (int i = 0; i < 2; ++i)
#pragma unroll
          for (int j = 0; j < 2; ++j) {
            acc[i][j] = __builtin_amdgcn_mfma_f32_16x16x32_f16(af[i][ks], bfh[j][ks], acc[i][j], 0, 0, 0);
            acc[i][j] = __builtin_amdgcn_mfma_f32_16x16x32_f16(af[i][ks], bfl[j][ks], acc[i][j], 0, 0, 0);
          }
      __syncthreads();
    }
#pragma unroll
    for (int i = 0; i < 2; ++i)
#pragma unroll
      for (int j = 0; j < 2; ++j) {
        int n = m0 + wm * 32 + i * 16 + (l >> 4) * 4;
        int e = n0 + wn * 32 + j * 16 + lr;
        *(f32x4*)&M32[(size_t)e * NN + n] = acc[i][j];
        f16x4 v;
#pragma unroll
        for (int r = 0; r < 4; ++r) v[r] = (_Float16)acc[i][j][r];
        *(f16x4*)&M16[(size_t)e * NN + n] = v;
      }
  } else {  // ns2: b = bid - 832
    float* s0a = (float*)smA;
    float* s1a = s0a + 256;
    float* s2a = s0a + 512;
    int b = bid - 832;
    s0a[t] = wa[t];
    s1a[t] = wa[256 + t];
    s2a[t] = wa[512 + t];
    __syncthreads();
    float s0 = 0.f, s1 = 0.f, s2 = 0.f;
#pragma unroll 4
    for (int c = 0; c < 256; ++c) {
      const float* row;
      if (c < 96) row = x + ((size_t)b * 96 + c) * NN;
      else if (c < 192) row = m + ((size_t)b * 96 + (c - 96)) * NN;
      else row = hid + ((size_t)b * 64 + (c - 192)) * NN;
      float v = row[t];
      s0 += v * s0a[c];
      s1 += v * s1a[c];
      s2 += v * s2a[c];
    }
    float bv = bias[t];
    int idx = b * NN + t;
    node_sc[idx] = s0 + bv * wa[768];
    g1[idx] = s1 + bv * wa[769];
    g2[idx] = s2 + bv * wa[770];
  }
}

// ---- k_out1s: out1/out1T16 GEMM (3072 blocks, 64x64) + score (768 blocks) ----
__global__ __launch_bounds__(256) void k_out1s(const _Float16* __restrict__ M16, const _Float16* __restrict__ hThi,
                                               float* __restrict__ out1, _Float16* __restrict__ out1T,
                                               const float* __restrict__ M32, const float* __restrict__ g1,
                                               const float* __restrict__ g2, const float* __restrict__ node_sc,
                                               const float* __restrict__ pri_e, const float* __restrict__ a2,
                                               const float* __restrict__ a3, const _Float16* __restrict__ incT,
                                               float* __restrict__ edge_sc, float* __restrict__ time_e,
                                               float* __restrict__ rmax, float* __restrict__ rinv) {
  __shared__ _Float16 smA[64 * 64];
  __shared__ _Float16 smB[64 * 64];
  int bid = blockIdx.x;
  int t = threadIdx.x;
  if (bid < 3072) {  // out1[b,e,d] = sum_n M16[e,n]*hThi[b,d,n]; 64e x 64d; b-pinned XCD
    int xcd = bid & 7, il = bid >> 3;            // 384 per XCD
    int ep = il & 15, dblk = (il >> 4) & 3, bl = il >> 6;
    int b = xcd * 6 + bl;
    int e0 = ep * 64, d0 = dblk * 64;
    int w = t >> 6, l = t & 63;
    int wm = w >> 1, wn = w & 1;
    int lr = l & 15;
    const _Float16* A = M16 + (size_t)e0 * NN;
    const _Float16* Bp = hThi + ((size_t)b * DD + d0) * NN;
    int lrow = l >> 3;
    int scol = 8 * ((l & 7) ^ (lrow & 7));
    f32x4 acc[2][2];
    f32x4 z = {0.f, 0.f, 0.f, 0.f};
#pragma unroll
    for (int i = 0; i < 2; ++i)
#pragma unroll
      for (int j = 0; j < 2; ++j) acc[i][j] = z;
    for (int kk = 0; kk < NN; kk += 64) {
#pragma unroll
      for (int q = 0; q < 2; ++q) {
        int row = q * 32 + w * 8 + lrow;
        int lb = (q * 32 + w * 8) * 64;
        gload16(A + (size_t)row * NN + kk + scol, smA + lb);
        gload16(Bp + (size_t)row * NN + kk + scol, smB + lb);
      }
      __syncthreads();
      f16x8 af[2][2], bf[2][2];
#pragma unroll
      for (int i = 0; i < 2; ++i)
#pragma unroll
        for (int ks = 0; ks < 2; ++ks) {
          int ra = wm * 32 + i * 16 + lr;
          af[i][ks] = *(const f16x8*)&smA[ra * 64 + ((ks * 32 + (l >> 4) * 8) ^ ((ra & 7) << 3))];
          int rb = wn * 32 + i * 16 + lr;
          bf[i][ks] = *(const f16x8*)&smB[rb * 64 + ((ks * 32 + (l >> 4) * 8) ^ ((rb & 7) << 3))];
        }
#pragma unroll
      for (int ks = 0; ks < 2; ++ks)
#pragma unroll
        for (int i = 0; i < 2; ++i)
#pragma unroll
          for (int j = 0; j < 2; ++j)
            acc[i][j] = __builtin_amdgcn_mfma_f32_16x16x32_f16(af[i][ks], bf[j][ks], acc[i][j], 0, 0, 0);
      __syncthreads();
    }
#pragma unroll
    for (int i = 0; i < 2; ++i)
#pragma unroll
      for (int j = 0; j < 2; ++j) {
        int e = e0 + wm * 32 + i * 16 + (l >> 4) * 4;
        int d = d0 + wn * 32 + j * 16 + lr;
        f16x4 v16;
#pragma unroll
        for (int r = 0; r < 4; ++r) {
          out1[((size_t)b * EE + e + r) * DD + d] = acc[i][j][r];
          v16[r] = (_Float16)acc[i][j][r];
        }
        *(f16x4*)&out1T[((size_t)b * DD + d) * EE + e] = v16;
      }
  } else {  // score
    float* sg1 = (float*)smA;      // 256
    float* sg2 = sg1 + 256;        // 256
    float* snc = sg2 + 256;        // 256
    float(*r1)[4] = (float(*)[4])(snc + 256);  // 64*4
    float(*r2)[4] = r1 + 64;                   // 64*4
    float* sesc = (float*)(r2 + 64);           // 64
    float* steA = sesc + 64;                   // 64
    int sb = bid - 3072;
    int e0 = (sb & 15) * 64, b = sb >> 4;
    float a30 = a3[0], a31 = a3[1];
    sg1[t] = g1[b * NN + t];
    sg2[t] = g2[b * NN + t];
    snc[t] = node_sc[b * NN + t];
    __syncthreads();
    {  // phase 1: esc/te for 64 e's
      int ei = t >> 2, part = t & 3;
      const float* Mr = M32 + (size_t)(e0 + ei) * NN + part * 64;
      const float* pg1 = sg1 + part * 64;
      const float* pg2 = sg2 + part * 64;
      float s1 = 0.f, s2 = 0.f;
      for (int i = 0; i < 64; i += 4) {
        f32x4 mv = *(const f32x4*)&Mr[i];
        f32x4 v1 = *(const f32x4*)&pg1[i];
        f32x4 v2 = *(const f32x4*)&pg2[i];
        s1 += mv[0] * v1[0] + mv[1] * v1[1] + mv[2] * v1[2] + mv[3] * v1[3];
        s2 += mv[0] * v2[0] + mv[1] * v2[1] + mv[2] * v2[2] + mv[3] * v2[3];
      }
      r1[ei][part] = s1;
      r2[ei][part] = s2;
    }
    __syncthreads();
    if (t < 64) {
      int row = b * EE + e0 + t;
      float es = r1[t][0] + r1[t][1] + r1[t][2] + r1[t][3];
      float te = lrelu(r2[t][0] + r2[t][1] + r2[t][2] + r2[t][3] + pri_e[row] * a2[DD]);
      edge_sc[row] = es;
      time_e[row] = te;
      sesc[t] = es;
      steA[t] = te * a30;
    }
    __syncthreads();
    int w = t >> 6, l = t & 63;
    for (int rr = 0; rr < 16; ++rr) {
      int er = w * 16 + rr;
      int e = e0 + er;
      float es = sesc[er], ta = steA[er];
      f16x4 ic = *(const f16x4*)&incT[(size_t)e * NN + l * 4];
      float s2v[4];
      bool msk[4];
      float vmax = -3.0e38f;
#pragma unroll
      for (int q = 0; q < 4; ++q) {
        float s1 = lrelu(snc[l * 4 + q] + es);
        float s2 = lrelu(ta + s1 * a31);
        msk[q] = (float)ic[q] > 0.f;
        s2v[q] = s2;
        if (msk[q]) vmax = fmaxf(vmax, s2);
      }
#pragma unroll
      for (int off = 32; off > 0; off >>= 1) vmax = fmaxf(vmax, __shfl_xor(vmax, off));
      float ss = 0.f;
#pragma unroll
      for (int q = 0; q < 4; ++q)
        if (msk[q]) ss += __expf(s2v[q] - vmax);
#pragma unroll
      for (int off = 32; off > 0; off >>= 1) ss += __shfl_xor(ss, off);
      if (l == 0) {
        int row = b * EE + e;
        rmax[row] = vmax;
        rinv[row] = 1.0f / ss;
      }
    }
  }
}

// out0[b,d,n] = sum_e att[n,e]*out1T16[d,e]; att computed in-kernel; b-pinned XCD
__global__ __launch_bounds__(256) void k_fg2(const _Float16* __restrict__ out1T, const float* __restrict__ inc,
                                             const float* __restrict__ node_sc, const float* __restrict__ edge_sc,
                                             const float* __restrict__ time_e, const float* __restrict__ rmax,
                                             const float* __restrict__ rinv, const float* __restrict__ a3,
                                             float* __restrict__ out0) {
  __shared__ _Float16 smA[64 * 64];
  __shared__ _Float16 smB[64 * 64];
  __shared__ float sE[4][1024];
  __shared__ float snc[64];
  int bid = blockIdx.x;
  int xcd = bid & 7, il = bid >> 3;
  int ntile = il & 3, dtile = (il >> 2) & 3, bl = il >> 4;
  int b = xcd * 6 + bl;
  int n0 = ntile * 64, d0 = dtile * 64;
  int t = threadIdx.x, w = t >> 6, l = t & 63;
  int wm = w >> 1, wn = w & 1;
  int lr = l & 15;
  float a30 = a3[0], a31 = a3[1];
  {
    int be = b * EE + t * 4;
    float4 e4 = *(const float4*)&edge_sc[be];
    float4 t4 = *(const float4*)&time_e[be];
    float4 m4 = *(const float4*)&rmax[be];
    float4 r4 = *(const float4*)&rinv[be];
    *(float4*)&sE[0][t * 4] = e4;
    *(float4*)&sE[1][t * 4] = make_float4(t4.x * a30, t4.y * a30, t4.z * a30, t4.w * a30);
    *(float4*)&sE[2][t * 4] = m4;
    *(float4*)&sE[3][t * 4] = r4;
    if (t < 64) snc[t] = node_sc[b * NN + n0 + t];
  }
  const _Float16* Bp = out1T + ((size_t)b * DD + d0) * EE;
  int lrow = l >> 3;
  int scol = 8 * ((l & 7) ^ (lrow & 7));
  int eq = t & 15, nq = t >> 4;
  f32x4 acc[2][2];
  f32x4 z = {0.f, 0.f, 0.f, 0.f};
#pragma unroll
  for (int i = 0; i < 2; ++i)
#pragma unroll
    for (int j = 0; j < 2; ++j) acc[i][j] = z;
  __syncthreads();
  for (int kk = 0; kk < EE; kk += 64) {
#pragma unroll
    for (int q = 0; q < 2; ++q) {
      int row = q * 32 + w * 8 + lrow;
      int lb = (q * 32 + w * 8) * 64;
      gload16(Bp + (size_t)row * EE + kk + scol, smB + lb);
    }
    {
      int e0 = eq * 4;
      f32x4 esc = *(const f32x4*)&sE[0][kk + e0];
      f32x4 tea = *(const f32x4*)&sE[1][kk + e0];
      f32x4 rmx = *(const f32x4*)&sE[2][kk + e0];
      f32x4 riv = *(const f32x4*)&sE[3][kk + e0];
#pragma unroll
      for (int i = 0; i < 4; ++i) {
        int n = nq * 4 + i;
        float ns = snc[n];
        float4 icv = *(const float4*)&inc[(size_t)(n0 + n) * EE + kk + e0];
        float ica[4] = {icv.x, icv.y, icv.z, icv.w};
        f16x4 o;
#pragma unroll
        for (int q = 0; q < 4; ++q) {
          float att = 0.f;
          if (ica[q] > 0.f) {
            float s1 = lrelu(ns + esc[q]);
            float s2 = lrelu(tea[q] + s1 * a31);
            att = __expf(s2 - rmx[q]) * riv[q];
          }
          o[q] = (_Float16)att;
        }
        int addr = n * 64 + (((e0 & ~7) ^ ((n & 7) << 3)) | (e0 & 7));
        *(f16x4*)&smA[addr] = o;
      }
    }
    __syncthreads();
    f16x8 af[2][2], bf[2][2];
#pragma unroll
    for (int i = 0; i < 2; ++i)
#pragma unroll
      for (int ks = 0; ks < 2; ++ks) {
        int ra = wm * 32 + i * 16 + lr;
        af[i][ks] = *(const f16x8*)&smA[ra * 64 + ((ks * 32 + (l >> 4) * 8) ^ ((ra & 7) << 3))];
        int rb = wn * 32 + i * 16 + lr;
        bf[i][ks] = *(const f16x8*)&smB[rb * 64 + ((ks * 32 + (l >> 4) * 8) ^ ((rb & 7) << 3))];
      }
#pragma unroll
    for (int ks = 0; ks < 2; ++ks)
#pragma unroll
      for (int i = 0; i < 2; ++i)
#pragma unroll
        for (int j = 0; j < 2; ++j)
          acc[i][j] = __builtin_amdgcn_mfma_f32_16x16x32_f16(af[i][ks], bf[j][ks], acc[i][j], 0, 0, 0);
    __syncthreads();
  }
  float* ob = out0 + (size_t)b * DD * NN;
#pragma unroll
  for (int i = 0; i < 2; ++i)
#pragma unroll
    for (int j = 0; j < 2; ++j) {
      int n = n0 + wm * 32 + i * 16 + (l >> 4) * 4;
      int d = d0 + wn * 32 + j * 16 + lr;
      *(float4*)&ob[(size_t)d * NN + n] =
          make_float4(acc[i][j][0], acc[i][j][1], acc[i][j][2], acc[i][j][3]);
    }
}

extern "C" void kernel_launch(void* const* d_in, const int* in_sizes, int n_in, void* d_out, int out_size,
                              void* d_ws, size_t ws_size, hipStream_t stream) {
  (void)in_sizes;
  (void)n_in;
  (void)out_size;
  (void)ws_size;
  const float* x = (const float*)d_in[0];
  const float* m = (const float*)d_in[1];
  const float* hid = (const float*)d_in[2];
  const float* pri_e = (const float*)d_in[3];
  const float* inc = (const float*)d_in[5];
  const float* W = (const float*)d_in[6];
  const float* bias = (const float*)d_in[7];
  const float* W2 = (const float*)d_in[8];
  const float* a = (const float*)d_in[9];
  const float* a2 = (const float*)d_in[10];
  const float* a3 = (const float*)d_in[11];

  float* out0 = (float*)d_out;                // [B,D,N]
  float* out1 = out0 + (size_t)BB * DD * NN;  // [B,E,D] fp32 (written by k_out1s)
  _Float16* xt16 = (_Float16*)out1;           // [B,N,CIN] fp16 — dead after k_mid, before out1 written

  _Float16* out1T16 = (_Float16*)d_ws;                 // [B,D,E]
  _Float16* hThi = out1T16 + (size_t)BB * DD * EE;     // [B,D,N]
  _Float16* incT = hThi + (size_t)BB * DD * NN;        // [E,N]
  _Float16* w2shi = incT + (size_t)EE * NN;            // [E,E]
  _Float16* w2slo = w2shi + (size_t)EE * EE;           // [E,E]
  _Float16* inc16 = w2slo + (size_t)EE * EE;           // [N,E]
  _Float16* M16 = inc16 + (size_t)NN * EE;             // [E,N]
  _Float16* wt16 = M16 + (size_t)EE * NN;              // [D,CIN]
  float* M32 = (float*)(wt16 + (size_t)DD * CIN);      // [E,N] fp32
  float* node_sc = M32 + (size_t)EE * NN;              // B*N
  float* g1 = node_sc + (size_t)BB * NN;               // B*N
  float* g2 = g1 + (size_t)BB * NN;                    // B*N
  float* edge_sc = g2 + (size_t)BB * NN;               // B*E
  float* time_e = edge_sc + (size_t)BB * EE;           // B*E
  float* rmax = time_e + (size_t)BB * EE;              // B*E
  float* rinv = rmax + (size_t)BB * EE;                // B*E
  float* wa = rinv + (size_t)BB * EE;                  // 1024

  k_prep<<<dim3(1376), 256, 0, stream>>>(inc, W2, W, x, m, hid, a, a2, incT, w2shi, w2slo, wt16, inc16, wa, xt16);
  k_mid<<<dim3(880), 256, 0, stream>>>(xt16, wt16, bias, hThi, inc16, w2shi, w2slo, M32, M16, x, m, hid, wa,
                                       node_sc, g1, g2);
  k_out1s<<<dim3(3072 + 768), 256, 0, stream>>>(M16, hThi, out1, out1T16, M32, g1, g2, node_sc, pri_e, a2, a3,
                                                incT, edge_sc, time_e, rmax, rinv);
  k_fg2<<<dim3(8 * 96), 256, 0, stream>>>(out1T16, inc, node_sc, edge_sc, time_e, rmax, rinv, a3, out0);
}

// Round 13
// 115.799 us; speedup vs baseline: 1.7376x; 1.1479x over previous
//
#include <hip/hip_runtime.h>

#define BB 48
#define NN 256
#define EE 1024
#define DD 256
#define CIN 256

typedef __attribute__((ext_vector_type(4))) float f32x4;
typedef __attribute__((ext_vector_type(8))) _Float16 f16x8;
typedef __attribute__((ext_vector_type(4))) _Float16 f16x4;

__device__ __forceinline__ float lrelu(float t) { return t >= 0.0f ? t : 0.2f * t; }

__device__ __forceinline__ void gload16(const void* g, void* l) {
  __builtin_amdgcn_global_load_lds((const __attribute__((address_space(1))) void*)g,
                                   (__attribute__((address_space(3))) void*)l, 16, 0, 0);
}

// ---- k_prep: w2s hi/lo, incT, wt16, inc16, wa, xt (all input-only) ----
__global__ __launch_bounds__(256) void k_prep(const float* __restrict__ inc, const float* __restrict__ W2,
                                              const float* __restrict__ W, const float* __restrict__ x,
                                              const float* __restrict__ m, const float* __restrict__ hid,
                                              const float* __restrict__ a, const float* __restrict__ a2,
                                              _Float16* __restrict__ incT, _Float16* __restrict__ w2shi,
                                              _Float16* __restrict__ w2slo, _Float16* __restrict__ wt16,
                                              _Float16* __restrict__ inc16, float* __restrict__ wa,
                                              _Float16* __restrict__ xt) {
  __shared__ float tile[64][65];
  __shared__ float aux[4][64];
  __shared__ float aux2[64];
  int bid = blockIdx.x;
  int t = threadIdx.x;
  if (bid < 256) {  // w2s[e,f] = W2[f,e]*invdeg[f], hi/lo fp16 split
    int f0 = (bid & 15) * 64, e0 = (bid >> 4) * 64;
    int c = t & 63, r = t >> 6;
    {
      float s = 0.f;
      for (int i = 0; i < 64; ++i) s += inc[(size_t)(r * 64 + i) * EE + f0 + c];
      aux[r][c] = s;
    }
#pragma unroll
    for (int i = 0; i < 16; ++i) tile[r + i * 4][c] = W2[(size_t)(f0 + r + i * 4) * EE + e0 + c];
    __syncthreads();
    if (t < 64) aux2[t] = 1.0f / (aux[0][t] + aux[1][t] + aux[2][t] + aux[3][t]);
    __syncthreads();
#pragma unroll
    for (int i = 0; i < 16; ++i) {
      int row = r + i * 4;
      float v = tile[c][row] * aux2[c];
      _Float16 hh = (_Float16)v;
      w2shi[(size_t)(e0 + row) * EE + f0 + c] = hh;
      w2slo[(size_t)(e0 + row) * EE + f0 + c] = (_Float16)(v - (float)hh);
    }
  } else if (bid < 320) {  // incT[e,n] = inc[n,e]
    int s = bid - 256;
    int e0 = (s & 15) * 64, n0 = (s >> 4) * 64;
    int c = t & 63, r = t >> 6;
#pragma unroll
    for (int i = 0; i < 16; ++i) tile[r + i * 4][c] = inc[(size_t)(n0 + r + i * 4) * EE + e0 + c];
    __syncthreads();
#pragma unroll
    for (int i = 0; i < 16; ++i) {
      int row = r + i * 4;
      incT[(size_t)(e0 + row) * NN + n0 + c] = (_Float16)tile[c][row];
    }
  } else if (bid < 336) {  // wt16[d,c] = fp16(W[c,d])
    int s = bid - 320;
    int c0 = (s & 3) * 64, d0 = (s >> 2) * 64;
    int c = t & 63, r = t >> 6;
#pragma unroll
    for (int i = 0; i < 16; ++i) tile[r + i * 4][c] = W[(size_t)(c0 + r + i * 4) * DD + d0 + c];
    __syncthreads();
#pragma unroll
    for (int i = 0; i < 16; ++i) {
      int row = r + i * 4;
      wt16[(size_t)(d0 + row) * CIN + c0 + c] = (_Float16)tile[c][row];
    }
  } else if (bid < 352) {  // inc16[n,f] = fp16(inc) (exact 0/1)
    int s = bid - 336;
    size_t base = ((size_t)s * 256 + t) * 64;
#pragma unroll
    for (int i = 0; i < 16; ++i) {
      f32x4 v = *(const f32x4*)&inc[base + i * 4];
      f16x4 o;
      o[0] = (_Float16)v[0];
      o[1] = (_Float16)v[1];
      o[2] = (_Float16)v[2];
      o[3] = (_Float16)v[3];
      *(f16x4*)&inc16[base + i * 4] = o;
    }
  } else if (bid < 608) {  // wa
    float(*red)[4] = (float(*)[4])aux;
    int c = bid - 352;
    int l = t & 63, wv = t >> 6;
    float w = W[(size_t)c * DD + t];
    float p0 = w * a[t], p1 = w * a[DD + t], p2 = w * a2[t];
#pragma unroll
    for (int off = 32; off > 0; off >>= 1) {
      p0 += __shfl_down(p0, off);
      p1 += __shfl_down(p1, off);
      p2 += __shfl_down(p2, off);
    }
    if (l == 0) {
      red[0][wv] = p0;
      red[1][wv] = p1;
      red[2][wv] = p2;
    }
    __syncthreads();
    if (t == 0) wa[c] = red[0][0] + red[0][1] + red[0][2] + red[0][3];
    if (t == 1) wa[256 + c] = red[1][0] + red[1][1] + red[1][2] + red[1][3];
    if (t == 2) wa[512 + c] = red[2][0] + red[2][1] + red[2][2] + red[2][3];
    if (c == 0) {
      __syncthreads();
      float q0 = a[t], q1 = a[DD + t], q2 = a2[t];
#pragma unroll
      for (int off = 32; off > 0; off >>= 1) {
        q0 += __shfl_down(q0, off);
        q1 += __shfl_down(q1, off);
        q2 += __shfl_down(q2, off);
      }
      if (l == 0) {
        red[0][wv] = q0;
        red[1][wv] = q1;
        red[2][wv] = q2;
      }
      __syncthreads();
      if (t == 0) wa[768] = red[0][0] + red[0][1] + red[0][2] + red[0][3];
      if (t == 1) wa[769] = red[1][0] + red[1][1] + red[1][2] + red[1][3];
      if (t == 2) wa[770] = red[2][0] + red[2][1] + red[2][2] + red[2][3];
    }
  } else {  // xt16[b,n,c] = fp16(x_in[b,c,n]); 768 blocks
    int s = bid - 608;
    int c0 = (s & 3) * 64, n0 = ((s >> 2) & 3) * 64, b = s >> 4;
    int c = t & 63, r = t >> 6;
#pragma unroll
    for (int i = 0; i < 16; ++i) {
      int ch = c0 + r + i * 4;
      const float* row;
      if (ch < 96) row = x + ((size_t)b * 96 + ch) * NN;
      else if (ch < 192) row = m + ((size_t)b * 96 + (ch - 96)) * NN;
      else row = hid + ((size_t)b * 64 + (ch - 192)) * NN;
      tile[r + i * 4][c] = row[n0 + c];
    }
    __syncthreads();
#pragma unroll
    for (int i = 0; i < 16; ++i) {
      int row = r + i * 4;
      xt[((size_t)b * NN + n0 + row) * CIN + c0 + c] = (_Float16)tile[c][row];
    }
  }
}

// ---- k_mid: h16 (768) + M32/M16 2-term split MFMA (64) + ns2 (48) ----
__global__ __launch_bounds__(256) void k_mid(const _Float16* __restrict__ xt, const _Float16* __restrict__ wt,
                                             const float* __restrict__ bias, _Float16* __restrict__ hThi,
                                             const _Float16* __restrict__ inc16, const _Float16* __restrict__ w2shi,
                                             const _Float16* __restrict__ w2slo, float* __restrict__ M32,
                                             _Float16* __restrict__ M16, const float* __restrict__ x,
                                             const float* __restrict__ m, const float* __restrict__ hid,
                                             const float* __restrict__ wa, float* __restrict__ node_sc,
                                             float* __restrict__ g1, float* __restrict__ g2) {
  __shared__ _Float16 smA[64 * 64];
  __shared__ _Float16 smB[64 * 64];
  __shared__ _Float16 smB2[64 * 64];
  int bid = blockIdx.x;
  int t = threadIdx.x;
  if (bid < 768) {  // h16
    int xcd = bid & 7, il = bid >> 3;
    int ntile = il & 3, dtile = (il >> 2) & 3, bl = il >> 4;
    int b = xcd * 6 + bl;
    int n0 = ntile * 64, d0 = dtile * 64;
    int w = t >> 6, l = t & 63;
    int wm = w >> 1, wn = w & 1;
    int lr = l & 15;
    const _Float16* A = xt + ((size_t)b * NN + n0) * CIN;
    const _Float16* Bp = wt + (size_t)d0 * CIN;
    int lrow = l >> 3;
    int scol = 8 * ((l & 7) ^ (lrow & 7));
    f32x4 acc[2][2];
    f32x4 z = {0.f, 0.f, 0.f, 0.f};
#pragma unroll
    for (int i = 0; i < 2; ++i)
#pragma unroll
      for (int j = 0; j < 2; ++j) acc[i][j] = z;
    for (int kk = 0; kk < CIN; kk += 64) {
#pragma unroll
      for (int q = 0; q < 2; ++q) {
        int row = q * 32 + w * 8 + lrow;
        int lb = (q * 32 + w * 8) * 64;
        gload16(A + (size_t)row * CIN + kk + scol, smA + lb);
        gload16(Bp + (size_t)row * CIN + kk + scol, smB + lb);
      }
      __syncthreads();
      f16x8 af[2][2], bf[2][2];
#pragma unroll
      for (int i = 0; i < 2; ++i)
#pragma unroll
        for (int ks = 0; ks < 2; ++ks) {
          int ra = wm * 32 + i * 16 + lr;
          af[i][ks] = *(const f16x8*)&smA[ra * 64 + ((ks * 32 + (l >> 4) * 8) ^ ((ra & 7) << 3))];
          int rb = wn * 32 + i * 16 + lr;
          bf[i][ks] = *(const f16x8*)&smB[rb * 64 + ((ks * 32 + (l >> 4) * 8) ^ ((rb & 7) << 3))];
        }
#pragma unroll
      for (int ks = 0; ks < 2; ++ks)
#pragma unroll
        for (int i = 0; i < 2; ++i)
#pragma unroll
          for (int j = 0; j < 2; ++j)
            acc[i][j] = __builtin_amdgcn_mfma_f32_16x16x32_f16(af[i][ks], bf[j][ks], acc[i][j], 0, 0, 0);
      __syncthreads();
    }
#pragma unroll
    for (int i = 0; i < 2; ++i)
#pragma unroll
      for (int j = 0; j < 2; ++j) {
        int nb = n0 + wm * 32 + i * 16 + (l >> 4) * 4;
        int d = d0 + wn * 32 + j * 16 + lr;
        float4 bv = *(const float4*)&bias[nb];
        f16x4 vh;
        vh[0] = (_Float16)(acc[i][j][0] + bv.x);
        vh[1] = (_Float16)(acc[i][j][1] + bv.y);
        vh[2] = (_Float16)(acc[i][j][2] + bv.z);
        vh[3] = (_Float16)(acc[i][j][3] + bv.w);
        *(f16x4*)&hThi[((size_t)b * DD + d) * NN + nb] = vh;
      }
  } else if (bid < 832) {  // M32/M16[e,n] = sum_f inc16[n,f]*(w2shi+w2slo)[e,f]; 64 blocks
    int mb = bid - 768;
    int np = mb & 3, ep = mb >> 2;
    int m0 = np * 64;
    int n0 = ep * 64;
    int w = t >> 6, l = t & 63;
    int wm = w >> 1, wn = w & 1;
    int lr = l & 15;
    const _Float16* A = inc16 + (size_t)m0 * EE;
    const _Float16* Bh = w2shi + (size_t)n0 * EE;
    const _Float16* Bl = w2slo + (size_t)n0 * EE;
    int lrow = l >> 3;
    int scol = 8 * ((l & 7) ^ (lrow & 7));
    f32x4 acc[2][2];
    f32x4 z = {0.f, 0.f, 0.f, 0.f};
#pragma unroll
    for (int i = 0; i < 2; ++i)
#pragma unroll
      for (int j = 0; j < 2; ++j) acc[i][j] = z;
    for (int kk = 0; kk < EE; kk += 64) {
#pragma unroll
      for (int q = 0; q < 2; ++q) {
        int row = q * 32 + w * 8 + lrow;
        int lb = (q * 32 + w * 8) * 64;
        gload16(A + (size_t)row * EE + kk + scol, smA + lb);
        gload16(Bh + (size_t)row * EE + kk + scol, smB + lb);
        gload16(Bl + (size_t)row * EE + kk + scol, smB2 + lb);
      }
      __syncthreads();
      f16x8 af[2][2], bfh[2][2], bfl[2][2];
#pragma unroll
      for (int i = 0; i < 2; ++i)
#pragma unroll
        for (int ks = 0; ks < 2; ++ks) {
          int ra = wm * 32 + i * 16 + lr;
          int off_a = ra * 64 + ((ks * 32 + (l >> 4) * 8) ^ ((ra & 7) << 3));
          af[i][ks] = *(const f16x8*)&smA[off_a];
          int rb = wn * 32 + i * 16 + lr;
          int off_b = rb * 64 + ((ks * 32 + (l >> 4) * 8) ^ ((rb & 7) << 3));
          bfh[i][ks] = *(const f16x8*)&smB[off_b];
          bfl[i][ks] = *(const f16x8*)&smB2[off_b];
        }
#pragma unroll
      for (int ks = 0; ks < 2; ++ks)
#pragma unroll
        for (int i = 0; i < 2; ++i)
#pragma unroll
          for (int j = 0; j < 2; ++j) {
            acc[i][j] = __builtin_amdgcn_mfma_f32_16x16x32_f16(af[i][ks], bfh[j][ks], acc[i][j], 0, 0, 0);
            acc[i][j] = __builtin_amdgcn_mfma_f32_16x16x32_f16(af[i][ks], bfl[j][ks], acc[i][j], 0, 0, 0);
          }
      __syncthreads();
    }
#pragma unroll
    for (int i = 0; i < 2; ++i)
#pragma unroll
      for (int j = 0; j < 2; ++j) {
        int n = m0 + wm * 32 + i * 16 + (l >> 4) * 4;
        int e = n0 + wn * 32 + j * 16 + lr;
        *(f32x4*)&M32[(size_t)e * NN + n] = acc[i][j];
        f16x4 v;
#pragma unroll
        for (int r = 0; r < 4; ++r) v[r] = (_Float16)acc[i][j][r];
        *(f16x4*)&M16[(size_t)e * NN + n] = v;
      }
  } else {  // ns2: b = bid - 832
    float* s0a = (float*)smA;
    float* s1a = s0a + 256;
    float* s2a = s0a + 512;
    int b = bid - 832;
    s0a[t] = wa[t];
    s1a[t] = wa[256 + t];
    s2a[t] = wa[512 + t];
    __syncthreads();
    float s0 = 0.f, s1 = 0.f, s2 = 0.f;
#pragma unroll 4
    for (int c = 0; c < 256; ++c) {
      const float* row;
      if (c < 96) row = x + ((size_t)b * 96 + c) * NN;
      else if (c < 192) row = m + ((size_t)b * 96 + (c - 96)) * NN;
      else row = hid + ((size_t)b * 64 + (c - 192)) * NN;
      float v = row[t];
      s0 += v * s0a[c];
      s1 += v * s1a[c];
      s2 += v * s2a[c];
    }
    float bv = bias[t];
    int idx = b * NN + t;
    node_sc[idx] = s0 + bv * wa[768];
    g1[idx] = s1 + bv * wa[769];
    g2[idx] = s2 + bv * wa[770];
  }
}

// ---- k_out1s: out1/out1T16 GEMM (3072 blocks) + score/att16 (768 blocks) ----
__global__ __launch_bounds__(256) void k_out1s(const _Float16* __restrict__ M16, const _Float16* __restrict__ hThi,
                                               float* __restrict__ out1, _Float16* __restrict__ out1T,
                                               const float* __restrict__ M32, const float* __restrict__ g1,
                                               const float* __restrict__ g2, const float* __restrict__ node_sc,
                                               const float* __restrict__ pri_e, const float* __restrict__ a2,
                                               const float* __restrict__ a3, const _Float16* __restrict__ incT,
                                               const float* __restrict__ inc, _Float16* __restrict__ att16) {
  __shared__ _Float16 smA[64 * 64];
  __shared__ _Float16 smB[64 * 64];
  int bid = blockIdx.x;
  int t = threadIdx.x;
  if (bid < 3072) {  // out1[b,e,d] = sum_n M16[e,n]*hThi[b,d,n]; 64e x 64d; b-pinned XCD
    int xcd = bid & 7, il = bid >> 3;
    int ep = il & 15, dblk = (il >> 4) & 3, bl = il >> 6;
    int b = xcd * 6 + bl;
    int e0 = ep * 64, d0 = dblk * 64;
    int w = t >> 6, l = t & 63;
    int wm = w >> 1, wn = w & 1;
    int lr = l & 15;
    const _Float16* A = M16 + (size_t)e0 * NN;
    const _Float16* Bp = hThi + ((size_t)b * DD + d0) * NN;
    int lrow = l >> 3;
    int scol = 8 * ((l & 7) ^ (lrow & 7));
    f32x4 acc[2][2];
    f32x4 z = {0.f, 0.f, 0.f, 0.f};
#pragma unroll
    for (int i = 0; i < 2; ++i)
#pragma unroll
      for (int j = 0; j < 2; ++j) acc[i][j] = z;
    for (int kk = 0; kk < NN; kk += 64) {
#pragma unroll
      for (int q = 0; q < 2; ++q) {
        int row = q * 32 + w * 8 + lrow;
        int lb = (q * 32 + w * 8) * 64;
        gload16(A + (size_t)row * NN + kk + scol, smA + lb);
        gload16(Bp + (size_t)row * NN + kk + scol, smB + lb);
      }
      __syncthreads();
      f16x8 af[2][2], bf[2][2];
#pragma unroll
      for (int i = 0; i < 2; ++i)
#pragma unroll
        for (int ks = 0; ks < 2; ++ks) {
          int ra = wm * 32 + i * 16 + lr;
          af[i][ks] = *(const f16x8*)&smA[ra * 64 + ((ks * 32 + (l >> 4) * 8) ^ ((ra & 7) << 3))];
          int rb = wn * 32 + i * 16 + lr;
          bf[i][ks] = *(const f16x8*)&smB[rb * 64 + ((ks * 32 + (l >> 4) * 8) ^ ((rb & 7) << 3))];
        }
#pragma unroll
      for (int ks = 0; ks < 2; ++ks)
#pragma unroll
        for (int i = 0; i < 2; ++i)
#pragma unroll
          for (int j = 0; j < 2; ++j)
            acc[i][j] = __builtin_amdgcn_mfma_f32_16x16x32_f16(af[i][ks], bf[j][ks], acc[i][j], 0, 0, 0);
      __syncthreads();
    }
#pragma unroll
    for (int i = 0; i < 2; ++i)
#pragma unroll
      for (int j = 0; j < 2; ++j) {
        int e = e0 + wm * 32 + i * 16 + (l >> 4) * 4;
        int d = d0 + wn * 32 + j * 16 + lr;
        f16x4 v16;
#pragma unroll
        for (int r = 0; r < 4; ++r) {
          out1[((size_t)b * EE + e + r) * DD + d] = acc[i][j][r];
          v16[r] = (_Float16)acc[i][j][r];
        }
        *(f16x4*)&out1T[((size_t)b * DD + d) * EE + e] = v16;
      }
  } else {  // score + att16
    float* sg1 = (float*)smA;                  // 256
    float* sg2 = sg1 + 256;                    // 256
    float* snc = sg2 + 256;                    // 256
    float(*r1)[4] = (float(*)[4])(snc + 256);  // 64*4
    float(*r2)[4] = r1 + 64;                   // 64*4
    float* sesc = (float*)(r2 + 64);           // 64
    float* steA = sesc + 64;                   // 64
    float* srm = steA + 64;                    // 64
    float* sri = srm + 64;                     // 64
    int sb = bid - 3072;
    int e0p = (sb & 15) * 64, b = sb >> 4;
    float a30 = a3[0], a31 = a3[1];
    sg1[t] = g1[b * NN + t];
    sg2[t] = g2[b * NN + t];
    snc[t] = node_sc[b * NN + t];
    __syncthreads();
    {  // phase 1: esc/te for 64 e's (fp32-exact via M32)
      int ei = t >> 2, part = t & 3;
      const float* Mr = M32 + (size_t)(e0p + ei) * NN + part * 64;
      const float* pg1 = sg1 + part * 64;
      const float* pg2 = sg2 + part * 64;
      float s1 = 0.f, s2 = 0.f;
      for (int i = 0; i < 64; i += 4) {
        f32x4 mv = *(const f32x4*)&Mr[i];
        f32x4 v1 = *(const f32x4*)&pg1[i];
        f32x4 v2 = *(const f32x4*)&pg2[i];
        s1 += mv[0] * v1[0] + mv[1] * v1[1] + mv[2] * v1[2] + mv[3] * v1[3];
        s2 += mv[0] * v2[0] + mv[1] * v2[1] + mv[2] * v2[2] + mv[3] * v2[3];
      }
      r1[ei][part] = s1;
      r2[ei][part] = s2;
    }
    __syncthreads();
    if (t < 64) {
      int row = b * EE + e0p + t;
      float es = r1[t][0] + r1[t][1] + r1[t][2] + r1[t][3];
      float te = lrelu(r2[t][0] + r2[t][1] + r2[t][2] + r2[t][3] + pri_e[row] * a2[DD]);
      sesc[t] = es;
      steA[t] = te * a30;
    }
    __syncthreads();
    {  // phase 2: masked max + exp-sum per e (wave per row)
      int w = t >> 6, l = t & 63;
      for (int rr = 0; rr < 16; ++rr) {
        int er = w * 16 + rr;
        int e = e0p + er;
        float es = sesc[er], ta = steA[er];
        f16x4 ic = *(const f16x4*)&incT[(size_t)e * NN + l * 4];
        float s2v[4];
        bool msk[4];
        float vmax = -3.0e38f;
#pragma unroll
        for (int q = 0; q < 4; ++q) {
          float s1 = lrelu(snc[l * 4 + q] + es);
          float s2 = lrelu(ta + s1 * a31);
          msk[q] = (float)ic[q] > 0.f;
          s2v[q] = s2;
          if (msk[q]) vmax = fmaxf(vmax, s2);
        }
#pragma unroll
        for (int off = 32; off > 0; off >>= 1) vmax = fmaxf(vmax, __shfl_xor(vmax, off));
        float ss = 0.f;
#pragma unroll
        for (int q = 0; q < 4; ++q)
          if (msk[q]) ss += __expf(s2v[q] - vmax);
#pragma unroll
        for (int off = 32; off > 0; off >>= 1) ss += __shfl_xor(ss, off);
        if (l == 0) {
          srm[er] = vmax;
          sri[er] = 1.0f / ss;
        }
      }
    }
    __syncthreads();
    {  // phase 3: emit att16[b, all n, e-panel] (fp16, linear layout)
      _Float16* ab = att16 + (size_t)b * NN * EE;
      int nb = t >> 2, eq = (t & 3) * 16;
#pragma unroll
      for (int rep = 0; rep < 4; ++rep) {
        int n = nb + rep * 64;
        float ns = snc[n];
#pragma unroll
        for (int q = 0; q < 4; ++q) {
          int er = eq + q * 4;
          float4 icv = *(const float4*)&inc[(size_t)n * EE + e0p + er];
          float ica[4] = {icv.x, icv.y, icv.z, icv.w};
          f16x4 o;
#pragma unroll
          for (int qq = 0; qq < 4; ++qq) {
            float att = 0.f;
            if (ica[qq] > 0.f) {
              float s1v = lrelu(ns + sesc[er + qq]);
              float s2v = lrelu(steA[er + qq] + s1v * a31);
              att = __expf(s2v - srm[er + qq]) * sri[er + qq];
            }
            o[qq] = (_Float16)att;
          }
          *(f16x4*)&ab[(size_t)n * EE + e0p + er] = o;
        }
      }
    }
  }
}

// out0[b,d,n] = sum_e att16[n,e]*out1T16[d,e]; pure fp16 MFMA GEMM; b-pinned XCD
__global__ __launch_bounds__(256) void k_fgemm(const _Float16* __restrict__ att16, const _Float16* __restrict__ out1T,
                                               float* __restrict__ out0) {
  __shared__ _Float16 smA[64 * 64];
  __shared__ _Float16 smB[64 * 64];
  int bid = blockIdx.x;
  int xcd = bid & 7, il = bid >> 3;  // 96 per XCD
  int ntile = il & 3, dtile = (il >> 2) & 3, bl = il >> 4;
  int b = xcd * 6 + bl;
  int n0 = ntile * 64, d0 = dtile * 64;
  int t = threadIdx.x, w = t >> 6, l = t & 63;
  int wm = w >> 1, wn = w & 1;
  int lr = l & 15;
  const _Float16* A = att16 + ((size_t)b * NN + n0) * EE;
  const _Float16* Bp = out1T + ((size_t)b * DD + d0) * EE;
  int lrow = l >> 3;
  int scol = 8 * ((l & 7) ^ (lrow & 7));
  f32x4 acc[2][2];
  f32x4 z = {0.f, 0.f, 0.f, 0.f};
#pragma unroll
  for (int i = 0; i < 2; ++i)
#pragma unroll
    for (int j = 0; j < 2; ++j) acc[i][j] = z;
  for (int kk = 0; kk < EE; kk += 64) {
#pragma unroll
    for (int q = 0; q < 2; ++q) {
      int row = q * 32 + w * 8 + lrow;
      int lb = (q * 32 + w * 8) * 64;
      gload16(A + (size_t)row * EE + kk + scol, smA + lb);
      gload16(Bp + (size_t)row * EE + kk + scol, smB + lb);
    }
    __syncthreads();
    f16x8 af[2][2], bf[2][2];
#pragma unroll
    for (int i = 0; i < 2; ++i)
#pragma unroll
      for (int ks = 0; ks < 2; ++ks) {
        int ra = wm * 32 + i * 16 + lr;
        af[i][ks] = *(const f16x8*)&smA[ra * 64 + ((ks * 32 + (l >> 4) * 8) ^ ((ra & 7) << 3))];
        int rb = wn * 32 + i * 16 + lr;
        bf[i][ks] = *(const f16x8*)&smB[rb * 64 + ((ks * 32 + (l >> 4) * 8) ^ ((rb & 7) << 3))];
      }
#pragma unroll
    for (int ks = 0; ks < 2; ++ks)
#pragma unroll
      for (int i = 0; i < 2; ++i)
#pragma unroll
        for (int j = 0; j < 2; ++j)
          acc[i][j] = __builtin_amdgcn_mfma_f32_16x16x32_f16(af[i][ks], bf[j][ks], acc[i][j], 0, 0, 0);
    __syncthreads();
  }
  float* ob = out0 + (size_t)b * DD * NN;
#pragma unroll
  for (int i = 0; i < 2; ++i)
#pragma unroll
    for (int j = 0; j < 2; ++j) {
      int n = n0 + wm * 32 + i * 16 + (l >> 4) * 4;
      int d = d0 + wn * 32 + j * 16 + lr;
      *(float4*)&ob[(size_t)d * NN + n] =
          make_float4(acc[i][j][0], acc[i][j][1], acc[i][j][2], acc[i][j][3]);
    }
}

extern "C" void kernel_launch(void* const* d_in, const int* in_sizes, int n_in, void* d_out, int out_size,
                              void* d_ws, size_t ws_size, hipStream_t stream) {
  (void)in_sizes;
  (void)n_in;
  (void)out_size;
  (void)ws_size;
  const float* x = (const float*)d_in[0];
  const float* m = (const float*)d_in[1];
  const float* hid = (const float*)d_in[2];
  const float* pri_e = (const float*)d_in[3];
  const float* inc = (const float*)d_in[5];
  const float* W = (const float*)d_in[6];
  const float* bias = (const float*)d_in[7];
  const float* W2 = (const float*)d_in[8];
  const float* a = (const float*)d_in[9];
  const float* a2 = (const float*)d_in[10];
  const float* a3 = (const float*)d_in[11];

  float* out0 = (float*)d_out;                // [B,D,N]
  float* out1 = out0 + (size_t)BB * DD * NN;  // [B,E,D] fp32 (written by k_out1s)
  _Float16* xt16 = (_Float16*)out1;           // [B,N,CIN] fp16 — dead after k_mid, before out1 written

  _Float16* out1T16 = (_Float16*)d_ws;                 // [B,D,E]
  _Float16* hThi = out1T16 + (size_t)BB * DD * EE;     // [B,D,N]
  _Float16* incT = hThi + (size_t)BB * DD * NN;        // [E,N]
  _Float16* w2shi = incT + (size_t)EE * NN;            // [E,E]
  _Float16* w2slo = w2shi + (size_t)EE * EE;           // [E,E]
  _Float16* inc16 = w2slo + (size_t)EE * EE;           // [N,E]
  _Float16* M16 = inc16 + (size_t)NN * EE;             // [E,N]
  _Float16* wt16 = M16 + (size_t)EE * NN;              // [D,CIN]
  _Float16* att16 = wt16 + (size_t)DD * CIN;           // [B,N,E]
  float* M32 = (float*)(att16 + (size_t)BB * NN * EE); // [E,N] fp32
  float* node_sc = M32 + (size_t)EE * NN;              // B*N
  float* g1 = node_sc + (size_t)BB * NN;               // B*N
  float* g2 = g1 + (size_t)BB * NN;                    // B*N
  float* wa = g2 + (size_t)BB * NN;                    // 1024

  k_prep<<<dim3(1376), 256, 0, stream>>>(inc, W2, W, x, m, hid, a, a2, incT, w2shi, w2slo, wt16, inc16, wa, xt16);
  k_mid<<<dim3(880), 256, 0, stream>>>(xt16, wt16, bias, hThi, inc16, w2shi, w2slo, M32, M16, x, m, hid, wa,
                                       node_sc, g1, g2);
  k_out1s<<<dim3(3072 + 768), 256, 0, stream>>>(M16, hThi, out1, out1T16, M32, g1, g2, node_sc, pri_e, a2, a3,
                                                incT, inc, att16);
  k_fgemm<<<dim3(8 * 96), 256, 0, stream>>>(att16, out1T16, out0);
}

// Round 14
// 113.351 us; speedup vs baseline: 1.7752x; 1.0216x over previous
//
#include <hip/hip_runtime.h>

#define BB 48
#define NN 256
#define EE 1024
#define DD 256
#define CIN 256

typedef __attribute__((ext_vector_type(4))) float f32x4;
typedef __attribute__((ext_vector_type(8))) _Float16 f16x8;
typedef __attribute__((ext_vector_type(4))) _Float16 f16x4;

__device__ __forceinline__ float lrelu(float t) { return t >= 0.0f ? t : 0.2f * t; }

__device__ __forceinline__ void gload16(const void* g, void* l) {
  __builtin_amdgcn_global_load_lds((const __attribute__((address_space(1))) void*)g,
                                   (__attribute__((address_space(3))) void*)l, 16, 0, 0);
}

// ---- k_prep: w2s hi/lo, incT, wt16, inc16, wa, xt (all input-only) ----
__global__ __launch_bounds__(256) void k_prep(const float* __restrict__ inc, const float* __restrict__ W2,
                                              const float* __restrict__ W, const float* __restrict__ x,
                                              const float* __restrict__ m, const float* __restrict__ hid,
                                              const float* __restrict__ a, const float* __restrict__ a2,
                                              _Float16* __restrict__ incT, _Float16* __restrict__ w2shi,
                                              _Float16* __restrict__ w2slo, _Float16* __restrict__ wt16,
                                              _Float16* __restrict__ inc16, float* __restrict__ wa,
                                              _Float16* __restrict__ xt) {
  __shared__ float tile[64][65];
  __shared__ float aux[4][64];
  __shared__ float aux2[64];
  int bid = blockIdx.x;
  int t = threadIdx.x;
  if (bid < 256) {  // w2s[e,f] = W2[f,e]*invdeg[f], hi/lo fp16 split
    int f0 = (bid & 15) * 64, e0 = (bid >> 4) * 64;
    int c = t & 63, r = t >> 6;
    {
      float s = 0.f;
      for (int i = 0; i < 64; ++i) s += inc[(size_t)(r * 64 + i) * EE + f0 + c];
      aux[r][c] = s;
    }
#pragma unroll
    for (int i = 0; i < 16; ++i) tile[r + i * 4][c] = W2[(size_t)(f0 + r + i * 4) * EE + e0 + c];
    __syncthreads();
    if (t < 64) aux2[t] = 1.0f / (aux[0][t] + aux[1][t] + aux[2][t] + aux[3][t]);
    __syncthreads();
#pragma unroll
    for (int i = 0; i < 16; ++i) {
      int row = r + i * 4;
      float v = tile[c][row] * aux2[c];
      _Float16 hh = (_Float16)v;
      w2shi[(size_t)(e0 + row) * EE + f0 + c] = hh;
      w2slo[(size_t)(e0 + row) * EE + f0 + c] = (_Float16)(v - (float)hh);
    }
  } else if (bid < 320) {  // incT[e,n] = inc[n,e]
    int s = bid - 256;
    int e0 = (s & 15) * 64, n0 = (s >> 4) * 64;
    int c = t & 63, r = t >> 6;
#pragma unroll
    for (int i = 0; i < 16; ++i) tile[r + i * 4][c] = inc[(size_t)(n0 + r + i * 4) * EE + e0 + c];
    __syncthreads();
#pragma unroll
    for (int i = 0; i < 16; ++i) {
      int row = r + i * 4;
      incT[(size_t)(e0 + row) * NN + n0 + c] = (_Float16)tile[c][row];
    }
  } else if (bid < 336) {  // wt16[d,c] = fp16(W[c,d])
    int s = bid - 320;
    int c0 = (s & 3) * 64, d0 = (s >> 2) * 64;
    int c = t & 63, r = t >> 6;
#pragma unroll
    for (int i = 0; i < 16; ++i) tile[r + i * 4][c] = W[(size_t)(c0 + r + i * 4) * DD + d0 + c];
    __syncthreads();
#pragma unroll
    for (int i = 0; i < 16; ++i) {
      int row = r + i * 4;
      wt16[(size_t)(d0 + row) * CIN + c0 + c] = (_Float16)tile[c][row];
    }
  } else if (bid < 352) {  // inc16[n,f] = fp16(inc) (exact 0/1)
    int s = bid - 336;
    size_t base = ((size_t)s * 256 + t) * 64;
#pragma unroll
    for (int i = 0; i < 16; ++i) {
      f32x4 v = *(const f32x4*)&inc[base + i * 4];
      f16x4 o;
      o[0] = (_Float16)v[0];
      o[1] = (_Float16)v[1];
      o[2] = (_Float16)v[2];
      o[3] = (_Float16)v[3];
      *(f16x4*)&inc16[base + i * 4] = o;
    }
  } else if (bid < 608) {  // wa
    float(*red)[4] = (float(*)[4])aux;
    int c = bid - 352;
    int l = t & 63, wv = t >> 6;
    float w = W[(size_t)c * DD + t];
    float p0 = w * a[t], p1 = w * a[DD + t], p2 = w * a2[t];
#pragma unroll
    for (int off = 32; off > 0; off >>= 1) {
      p0 += __shfl_down(p0, off);
      p1 += __shfl_down(p1, off);
      p2 += __shfl_down(p2, off);
    }
    if (l == 0) {
      red[0][wv] = p0;
      red[1][wv] = p1;
      red[2][wv] = p2;
    }
    __syncthreads();
    if (t == 0) wa[c] = red[0][0] + red[0][1] + red[0][2] + red[0][3];
    if (t == 1) wa[256 + c] = red[1][0] + red[1][1] + red[1][2] + red[1][3];
    if (t == 2) wa[512 + c] = red[2][0] + red[2][1] + red[2][2] + red[2][3];
    if (c == 0) {
      __syncthreads();
      float q0 = a[t], q1 = a[DD + t], q2 = a2[t];
#pragma unroll
      for (int off = 32; off > 0; off >>= 1) {
        q0 += __shfl_down(q0, off);
        q1 += __shfl_down(q1, off);
        q2 += __shfl_down(q2, off);
      }
      if (l == 0) {
        red[0][wv] = q0;
        red[1][wv] = q1;
        red[2][wv] = q2;
      }
      __syncthreads();
      if (t == 0) wa[768] = red[0][0] + red[0][1] + red[0][2] + red[0][3];
      if (t == 1) wa[769] = red[1][0] + red[1][1] + red[1][2] + red[1][3];
      if (t == 2) wa[770] = red[2][0] + red[2][1] + red[2][2] + red[2][3];
    }
  } else {  // xt16[b,n,c] = fp16(x_in[b,c,n]); 768 blocks
    int s = bid - 608;
    int c0 = (s & 3) * 64, n0 = ((s >> 2) & 3) * 64, b = s >> 4;
    int c = t & 63, r = t >> 6;
#pragma unroll
    for (int i = 0; i < 16; ++i) {
      int ch = c0 + r + i * 4;
      const float* row;
      if (ch < 96) row = x + ((size_t)b * 96 + ch) * NN;
      else if (ch < 192) row = m + ((size_t)b * 96 + (ch - 96)) * NN;
      else row = hid + ((size_t)b * 64 + (ch - 192)) * NN;
      tile[r + i * 4][c] = row[n0 + c];
    }
    __syncthreads();
#pragma unroll
    for (int i = 0; i < 16; ++i) {
      int row = r + i * 4;
      xt[((size_t)b * NN + n0 + row) * CIN + c0 + c] = (_Float16)tile[c][row];
    }
  }
}

// ---- k_mid: h16 (768) + M32/M16 2-term split MFMA (64) + ns2 (48) ----
__global__ __launch_bounds__(256) void k_mid(const _Float16* __restrict__ xt, const _Float16* __restrict__ wt,
                                             const float* __restrict__ bias, _Float16* __restrict__ hThi,
                                             const _Float16* __restrict__ inc16, const _Float16* __restrict__ w2shi,
                                             const _Float16* __restrict__ w2slo, float* __restrict__ M32,
                                             _Float16* __restrict__ M16, const float* __restrict__ x,
                                             const float* __restrict__ m, const float* __restrict__ hid,
                                             const float* __restrict__ wa, float* __restrict__ node_sc,
                                             float* __restrict__ g1, float* __restrict__ g2) {
  __shared__ _Float16 smA[64 * 64];
  __shared__ _Float16 smB[64 * 64];
  __shared__ _Float16 smB2[64 * 64];
  int bid = blockIdx.x;
  int t = threadIdx.x;
  if (bid < 768) {  // h16
    int xcd = bid & 7, il = bid >> 3;
    int ntile = il & 3, dtile = (il >> 2) & 3, bl = il >> 4;
    int b = xcd * 6 + bl;
    int n0 = ntile * 64, d0 = dtile * 64;
    int w = t >> 6, l = t & 63;
    int wm = w >> 1, wn = w & 1;
    int lr = l & 15;
    const _Float16* A = xt + ((size_t)b * NN + n0) * CIN;
    const _Float16* Bp = wt + (size_t)d0 * CIN;
    int lrow = l >> 3;
    int scol = 8 * ((l & 7) ^ (lrow & 7));
    f32x4 acc[2][2];
    f32x4 z = {0.f, 0.f, 0.f, 0.f};
#pragma unroll
    for (int i = 0; i < 2; ++i)
#pragma unroll
      for (int j = 0; j < 2; ++j) acc[i][j] = z;
    for (int kk = 0; kk < CIN; kk += 64) {
#pragma unroll
      for (int q = 0; q < 2; ++q) {
        int row = q * 32 + w * 8 + lrow;
        int lb = (q * 32 + w * 8) * 64;
        gload16(A + (size_t)row * CIN + kk + scol, smA + lb);
        gload16(Bp + (size_t)row * CIN + kk + scol, smB + lb);
      }
      __syncthreads();
      f16x8 af[2][2], bf[2][2];
#pragma unroll
      for (int i = 0; i < 2; ++i)
#pragma unroll
        for (int ks = 0; ks < 2; ++ks) {
          int ra = wm * 32 + i * 16 + lr;
          af[i][ks] = *(const f16x8*)&smA[ra * 64 + ((ks * 32 + (l >> 4) * 8) ^ ((ra & 7) << 3))];
          int rb = wn * 32 + i * 16 + lr;
          bf[i][ks] = *(const f16x8*)&smB[rb * 64 + ((ks * 32 + (l >> 4) * 8) ^ ((rb & 7) << 3))];
        }
#pragma unroll
      for (int ks = 0; ks < 2; ++ks)
#pragma unroll
        for (int i = 0; i < 2; ++i)
#pragma unroll
          for (int j = 0; j < 2; ++j)
            acc[i][j] = __builtin_amdgcn_mfma_f32_16x16x32_f16(af[i][ks], bf[j][ks], acc[i][j], 0, 0, 0);
      __syncthreads();
    }
#pragma unroll
    for (int i = 0; i < 2; ++i)
#pragma unroll
      for (int j = 0; j < 2; ++j) {
        int nb = n0 + wm * 32 + i * 16 + (l >> 4) * 4;
        int d = d0 + wn * 32 + j * 16 + lr;
        float4 bv = *(const float4*)&bias[nb];
        f16x4 vh;
        vh[0] = (_Float16)(acc[i][j][0] + bv.x);
        vh[1] = (_Float16)(acc[i][j][1] + bv.y);
        vh[2] = (_Float16)(acc[i][j][2] + bv.z);
        vh[3] = (_Float16)(acc[i][j][3] + bv.w);
        *(f16x4*)&hThi[((size_t)b * DD + d) * NN + nb] = vh;
      }
  } else if (bid < 832) {  // M32/M16[e,n] = sum_f inc16[n,f]*(w2shi+w2slo)[e,f]; 64 blocks
    int mb = bid - 768;
    int np = mb & 3, ep = mb >> 2;
    int m0 = np * 64;
    int n0 = ep * 64;
    int w = t >> 6, l = t & 63;
    int wm = w >> 1, wn = w & 1;
    int lr = l & 15;
    const _Float16* A = inc16 + (size_t)m0 * EE;
    const _Float16* Bh = w2shi + (size_t)n0 * EE;
    const _Float16* Bl = w2slo + (size_t)n0 * EE;
    int lrow = l >> 3;
    int scol = 8 * ((l & 7) ^ (lrow & 7));
    f32x4 acc[2][2];
    f32x4 z = {0.f, 0.f, 0.f, 0.f};
#pragma unroll
    for (int i = 0; i < 2; ++i)
#pragma unroll
      for (int j = 0; j < 2; ++j) acc[i][j] = z;
    for (int kk = 0; kk < EE; kk += 64) {
#pragma unroll
      for (int q = 0; q < 2; ++q) {
        int row = q * 32 + w * 8 + lrow;
        int lb = (q * 32 + w * 8) * 64;
        gload16(A + (size_t)row * EE + kk + scol, smA + lb);
        gload16(Bh + (size_t)row * EE + kk + scol, smB + lb);
        gload16(Bl + (size_t)row * EE + kk + scol, smB2 + lb);
      }
      __syncthreads();
      f16x8 af[2][2], bfh[2][2], bfl[2][2];
#pragma unroll
      for (int i = 0; i < 2; ++i)
#pragma unroll
        for (int ks = 0; ks < 2; ++ks) {
          int ra = wm * 32 + i * 16 + lr;
          int off_a = ra * 64 + ((ks * 32 + (l >> 4) * 8) ^ ((ra & 7) << 3));
          af[i][ks] = *(const f16x8*)&smA[off_a];
          int rb = wn * 32 + i * 16 + lr;
          int off_b = rb * 64 + ((ks * 32 + (l >> 4) * 8) ^ ((rb & 7) << 3));
          bfh[i][ks] = *(const f16x8*)&smB[off_b];
          bfl[i][ks] = *(const f16x8*)&smB2[off_b];
        }
#pragma unroll
      for (int ks = 0; ks < 2; ++ks)
#pragma unroll
        for (int i = 0; i < 2; ++i)
#pragma unroll
          for (int j = 0; j < 2; ++j) {
            acc[i][j] = __builtin_amdgcn_mfma_f32_16x16x32_f16(af[i][ks], bfh[j][ks], acc[i][j], 0, 0, 0);
            acc[i][j] = __builtin_amdgcn_mfma_f32_16x16x32_f16(af[i][ks], bfl[j][ks], acc[i][j], 0, 0, 0);
          }
      __syncthreads();
    }
#pragma unroll
    for (int i = 0; i < 2; ++i)
#pragma unroll
      for (int j = 0; j < 2; ++j) {
        int n = m0 + wm * 32 + i * 16 + (l >> 4) * 4;
        int e = n0 + wn * 32 + j * 16 + lr;
        *(f32x4*)&M32[(size_t)e * NN + n] = acc[i][j];
        f16x4 v;
#pragma unroll
        for (int r = 0; r < 4; ++r) v[r] = (_Float16)acc[i][j][r];
        *(f16x4*)&M16[(size_t)e * NN + n] = v;
      }
  } else {  // ns2: b = bid - 832
    float* s0a = (float*)smA;
    float* s1a = s0a + 256;
    float* s2a = s0a + 512;
    int b = bid - 832;
    s0a[t] = wa[t];
    s1a[t] = wa[256 + t];
    s2a[t] = wa[512 + t];
    __syncthreads();
    float s0 = 0.f, s1 = 0.f, s2 = 0.f;
#pragma unroll 4
    for (int c = 0; c < 256; ++c) {
      const float* row;
      if (c < 96) row = x + ((size_t)b * 96 + c) * NN;
      else if (c < 192) row = m + ((size_t)b * 96 + (c - 96)) * NN;
      else row = hid + ((size_t)b * 64 + (c - 192)) * NN;
      float v = row[t];
      s0 += v * s0a[c];
      s1 += v * s1a[c];
      s2 += v * s2a[c];
    }
    float bv = bias[t];
    int idx = b * NN + t;
    node_sc[idx] = s0 + bv * wa[768];
    g1[idx] = s1 + bv * wa[769];
    g2[idx] = s2 + bv * wa[770];
  }
}

// ---- k_out1s: out1/out1T16 GEMM (3072 blocks) + score/att16 (768 blocks) ----
__global__ __launch_bounds__(256) void k_out1s(const _Float16* __restrict__ M16, const _Float16* __restrict__ hThi,
                                               float* __restrict__ out1, _Float16* __restrict__ out1T,
                                               const float* __restrict__ M32, const float* __restrict__ g1,
                                               const float* __restrict__ g2, const float* __restrict__ node_sc,
                                               const float* __restrict__ pri_e, const float* __restrict__ a2,
                                               const float* __restrict__ a3, const _Float16* __restrict__ incT,
                                               const float* __restrict__ inc, _Float16* __restrict__ att16) {
  __shared__ _Float16 smA[64 * 64];
  __shared__ _Float16 smB[64 * 64];
  int bid = blockIdx.x;
  int t = threadIdx.x;
  if (bid < 3072) {  // out1[b,e,d] = sum_n M16[e,n]*hThi[b,d,n]; 64e x 64d; b-pinned XCD
    int xcd = bid & 7, il = bid >> 3;
    int ep = il & 15, dblk = (il >> 4) & 3, bl = il >> 6;
    int b = xcd * 6 + bl;
    int e0 = ep * 64, d0 = dblk * 64;
    int w = t >> 6, l = t & 63;
    int wm = w >> 1, wn = w & 1;
    int lr = l & 15;
    const _Float16* A = M16 + (size_t)e0 * NN;
    const _Float16* Bp = hThi + ((size_t)b * DD + d0) * NN;
    int lrow = l >> 3;
    int scol = 8 * ((l & 7) ^ (lrow & 7));
    f32x4 acc[2][2];
    f32x4 z = {0.f, 0.f, 0.f, 0.f};
#pragma unroll
    for (int i = 0; i < 2; ++i)
#pragma unroll
      for (int j = 0; j < 2; ++j) acc[i][j] = z;
    for (int kk = 0; kk < NN; kk += 64) {
#pragma unroll
      for (int q = 0; q < 2; ++q) {
        int row = q * 32 + w * 8 + lrow;
        int lb = (q * 32 + w * 8) * 64;
        gload16(A + (size_t)row * NN + kk + scol, smA + lb);
        gload16(Bp + (size_t)row * NN + kk + scol, smB + lb);
      }
      __syncthreads();
      f16x8 af[2][2], bf[2][2];
#pragma unroll
      for (int i = 0; i < 2; ++i)
#pragma unroll
        for (int ks = 0; ks < 2; ++ks) {
          int ra = wm * 32 + i * 16 + lr;
          af[i][ks] = *(const f16x8*)&smA[ra * 64 + ((ks * 32 + (l >> 4) * 8) ^ ((ra & 7) << 3))];
          int rb = wn * 32 + i * 16 + lr;
          bf[i][ks] = *(const f16x8*)&smB[rb * 64 + ((ks * 32 + (l >> 4) * 8) ^ ((rb & 7) << 3))];
        }
#pragma unroll
      for (int ks = 0; ks < 2; ++ks)
#pragma unroll
        for (int i = 0; i < 2; ++i)
#pragma unroll
          for (int j = 0; j < 2; ++j)
            acc[i][j] = __builtin_amdgcn_mfma_f32_16x16x32_f16(af[i][ks], bf[j][ks], acc[i][j], 0, 0, 0);
      __syncthreads();
    }
    // out1 fp32 direct stores (64B-coalesced segments)
#pragma unroll
    for (int i = 0; i < 2; ++i)
#pragma unroll
      for (int j = 0; j < 2; ++j) {
        int e = e0 + wm * 32 + i * 16 + (l >> 4) * 4;
        int d = d0 + wn * 32 + j * 16 + lr;
#pragma unroll
        for (int r = 0; r < 4; ++r) out1[((size_t)b * EE + e + r) * DD + d] = acc[i][j][r];
      }
    // out1T16 via LDS staging -> coalesced 16B stores
#pragma unroll
    for (int i = 0; i < 2; ++i)
#pragma unroll
      for (int j = 0; j < 2; ++j) {
        int dr = wn * 32 + j * 16 + lr;
        int er = wm * 32 + i * 16 + (l >> 4) * 4;
        f16x4 v16;
#pragma unroll
        for (int r = 0; r < 4; ++r) v16[r] = (_Float16)acc[i][j][r];
        *(f16x4*)&smA[dr * 64 + (er ^ ((dr & 7) << 3))] = v16;
      }
    __syncthreads();
    {
      int dr = t >> 2, ec = (t & 3) * 16;
      _Float16* orow = out1T + ((size_t)b * DD + d0 + dr) * EE + e0;
#pragma unroll
      for (int g = 0; g < 2; ++g) {
        int e8 = ec + g * 8;
        f16x8 v = *(const f16x8*)&smA[dr * 64 + (e8 ^ ((dr & 7) << 3))];
        *(f16x8*)&orow[e8] = v;
      }
    }
  } else {  // score + att16
    float* sg1 = (float*)smA;                  // 256
    float* sg2 = sg1 + 256;                    // 256
    float* snc = sg2 + 256;                    // 256
    float(*r1)[4] = (float(*)[4])(snc + 256);  // 64*4
    float(*r2)[4] = r1 + 64;                   // 64*4
    float* sesc = (float*)(r2 + 64);           // 64
    float* steA = sesc + 64;                   // 64
    float* srm = steA + 64;                    // 64
    float* sri = srm + 64;                     // 64
    int sb = bid - 3072;
    int e0p = (sb & 15) * 64, b = sb >> 4;
    float a30 = a3[0], a31 = a3[1];
    sg1[t] = g1[b * NN + t];
    sg2[t] = g2[b * NN + t];
    snc[t] = node_sc[b * NN + t];
    __syncthreads();
    {  // phase 1: esc/te for 64 e's (fp32-exact via M32)
      int ei = t >> 2, part = t & 3;
      const float* Mr = M32 + (size_t)(e0p + ei) * NN + part * 64;
      const float* pg1 = sg1 + part * 64;
      const float* pg2 = sg2 + part * 64;
      float s1 = 0.f, s2 = 0.f;
      for (int i = 0; i < 64; i += 4) {
        f32x4 mv = *(const f32x4*)&Mr[i];
        f32x4 v1 = *(const f32x4*)&pg1[i];
        f32x4 v2 = *(const f32x4*)&pg2[i];
        s1 += mv[0] * v1[0] + mv[1] * v1[1] + mv[2] * v1[2] + mv[3] * v1[3];
        s2 += mv[0] * v2[0] + mv[1] * v2[1] + mv[2] * v2[2] + mv[3] * v2[3];
      }
      r1[ei][part] = s1;
      r2[ei][part] = s2;
    }
    __syncthreads();
    if (t < 64) {
      int row = b * EE + e0p + t;
      float es = r1[t][0] + r1[t][1] + r1[t][2] + r1[t][3];
      float te = lrelu(r2[t][0] + r2[t][1] + r2[t][2] + r2[t][3] + pri_e[row] * a2[DD]);
      sesc[t] = es;
      steA[t] = te * a30;
    }
    __syncthreads();
    {  // phase 2: masked max + exp-sum per e (wave per row)
      int w = t >> 6, l = t & 63;
      for (int rr = 0; rr < 16; ++rr) {
        int er = w * 16 + rr;
        int e = e0p + er;
        float es = sesc[er], ta = steA[er];
        f16x4 ic = *(const f16x4*)&incT[(size_t)e * NN + l * 4];
        float s2v[4];
        bool msk[4];
        float vmax = -3.0e38f;
#pragma unroll
        for (int q = 0; q < 4; ++q) {
          float s1 = lrelu(snc[l * 4 + q] + es);
          float s2 = lrelu(ta + s1 * a31);
          msk[q] = (float)ic[q] > 0.f;
          s2v[q] = s2;
          if (msk[q]) vmax = fmaxf(vmax, s2);
        }
#pragma unroll
        for (int off = 32; off > 0; off >>= 1) vmax = fmaxf(vmax, __shfl_xor(vmax, off));
        float ss = 0.f;
#pragma unroll
        for (int q = 0; q < 4; ++q)
          if (msk[q]) ss += __expf(s2v[q] - vmax);
#pragma unroll
        for (int off = 32; off > 0; off >>= 1) ss += __shfl_xor(ss, off);
        if (l == 0) {
          srm[er] = vmax;
          sri[er] = 1.0f / ss;
        }
      }
    }
    __syncthreads();
    {  // phase 3: emit att16 — f16x8 coalesced (8 lanes = 128B row segment)
      _Float16* ab = att16 + (size_t)b * NN * EE;
      int nb = t >> 3, el = (t & 7) * 8;
#pragma unroll
      for (int rep = 0; rep < 8; ++rep) {
        int n = nb + rep * 32;
        float ns = snc[n];
        float4 icv0 = *(const float4*)&inc[(size_t)n * EE + e0p + el];
        float4 icv1 = *(const float4*)&inc[(size_t)n * EE + e0p + el + 4];
        float ica[8] = {icv0.x, icv0.y, icv0.z, icv0.w, icv1.x, icv1.y, icv1.z, icv1.w};
        f16x8 o;
#pragma unroll
        for (int qq = 0; qq < 8; ++qq) {
          float att = 0.f;
          if (ica[qq] > 0.f) {
            float s1v = lrelu(ns + sesc[el + qq]);
            float s2v = lrelu(steA[el + qq] + s1v * a31);
            att = __expf(s2v - srm[el + qq]) * sri[el + qq];
          }
          o[qq] = (_Float16)att;
        }
        *(f16x8*)&ab[(size_t)n * EE + e0p + el] = o;
      }
    }
  }
}

// out0[b,d,n] = sum_e att16[n,e]*out1T16[d,e]; pure fp16 MFMA GEMM; b-pinned XCD
__global__ __launch_bounds__(256) void k_fgemm(const _Float16* __restrict__ att16, const _Float16* __restrict__ out1T,
                                               float* __restrict__ out0) {
  __shared__ _Float16 smA[64 * 64];
  __shared__ _Float16 smB[64 * 64];
  int bid = blockIdx.x;
  int xcd = bid & 7, il = bid >> 3;  // 96 per XCD
  int ntile = il & 3, dtile = (il >> 2) & 3, bl = il >> 4;
  int b = xcd * 6 + bl;
  int n0 = ntile * 64, d0 = dtile * 64;
  int t = threadIdx.x, w = t >> 6, l = t & 63;
  int wm = w >> 1, wn = w & 1;
  int lr = l & 15;
  const _Float16* A = att16 + ((size_t)b * NN + n0) * EE;
  const _Float16* Bp = out1T + ((size_t)b * DD + d0) * EE;
  int lrow = l >> 3;
  int scol = 8 * ((l & 7) ^ (lrow & 7));
  f32x4 acc[2][2];
  f32x4 z = {0.f, 0.f, 0.f, 0.f};
#pragma unroll
  for (int i = 0; i < 2; ++i)
#pragma unroll
    for (int j = 0; j < 2; ++j) acc[i][j] = z;
  for (int kk = 0; kk < EE; kk += 64) {
#pragma unroll
    for (int q = 0; q < 2; ++q) {
      int row = q * 32 + w * 8 + lrow;
      int lb = (q * 32 + w * 8) * 64;
      gload16(A + (size_t)row * EE + kk + scol, smA + lb);
      gload16(Bp + (size_t)row * EE + kk + scol, smB + lb);
    }
    __syncthreads();
    f16x8 af[2][2], bf[2][2];
#pragma unroll
    for (int i = 0; i < 2; ++i)
#pragma unroll
      for (int ks = 0; ks < 2; ++ks) {
        int ra = wm * 32 + i * 16 + lr;
        af[i][ks] = *(const f16x8*)&smA[ra * 64 + ((ks * 32 + (l >> 4) * 8) ^ ((ra & 7) << 3))];
        int rb = wn * 32 + i * 16 + lr;
        bf[i][ks] = *(const f16x8*)&smB[rb * 64 + ((ks * 32 + (l >> 4) * 8) ^ ((rb & 7) << 3))];
      }
#pragma unroll
    for (int ks = 0; ks < 2; ++ks)
#pragma unroll
      for (int i = 0; i < 2; ++i)
#pragma unroll
        for (int j = 0; j < 2; ++j)
          acc[i][j] = __builtin_amdgcn_mfma_f32_16x16x32_f16(af[i][ks], bf[j][ks], acc[i][j], 0, 0, 0);
    __syncthreads();
  }
  float* ob = out0 + (size_t)b * DD * NN;
#pragma unroll
  for (int i = 0; i < 2; ++i)
#pragma unroll
    for (int j = 0; j < 2; ++j) {
      int n = n0 + wm * 32 + i * 16 + (l >> 4) * 4;
      int d = d0 + wn * 32 + j * 16 + lr;
      *(float4*)&ob[(size_t)d * NN + n] =
          make_float4(acc[i][j][0], acc[i][j][1], acc[i][j][2], acc[i][j][3]);
    }
}

extern "C" void kernel_launch(void* const* d_in, const int* in_sizes, int n_in, void* d_out, int out_size,
                              void* d_ws, size_t ws_size, hipStream_t stream) {
  (void)in_sizes;
  (void)n_in;
  (void)out_size;
  (void)ws_size;
  const float* x = (const float*)d_in[0];
  const float* m = (const float*)d_in[1];
  const float* hid = (const float*)d_in[2];
  const float* pri_e = (const float*)d_in[3];
  const float* inc = (const float*)d_in[5];
  const float* W = (const float*)d_in[6];
  const float* bias = (const float*)d_in[7];
  const float* W2 = (const float*)d_in[8];
  const float* a = (const float*)d_in[9];
  const float* a2 = (const float*)d_in[10];
  const float* a3 = (const float*)d_in[11];

  float* out0 = (float*)d_out;                // [B,D,N]
  float* out1 = out0 + (size_t)BB * DD * NN;  // [B,E,D] fp32 (written by k_out1s)
  _Float16* xt16 = (_Float16*)out1;           // [B,N,CIN] fp16 — dead after k_mid, before out1 written

  _Float16* out1T16 = (_Float16*)d_ws;                 // [B,D,E]
  _Float16* hThi = out1T16 + (size_t)BB * DD * EE;     // [B,D,N]
  _Float16* incT = hThi + (size_t)BB * DD * NN;        // [E,N]
  _Float16* w2shi = incT + (size_t)EE * NN;            // [E,E]
  _Float16* w2slo = w2shi + (size_t)EE * EE;           // [E,E]
  _Float16* inc16 = w2slo + (size_t)EE * EE;           // [N,E]
  _Float16* M16 = inc16 + (size_t)NN * EE;             // [E,N]
  _Float16* wt16 = M16 + (size_t)EE * NN;              // [D,CIN]
  _Float16* att16 = wt16 + (size_t)DD * CIN;           // [B,N,E]
  float* M32 = (float*)(att16 + (size_t)BB * NN * EE); // [E,N] fp32
  float* node_sc = M32 + (size_t)EE * NN;              // B*N
  float* g1 = node_sc + (size_t)BB * NN;               // B*N
  float* g2 = g1 + (size_t)BB * NN;                    // B*N
  float* wa = g2 + (size_t)BB * NN;                    // 1024

  k_prep<<<dim3(1376), 256, 0, stream>>>(inc, W2, W, x, m, hid, a, a2, incT, w2shi, w2slo, wt16, inc16, wa, xt16);
  k_mid<<<dim3(880), 256, 0, stream>>>(xt16, wt16, bias, hThi, inc16, w2shi, w2slo, M32, M16, x, m, hid, wa,
                                       node_sc, g1, g2);
  k_out1s<<<dim3(3072 + 768), 256, 0, stream>>>(M16, hThi, out1, out1T16, M32, g1, g2, node_sc, pri_e, a2, a3,
                                                incT, inc, att16);
  k_fgemm<<<dim3(8 * 96), 256, 0, stream>>>(att16, out1T16, out0);
}

// Round 15
// 112.886 us; speedup vs baseline: 1.7825x; 1.0041x over previous
//
#include <hip/hip_runtime.h>

#define BB 48
#define NN 256
#define EE 1024
#define DD 256
#define CIN 256

typedef __attribute__((ext_vector_type(4))) float f32x4;
typedef __attribute__((ext_vector_type(8))) _Float16 f16x8;
typedef __attribute__((ext_vector_type(4))) _Float16 f16x4;

__device__ __forceinline__ float lrelu(float t) { return t >= 0.0f ? t : 0.2f * t; }

__device__ __forceinline__ void gload16(const void* g, void* l) {
  __builtin_amdgcn_global_load_lds((const __attribute__((address_space(1))) void*)g,
                                   (__attribute__((address_space(3))) void*)l, 16, 0, 0);
}

// ---- k_prep: w2s hi/lo, incT, wt16, inc16, wa, xt (all input-only) ----
__global__ __launch_bounds__(256) void k_prep(const float* __restrict__ inc, const float* __restrict__ W2,
                                              const float* __restrict__ W, const float* __restrict__ x,
                                              const float* __restrict__ m, const float* __restrict__ hid,
                                              const float* __restrict__ a, const float* __restrict__ a2,
                                              _Float16* __restrict__ incT, _Float16* __restrict__ w2shi,
                                              _Float16* __restrict__ w2slo, _Float16* __restrict__ wt16,
                                              _Float16* __restrict__ inc16, float* __restrict__ wa,
                                              _Float16* __restrict__ xt) {
  __shared__ float tile[64][65];
  __shared__ float aux[4][64];
  __shared__ float aux2[64];
  int bid = blockIdx.x;
  int t = threadIdx.x;
  if (bid < 256) {  // w2s[e,f] = W2[f,e]*invdeg[f], hi/lo fp16 split
    int f0 = (bid & 15) * 64, e0 = (bid >> 4) * 64;
    int c = t & 63, r = t >> 6;
    {
      float s = 0.f;
      for (int i = 0; i < 64; ++i) s += inc[(size_t)(r * 64 + i) * EE + f0 + c];
      aux[r][c] = s;
    }
#pragma unroll
    for (int i = 0; i < 16; ++i) tile[r + i * 4][c] = W2[(size_t)(f0 + r + i * 4) * EE + e0 + c];
    __syncthreads();
    if (t < 64) aux2[t] = 1.0f / (aux[0][t] + aux[1][t] + aux[2][t] + aux[3][t]);
    __syncthreads();
#pragma unroll
    for (int i = 0; i < 16; ++i) {
      int row = r + i * 4;
      float v = tile[c][row] * aux2[c];
      _Float16 hh = (_Float16)v;
      w2shi[(size_t)(e0 + row) * EE + f0 + c] = hh;
      w2slo[(size_t)(e0 + row) * EE + f0 + c] = (_Float16)(v - (float)hh);
    }
  } else if (bid < 320) {  // incT[e,n] = inc[n,e]
    int s = bid - 256;
    int e0 = (s & 15) * 64, n0 = (s >> 4) * 64;
    int c = t & 63, r = t >> 6;
#pragma unroll
    for (int i = 0; i < 16; ++i) tile[r + i * 4][c] = inc[(size_t)(n0 + r + i * 4) * EE + e0 + c];
    __syncthreads();
#pragma unroll
    for (int i = 0; i < 16; ++i) {
      int row = r + i * 4;
      incT[(size_t)(e0 + row) * NN + n0 + c] = (_Float16)tile[c][row];
    }
  } else if (bid < 336) {  // wt16[d,c] = fp16(W[c,d])
    int s = bid - 320;
    int c0 = (s & 3) * 64, d0 = (s >> 2) * 64;
    int c = t & 63, r = t >> 6;
#pragma unroll
    for (int i = 0; i < 16; ++i) tile[r + i * 4][c] = W[(size_t)(c0 + r + i * 4) * DD + d0 + c];
    __syncthreads();
#pragma unroll
    for (int i = 0; i < 16; ++i) {
      int row = r + i * 4;
      wt16[(size_t)(d0 + row) * CIN + c0 + c] = (_Float16)tile[c][row];
    }
  } else if (bid < 352) {  // inc16[n,f] = fp16(inc) (exact 0/1)
    int s = bid - 336;
    size_t base = ((size_t)s * 256 + t) * 64;
#pragma unroll
    for (int i = 0; i < 16; ++i) {
      f32x4 v = *(const f32x4*)&inc[base + i * 4];
      f16x4 o;
      o[0] = (_Float16)v[0];
      o[1] = (_Float16)v[1];
      o[2] = (_Float16)v[2];
      o[3] = (_Float16)v[3];
      *(f16x4*)&inc16[base + i * 4] = o;
    }
  } else if (bid < 608) {  // wa
    float(*red)[4] = (float(*)[4])aux;
    int c = bid - 352;
    int l = t & 63, wv = t >> 6;
    float w = W[(size_t)c * DD + t];
    float p0 = w * a[t], p1 = w * a[DD + t], p2 = w * a2[t];
#pragma unroll
    for (int off = 32; off > 0; off >>= 1) {
      p0 += __shfl_down(p0, off);
      p1 += __shfl_down(p1, off);
      p2 += __shfl_down(p2, off);
    }
    if (l == 0) {
      red[0][wv] = p0;
      red[1][wv] = p1;
      red[2][wv] = p2;
    }
    __syncthreads();
    if (t == 0) wa[c] = red[0][0] + red[0][1] + red[0][2] + red[0][3];
    if (t == 1) wa[256 + c] = red[1][0] + red[1][1] + red[1][2] + red[1][3];
    if (t == 2) wa[512 + c] = red[2][0] + red[2][1] + red[2][2] + red[2][3];
    if (c == 0) {
      __syncthreads();
      float q0 = a[t], q1 = a[DD + t], q2 = a2[t];
#pragma unroll
      for (int off = 32; off > 0; off >>= 1) {
        q0 += __shfl_down(q0, off);
        q1 += __shfl_down(q1, off);
        q2 += __shfl_down(q2, off);
      }
      if (l == 0) {
        red[0][wv] = q0;
        red[1][wv] = q1;
        red[2][wv] = q2;
      }
      __syncthreads();
      if (t == 0) wa[768] = red[0][0] + red[0][1] + red[0][2] + red[0][3];
      if (t == 1) wa[769] = red[1][0] + red[1][1] + red[1][2] + red[1][3];
      if (t == 2) wa[770] = red[2][0] + red[2][1] + red[2][2] + red[2][3];
    }
  } else {  // xt16[b,n,c] = fp16(x_in[b,c,n]); 768 blocks
    int s = bid - 608;
    int c0 = (s & 3) * 64, n0 = ((s >> 2) & 3) * 64, b = s >> 4;
    int c = t & 63, r = t >> 6;
#pragma unroll
    for (int i = 0; i < 16; ++i) {
      int ch = c0 + r + i * 4;
      const float* row;
      if (ch < 96) row = x + ((size_t)b * 96 + ch) * NN;
      else if (ch < 192) row = m + ((size_t)b * 96 + (ch - 96)) * NN;
      else row = hid + ((size_t)b * 64 + (ch - 192)) * NN;
      tile[r + i * 4][c] = row[n0 + c];
    }
    __syncthreads();
#pragma unroll
    for (int i = 0; i < 16; ++i) {
      int row = r + i * 4;
      xt[((size_t)b * NN + n0 + row) * CIN + c0 + c] = (_Float16)tile[c][row];
    }
  }
}

// ---- k_mid: h16 (768) + M32/M16 2-term split MFMA (64) + ns2 (48) ----
__global__ __launch_bounds__(256) void k_mid(const _Float16* __restrict__ xt, const _Float16* __restrict__ wt,
                                             const float* __restrict__ bias, _Float16* __restrict__ hThi,
                                             const _Float16* __restrict__ inc16, const _Float16* __restrict__ w2shi,
                                             const _Float16* __restrict__ w2slo, float* __restrict__ M32,
                                             _Float16* __restrict__ M16, const float* __restrict__ x,
                                             const float* __restrict__ m, const float* __restrict__ hid,
                                             const float* __restrict__ wa, float* __restrict__ node_sc,
                                             float* __restrict__ g1, float* __restrict__ g2) {
  __shared__ _Float16 smA[64 * 64];
  __shared__ _Float16 smB[64 * 64];
  __shared__ _Float16 smB2[64 * 64];
  int bid = blockIdx.x;
  int t = threadIdx.x;
  if (bid < 768) {  // h16
    int xcd = bid & 7, il = bid >> 3;
    int ntile = il & 3, dtile = (il >> 2) & 3, bl = il >> 4;
    int b = xcd * 6 + bl;
    int n0 = ntile * 64, d0 = dtile * 64;
    int w = t >> 6, l = t & 63;
    int wm = w >> 1, wn = w & 1;
    int lr = l & 15;
    const _Float16* A = xt + ((size_t)b * NN + n0) * CIN;
    const _Float16* Bp = wt + (size_t)d0 * CIN;
    int lrow = l >> 3;
    int scol = 8 * ((l & 7) ^ (lrow & 7));
    f32x4 acc[2][2];
    f32x4 z = {0.f, 0.f, 0.f, 0.f};
#pragma unroll
    for (int i = 0; i < 2; ++i)
#pragma unroll
      for (int j = 0; j < 2; ++j) acc[i][j] = z;
    for (int kk = 0; kk < CIN; kk += 64) {
#pragma unroll
      for (int q = 0; q < 2; ++q) {
        int row = q * 32 + w * 8 + lrow;
        int lb = (q * 32 + w * 8) * 64;
        gload16(A + (size_t)row * CIN + kk + scol, smA + lb);
        gload16(Bp + (size_t)row * CIN + kk + scol, smB + lb);
      }
      __syncthreads();
      f16x8 af[2][2], bf[2][2];
#pragma unroll
      for (int i = 0; i < 2; ++i)
#pragma unroll
        for (int ks = 0; ks < 2; ++ks) {
          int ra = wm * 32 + i * 16 + lr;
          af[i][ks] = *(const f16x8*)&smA[ra * 64 + ((ks * 32 + (l >> 4) * 8) ^ ((ra & 7) << 3))];
          int rb = wn * 32 + i * 16 + lr;
          bf[i][ks] = *(const f16x8*)&smB[rb * 64 + ((ks * 32 + (l >> 4) * 8) ^ ((rb & 7) << 3))];
        }
#pragma unroll
      for (int ks = 0; ks < 2; ++ks)
#pragma unroll
        for (int i = 0; i < 2; ++i)
#pragma unroll
          for (int j = 0; j < 2; ++j)
            acc[i][j] = __builtin_amdgcn_mfma_f32_16x16x32_f16(af[i][ks], bf[j][ks], acc[i][j], 0, 0, 0);
      __syncthreads();
    }
#pragma unroll
    for (int i = 0; i < 2; ++i)
#pragma unroll
      for (int j = 0; j < 2; ++j) {
        int nb = n0 + wm * 32 + i * 16 + (l >> 4) * 4;
        int d = d0 + wn * 32 + j * 16 + lr;
        float4 bv = *(const float4*)&bias[nb];
        f16x4 vh;
        vh[0] = (_Float16)(acc[i][j][0] + bv.x);
        vh[1] = (_Float16)(acc[i][j][1] + bv.y);
        vh[2] = (_Float16)(acc[i][j][2] + bv.z);
        vh[3] = (_Float16)(acc[i][j][3] + bv.w);
        *(f16x4*)&hThi[((size_t)b * DD + d) * NN + nb] = vh;
      }
  } else if (bid < 832) {  // M32/M16[e,n] = sum_f inc16[n,f]*(w2shi+w2slo)[e,f]; 64 blocks
    int mb = bid - 768;
    int np = mb & 3, ep = mb >> 2;
    int m0 = np * 64;
    int n0 = ep * 64;
    int w = t >> 6, l = t & 63;
    int wm = w >> 1, wn = w & 1;
    int lr = l & 15;
    const _Float16* A = inc16 + (size_t)m0 * EE;
    const _Float16* Bh = w2shi + (size_t)n0 * EE;
    const _Float16* Bl = w2slo + (size_t)n0 * EE;
    int lrow = l >> 3;
    int scol = 8 * ((l & 7) ^ (lrow & 7));
    f32x4 acc[2][2];
    f32x4 z = {0.f, 0.f, 0.f, 0.f};
#pragma unroll
    for (int i = 0; i < 2; ++i)
#pragma unroll
      for (int j = 0; j < 2; ++j) acc[i][j] = z;
    for (int kk = 0; kk < EE; kk += 64) {
#pragma unroll
      for (int q = 0; q < 2; ++q) {
        int row = q * 32 + w * 8 + lrow;
        int lb = (q * 32 + w * 8) * 64;
        gload16(A + (size_t)row * EE + kk + scol, smA + lb);
        gload16(Bh + (size_t)row * EE + kk + scol, smB + lb);
        gload16(Bl + (size_t)row * EE + kk + scol, smB2 + lb);
      }
      __syncthreads();
      f16x8 af[2][2], bfh[2][2], bfl[2][2];
#pragma unroll
      for (int i = 0; i < 2; ++i)
#pragma unroll
        for (int ks = 0; ks < 2; ++ks) {
          int ra = wm * 32 + i * 16 + lr;
          int off_a = ra * 64 + ((ks * 32 + (l >> 4) * 8) ^ ((ra & 7) << 3));
          af[i][ks] = *(const f16x8*)&smA[off_a];
          int rb = wn * 32 + i * 16 + lr;
          int off_b = rb * 64 + ((ks * 32 + (l >> 4) * 8) ^ ((rb & 7) << 3));
          bfh[i][ks] = *(const f16x8*)&smB[off_b];
          bfl[i][ks] = *(const f16x8*)&smB2[off_b];
        }
#pragma unroll
      for (int ks = 0; ks < 2; ++ks)
#pragma unroll
        for (int i = 0; i < 2; ++i)
#pragma unroll
          for (int j = 0; j < 2; ++j) {
            acc[i][j] = __builtin_amdgcn_mfma_f32_16x16x32_f16(af[i][ks], bfh[j][ks], acc[i][j], 0, 0, 0);
            acc[i][j] = __builtin_amdgcn_mfma_f32_16x16x32_f16(af[i][ks], bfl[j][ks], acc[i][j], 0, 0, 0);
          }
      __syncthreads();
    }
#pragma unroll
    for (int i = 0; i < 2; ++i)
#pragma unroll
      for (int j = 0; j < 2; ++j) {
        int n = m0 + wm * 32 + i * 16 + (l >> 4) * 4;
        int e = n0 + wn * 32 + j * 16 + lr;
        *(f32x4*)&M32[(size_t)e * NN + n] = acc[i][j];
        f16x4 v;
#pragma unroll
        for (int r = 0; r < 4; ++r) v[r] = (_Float16)acc[i][j][r];
        *(f16x4*)&M16[(size_t)e * NN + n] = v;
      }
  } else {  // ns2: b = bid - 832
    float* s0a = (float*)smA;
    float* s1a = s0a + 256;
    float* s2a = s0a + 512;
    int b = bid - 832;
    s0a[t] = wa[t];
    s1a[t] = wa[256 + t];
    s2a[t] = wa[512 + t];
    __syncthreads();
    float s0 = 0.f, s1 = 0.f, s2 = 0.f;
#pragma unroll 4
    for (int c = 0; c < 256; ++c) {
      const float* row;
      if (c < 96) row = x + ((size_t)b * 96 + c) * NN;
      else if (c < 192) row = m + ((size_t)b * 96 + (c - 96)) * NN;
      else row = hid + ((size_t)b * 64 + (c - 192)) * NN;
      float v = row[t];
      s0 += v * s0a[c];
      s1 += v * s1a[c];
      s2 += v * s2a[c];
    }
    float bv = bias[t];
    int idx = b * NN + t;
    node_sc[idx] = s0 + bv * wa[768];
    g1[idx] = s1 + bv * wa[769];
    g2[idx] = s2 + bv * wa[770];
  }
}

// ---- k_out1s: score/att16 (768 blocks FIRST) + out1/out1T16 GEMM (3072 blocks) ----
__global__ __launch_bounds__(256) void k_out1s(const _Float16* __restrict__ M16, const _Float16* __restrict__ hThi,
                                               float* __restrict__ out1, _Float16* __restrict__ out1T,
                                               const float* __restrict__ M32, const float* __restrict__ g1,
                                               const float* __restrict__ g2, const float* __restrict__ node_sc,
                                               const float* __restrict__ pri_e, const float* __restrict__ a2,
                                               const float* __restrict__ a3, const _Float16* __restrict__ incT,
                                               const float* __restrict__ inc, _Float16* __restrict__ att16) {
  __shared__ _Float16 smA[64 * 64];
  __shared__ _Float16 smB[64 * 64];
  __shared__ float smf[64 * 65];
  int bid = blockIdx.x;
  int t = threadIdx.x;
  if (bid >= 768) {  // out1[b,e,d] = sum_n M16[e,n]*hThi[b,d,n]; 64e x 64d; b-pinned XCD
    int gb = bid - 768;
    int xcd = gb & 7, il = gb >> 3;
    int ep = il & 15, dblk = (il >> 4) & 3, bl = il >> 6;
    int b = xcd * 6 + bl;
    int e0 = ep * 64, d0 = dblk * 64;
    int w = t >> 6, l = t & 63;
    int wm = w >> 1, wn = w & 1;
    int lr = l & 15;
    const _Float16* A = M16 + (size_t)e0 * NN;
    const _Float16* Bp = hThi + ((size_t)b * DD + d0) * NN;
    int lrow = l >> 3;
    int scol = 8 * ((l & 7) ^ (lrow & 7));
    f32x4 acc[2][2];
    f32x4 z = {0.f, 0.f, 0.f, 0.f};
#pragma unroll
    for (int i = 0; i < 2; ++i)
#pragma unroll
      for (int j = 0; j < 2; ++j) acc[i][j] = z;
    for (int kk = 0; kk < NN; kk += 64) {
#pragma unroll
      for (int q = 0; q < 2; ++q) {
        int row = q * 32 + w * 8 + lrow;
        int lb = (q * 32 + w * 8) * 64;
        gload16(A + (size_t)row * NN + kk + scol, smA + lb);
        gload16(Bp + (size_t)row * NN + kk + scol, smB + lb);
      }
      __syncthreads();
      f16x8 af[2][2], bf[2][2];
#pragma unroll
      for (int i = 0; i < 2; ++i)
#pragma unroll
        for (int ks = 0; ks < 2; ++ks) {
          int ra = wm * 32 + i * 16 + lr;
          af[i][ks] = *(const f16x8*)&smA[ra * 64 + ((ks * 32 + (l >> 4) * 8) ^ ((ra & 7) << 3))];
          int rb = wn * 32 + i * 16 + lr;
          bf[i][ks] = *(const f16x8*)&smB[rb * 64 + ((ks * 32 + (l >> 4) * 8) ^ ((rb & 7) << 3))];
        }
#pragma unroll
      for (int ks = 0; ks < 2; ++ks)
#pragma unroll
        for (int i = 0; i < 2; ++i)
#pragma unroll
          for (int j = 0; j < 2; ++j)
            acc[i][j] = __builtin_amdgcn_mfma_f32_16x16x32_f16(af[i][ks], bf[j][ks], acc[i][j], 0, 0, 0);
      __syncthreads();
    }
    // stage fp32 tile (padded rows) + fp16 transposed tile (XOR swizzle) in LDS
#pragma unroll
    for (int i = 0; i < 2; ++i)
#pragma unroll
      for (int j = 0; j < 2; ++j) {
        int er = wm * 32 + i * 16 + (l >> 4) * 4;
        int dr = wn * 32 + j * 16 + lr;
        f16x4 v16;
#pragma unroll
        for (int r = 0; r < 4; ++r) {
          smf[(er + r) * 65 + dr] = acc[i][j][r];
          v16[r] = (_Float16)acc[i][j][r];
        }
        *(f16x4*)&smA[dr * 64 + (er ^ ((dr & 7) << 3))] = v16;
      }
    __syncthreads();
    {  // out1 fp32: 256B-contiguous rows, 16B/lane dwordx4
      int chunk = t & 15;
#pragma unroll
      for (int rep = 0; rep < 4; ++rep) {
        int row = (t >> 4) + rep * 16;
        f32x4 v = *(const f32x4*)&smf[row * 65 + chunk * 4];
        *(f32x4*)&out1[((size_t)b * EE + e0 + row) * DD + d0 + chunk * 4] = v;
      }
    }
    {  // out1T16: 1KB-contiguous per inst
      int dr = t >> 2, ec = (t & 3) * 16;
      _Float16* orow = out1T + ((size_t)b * DD + d0 + dr) * EE + e0;
#pragma unroll
      for (int g = 0; g < 2; ++g) {
        int e8 = ec + g * 8;
        f16x8 v = *(const f16x8*)&smA[dr * 64 + (e8 ^ ((dr & 7) << 3))];
        *(f16x8*)&orow[e8] = v;
      }
    }
  } else {  // score + att16 (dispatched first)
    float* sg1 = (float*)smA;                  // 256
    float* sg2 = sg1 + 256;                    // 256
    float* snc = sg2 + 256;                    // 256
    float(*r1)[4] = (float(*)[4])(snc + 256);  // 64*4
    float(*r2)[4] = r1 + 64;                   // 64*4
    float* sesc = (float*)(r2 + 64);           // 64
    float* steA = sesc + 64;                   // 64
    float* srm = steA + 64;                    // 64
    float* sri = srm + 64;                     // 64
    int sb = bid;
    int e0p = (sb & 15) * 64, b = sb >> 4;
    float a30 = a3[0], a31 = a3[1];
    sg1[t] = g1[b * NN + t];
    sg2[t] = g2[b * NN + t];
    snc[t] = node_sc[b * NN + t];
    __syncthreads();
    {  // phase 1: esc/te for 64 e's (fp32-exact via M32)
      int ei = t >> 2, part = t & 3;
      const float* Mr = M32 + (size_t)(e0p + ei) * NN + part * 64;
      const float* pg1 = sg1 + part * 64;
      const float* pg2 = sg2 + part * 64;
      float s1 = 0.f, s2 = 0.f;
      for (int i = 0; i < 64; i += 4) {
        f32x4 mv = *(const f32x4*)&Mr[i];
        f32x4 v1 = *(const f32x4*)&pg1[i];
        f32x4 v2 = *(const f32x4*)&pg2[i];
        s1 += mv[0] * v1[0] + mv[1] * v1[1] + mv[2] * v1[2] + mv[3] * v1[3];
        s2 += mv[0] * v2[0] + mv[1] * v2[1] + mv[2] * v2[2] + mv[3] * v2[3];
      }
      r1[ei][part] = s1;
      r2[ei][part] = s2;
    }
    __syncthreads();
    if (t < 64) {
      int row = b * EE + e0p + t;
      float es = r1[t][0] + r1[t][1] + r1[t][2] + r1[t][3];
      float te = lrelu(r2[t][0] + r2[t][1] + r2[t][2] + r2[t][3] + pri_e[row] * a2[DD]);
      sesc[t] = es;
      steA[t] = te * a30;
    }
    __syncthreads();
    {  // phase 2: masked max + exp-sum per e (wave per row)
      int w = t >> 6, l = t & 63;
      for (int rr = 0; rr < 16; ++rr) {
        int er = w * 16 + rr;
        int e = e0p + er;
        float es = sesc[er], ta = steA[er];
        f16x4 ic = *(const f16x4*)&incT[(size_t)e * NN + l * 4];
        float s2v[4];
        bool msk[4];
        float vmax = -3.0e38f;
#pragma unroll
        for (int q = 0; q < 4; ++q) {
          float s1 = lrelu(snc[l * 4 + q] + es);
          float s2 = lrelu(ta + s1 * a31);
          msk[q] = (float)ic[q] > 0.f;
          s2v[q] = s2;
          if (msk[q]) vmax = fmaxf(vmax, s2);
        }
#pragma unroll
        for (int off = 32; off > 0; off >>= 1) vmax = fmaxf(vmax, __shfl_xor(vmax, off));
        float ss = 0.f;
#pragma unroll
        for (int q = 0; q < 4; ++q)
          if (msk[q]) ss += __expf(s2v[q] - vmax);
#pragma unroll
        for (int off = 32; off > 0; off >>= 1) ss += __shfl_xor(ss, off);
        if (l == 0) {
          srm[er] = vmax;
          sri[er] = 1.0f / ss;
        }
      }
    }
    __syncthreads();
    {  // phase 3: emit att16 — f16x8 coalesced (8 lanes = 128B row segment)
      _Float16* ab = att16 + (size_t)b * NN * EE;
      int nb = t >> 3, el = (t & 7) * 8;
#pragma unroll
      for (int rep = 0; rep < 8; ++rep) {
        int n = nb + rep * 32;
        float ns = snc[n];
        float4 icv0 = *(const float4*)&inc[(size_t)n * EE + e0p + el];
        float4 icv1 = *(const float4*)&inc[(size_t)n * EE + e0p + el + 4];
        float ica[8] = {icv0.x, icv0.y, icv0.z, icv0.w, icv1.x, icv1.y, icv1.z, icv1.w};
        f16x8 o;
#pragma unroll
        for (int qq = 0; qq < 8; ++qq) {
          float att = 0.f;
          if (ica[qq] > 0.f) {
            float s1v = lrelu(ns + sesc[el + qq]);
            float s2v = lrelu(steA[el + qq] + s1v * a31);
            att = __expf(s2v - srm[el + qq]) * sri[el + qq];
          }
          o[qq] = (_Float16)att;
        }
        *(f16x8*)&ab[(size_t)n * EE + e0p + el] = o;
      }
    }
  }
}

// out0[b,d,n] = sum_e att16[n,e]*out1T16[d,e]; pure fp16 MFMA GEMM; b-pinned XCD
__global__ __launch_bounds__(256) void k_fgemm(const _Float16* __restrict__ att16, const _Float16* __restrict__ out1T,
                                               float* __restrict__ out0) {
  __shared__ _Float16 smA[64 * 64];
  __shared__ _Float16 smB[64 * 64];
  int bid = blockIdx.x;
  int xcd = bid & 7, il = bid >> 3;  // 96 per XCD
  int ntile = il & 3, dtile = (il >> 2) & 3, bl = il >> 4;
  int b = xcd * 6 + bl;
  int n0 = ntile * 64, d0 = dtile * 64;
  int t = threadIdx.x, w = t >> 6, l = t & 63;
  int wm = w >> 1, wn = w & 1;
  int lr = l & 15;
  const _Float16* A = att16 + ((size_t)b * NN + n0) * EE;
  const _Float16* Bp = out1T + ((size_t)b * DD + d0) * EE;
  int lrow = l >> 3;
  int scol = 8 * ((l & 7) ^ (lrow & 7));
  f32x4 acc[2][2];
  f32x4 z = {0.f, 0.f, 0.f, 0.f};
#pragma unroll
  for (int i = 0; i < 2; ++i)
#pragma unroll
    for (int j = 0; j < 2; ++j) acc[i][j] = z;
  for (int kk = 0; kk < EE; kk += 64) {
#pragma unroll
    for (int q = 0; q < 2; ++q) {
      int row = q * 32 + w * 8 + lrow;
      int lb = (q * 32 + w * 8) * 64;
      gload16(A + (size_t)row * EE + kk + scol, smA + lb);
      gload16(Bp + (size_t)row * EE + kk + scol, smB + lb);
    }
    __syncthreads();
    f16x8 af[2][2], bf[2][2];
#pragma unroll
    for (int i = 0; i < 2; ++i)
#pragma unroll
      for (int ks = 0; ks < 2; ++ks) {
        int ra = wm * 32 + i * 16 + lr;
        af[i][ks] = *(const f16x8*)&smA[ra * 64 + ((ks * 32 + (l >> 4) * 8) ^ ((ra & 7) << 3))];
        int rb = wn * 32 + i * 16 + lr;
        bf[i][ks] = *(const f16x8*)&smB[rb * 64 + ((ks * 32 + (l >> 4) * 8) ^ ((rb & 7) << 3))];
      }
#pragma unroll
    for (int ks = 0; ks < 2; ++ks)
#pragma unroll
      for (int i = 0; i < 2; ++i)
#pragma unroll
        for (int j = 0; j < 2; ++j)
          acc[i][j] = __builtin_amdgcn_mfma_f32_16x16x32_f16(af[i][ks], bf[j][ks], acc[i][j], 0, 0, 0);
    __syncthreads();
  }
  float* ob = out0 + (size_t)b * DD * NN;
#pragma unroll
  for (int i = 0; i < 2; ++i)
#pragma unroll
    for (int j = 0; j < 2; ++j) {
      int n = n0 + wm * 32 + i * 16 + (l >> 4) * 4;
      int d = d0 + wn * 32 + j * 16 + lr;
      *(float4*)&ob[(size_t)d * NN + n] =
          make_float4(acc[i][j][0], acc[i][j][1], acc[i][j][2], acc[i][j][3]);
    }
}

extern "C" void kernel_launch(void* const* d_in, const int* in_sizes, int n_in, void* d_out, int out_size,
                              void* d_ws, size_t ws_size, hipStream_t stream) {
  (void)in_sizes;
  (void)n_in;
  (void)out_size;
  (void)ws_size;
  const float* x = (const float*)d_in[0];
  const float* m = (const float*)d_in[1];
  const float* hid = (const float*)d_in[2];
  const float* pri_e = (const float*)d_in[3];
  const float* inc = (const float*)d_in[5];
  const float* W = (const float*)d_in[6];
  const float* bias = (const float*)d_in[7];
  const float* W2 = (const float*)d_in[8];
  const float* a = (const float*)d_in[9];
  const float* a2 = (const float*)d_in[10];
  const float* a3 = (const float*)d_in[11];

  float* out0 = (float*)d_out;                // [B,D,N]
  float* out1 = out0 + (size_t)BB * DD * NN;  // [B,E,D] fp32 (written by k_out1s)
  _Float16* xt16 = (_Float16*)out1;           // [B,N,CIN] fp16 — dead after k_mid, before out1 written

  _Float16* out1T16 = (_Float16*)d_ws;                 // [B,D,E]
  _Float16* hThi = out1T16 + (size_t)BB * DD * EE;     // [B,D,N]
  _Float16* incT = hThi + (size_t)BB * DD * NN;        // [E,N]
  _Float16* w2shi = incT + (size_t)EE * NN;            // [E,E]
  _Float16* w2slo = w2shi + (size_t)EE * EE;           // [E,E]
  _Float16* inc16 = w2slo + (size_t)EE * EE;           // [N,E]
  _Float16* M16 = inc16 + (size_t)NN * EE;             // [E,N]
  _Float16* wt16 = M16 + (size_t)EE * NN;              // [D,CIN]
  _Float16* att16 = wt16 + (size_t)DD * CIN;           // [B,N,E]
  float* M32 = (float*)(att16 + (size_t)BB * NN * EE); // [E,N] fp32
  float* node_sc = M32 + (size_t)EE * NN;              // B*N
  float* g1 = node_sc + (size_t)BB * NN;               // B*N
  float* g2 = g1 + (size_t)BB * NN;                    // B*N
  float* wa = g2 + (size_t)BB * NN;                    // 1024

  k_prep<<<dim3(1376), 256, 0, stream>>>(inc, W2, W, x, m, hid, a, a2, incT, w2shi, w2slo, wt16, inc16, wa, xt16);
  k_mid<<<dim3(880), 256, 0, stream>>>(xt16, wt16, bias, hThi, inc16, w2shi, w2slo, M32, M16, x, m, hid, wa,
                                       node_sc, g1, g2);
  k_out1s<<<dim3(768 + 3072), 256, 0, stream>>>(M16, hThi, out1, out1T16, M32, g1, g2, node_sc, pri_e, a2, a3,
                                                incT, inc, att16);
  k_fgemm<<<dim3(8 * 96), 256, 0, stream>>>(att16, out1T16, out0);
}

// Round 16
// 105.220 us; speedup vs baseline: 1.9123x; 1.0729x over previous
//
#include <hip/hip_runtime.h>

#define BB 48
#define NN 256
#define EE 1024
#define DD 256
#define CIN 256

typedef __attribute__((ext_vector_type(4))) float f32x4;
typedef __attribute__((ext_vector_type(8))) _Float16 f16x8;
typedef __attribute__((ext_vector_type(4))) _Float16 f16x4;

__device__ __forceinline__ float lrelu(float t) { return t >= 0.0f ? t : 0.2f * t; }

__device__ __forceinline__ void gload16(const void* g, void* l) {
  __builtin_amdgcn_global_load_lds((const __attribute__((address_space(1))) void*)g,
                                   (__attribute__((address_space(3))) void*)l, 16, 0, 0);
}

// ---- k_prep: w2s hi/lo, incT, wt16, inc16, wa, xt (all input-only) ----
__global__ __launch_bounds__(256) void k_prep(const float* __restrict__ inc, const float* __restrict__ W2,
                                              const float* __restrict__ W, const float* __restrict__ x,
                                              const float* __restrict__ m, const float* __restrict__ hid,
                                              const float* __restrict__ a, const float* __restrict__ a2,
                                              _Float16* __restrict__ incT, _Float16* __restrict__ w2shi,
                                              _Float16* __restrict__ w2slo, _Float16* __restrict__ wt16,
                                              _Float16* __restrict__ inc16, float* __restrict__ wa,
                                              _Float16* __restrict__ xt) {
  __shared__ float tile[64][65];
  __shared__ float aux[4][64];
  __shared__ float aux2[64];
  int bid = blockIdx.x;
  int t = threadIdx.x;
  if (bid < 256) {  // w2s[e,f] = W2[f,e]*invdeg[f], hi/lo fp16 split
    int f0 = (bid & 15) * 64, e0 = (bid >> 4) * 64;
    int c = t & 63, r = t >> 6;
    {
      float s = 0.f;
      for (int i = 0; i < 64; ++i) s += inc[(size_t)(r * 64 + i) * EE + f0 + c];
      aux[r][c] = s;
    }
#pragma unroll
    for (int i = 0; i < 16; ++i) tile[r + i * 4][c] = W2[(size_t)(f0 + r + i * 4) * EE + e0 + c];
    __syncthreads();
    if (t < 64) aux2[t] = 1.0f / (aux[0][t] + aux[1][t] + aux[2][t] + aux[3][t]);
    __syncthreads();
#pragma unroll
    for (int i = 0; i < 16; ++i) {
      int row = r + i * 4;
      float v = tile[c][row] * aux2[c];
      _Float16 hh = (_Float16)v;
      w2shi[(size_t)(e0 + row) * EE + f0 + c] = hh;
      w2slo[(size_t)(e0 + row) * EE + f0 + c] = (_Float16)(v - (float)hh);
    }
  } else if (bid < 320) {  // incT[e,n] = inc[n,e]
    int s = bid - 256;
    int e0 = (s & 15) * 64, n0 = (s >> 4) * 64;
    int c = t & 63, r = t >> 6;
#pragma unroll
    for (int i = 0; i < 16; ++i) tile[r + i * 4][c] = inc[(size_t)(n0 + r + i * 4) * EE + e0 + c];
    __syncthreads();
#pragma unroll
    for (int i = 0; i < 16; ++i) {
      int row = r + i * 4;
      incT[(size_t)(e0 + row) * NN + n0 + c] = (_Float16)tile[c][row];
    }
  } else if (bid < 336) {  // wt16[d,c] = fp16(W[c,d])
    int s = bid - 320;
    int c0 = (s & 3) * 64, d0 = (s >> 2) * 64;
    int c = t & 63, r = t >> 6;
#pragma unroll
    for (int i = 0; i < 16; ++i) tile[r + i * 4][c] = W[(size_t)(c0 + r + i * 4) * DD + d0 + c];
    __syncthreads();
#pragma unroll
    for (int i = 0; i < 16; ++i) {
      int row = r + i * 4;
      wt16[(size_t)(d0 + row) * CIN + c0 + c] = (_Float16)tile[c][row];
    }
  } else if (bid < 352) {  // inc16[n,f] = fp16(inc) (exact 0/1)
    int s = bid - 336;
    size_t base = ((size_t)s * 256 + t) * 64;
#pragma unroll
    for (int i = 0; i < 16; ++i) {
      f32x4 v = *(const f32x4*)&inc[base + i * 4];
      f16x4 o;
      o[0] = (_Float16)v[0];
      o[1] = (_Float16)v[1];
      o[2] = (_Float16)v[2];
      o[3] = (_Float16)v[3];
      *(f16x4*)&inc16[base + i * 4] = o;
    }
  } else if (bid < 608) {  // wa
    float(*red)[4] = (float(*)[4])aux;
    int c = bid - 352;
    int l = t & 63, wv = t >> 6;
    float w = W[(size_t)c * DD + t];
    float p0 = w * a[t], p1 = w * a[DD + t], p2 = w * a2[t];
#pragma unroll
    for (int off = 32; off > 0; off >>= 1) {
      p0 += __shfl_down(p0, off);
      p1 += __shfl_down(p1, off);
      p2 += __shfl_down(p2, off);
    }
    if (l == 0) {
      red[0][wv] = p0;
      red[1][wv] = p1;
      red[2][wv] = p2;
    }
    __syncthreads();
    if (t == 0) wa[c] = red[0][0] + red[0][1] + red[0][2] + red[0][3];
    if (t == 1) wa[256 + c] = red[1][0] + red[1][1] + red[1][2] + red[1][3];
    if (t == 2) wa[512 + c] = red[2][0] + red[2][1] + red[2][2] + red[2][3];
    if (c == 0) {
      __syncthreads();
      float q0 = a[t], q1 = a[DD + t], q2 = a2[t];
#pragma unroll
      for (int off = 32; off > 0; off >>= 1) {
        q0 += __shfl_down(q0, off);
        q1 += __shfl_down(q1, off);
        q2 += __shfl_down(q2, off);
      }
      if (l == 0) {
        red[0][wv] = q0;
        red[1][wv] = q1;
        red[2][wv] = q2;
      }
      __syncthreads();
      if (t == 0) wa[768] = red[0][0] + red[0][1] + red[0][2] + red[0][3];
      if (t == 1) wa[769] = red[1][0] + red[1][1] + red[1][2] + red[1][3];
      if (t == 2) wa[770] = red[2][0] + red[2][1] + red[2][2] + red[2][3];
    }
  } else {  // xt16[b,n,c] = fp16(x_in[b,c,n]); 768 blocks
    int s = bid - 608;
    int c0 = (s & 3) * 64, n0 = ((s >> 2) & 3) * 64, b = s >> 4;
    int c = t & 63, r = t >> 6;
#pragma unroll
    for (int i = 0; i < 16; ++i) {
      int ch = c0 + r + i * 4;
      const float* row;
      if (ch < 96) row = x + ((size_t)b * 96 + ch) * NN;
      else if (ch < 192) row = m + ((size_t)b * 96 + (ch - 96)) * NN;
      else row = hid + ((size_t)b * 64 + (ch - 192)) * NN;
      tile[r + i * 4][c] = row[n0 + c];
    }
    __syncthreads();
#pragma unroll
    for (int i = 0; i < 16; ++i) {
      int row = r + i * 4;
      xt[((size_t)b * NN + n0 + row) * CIN + c0 + c] = (_Float16)tile[c][row];
    }
  }
}

// ---- k_mid: h16 (768) + M32/M16 2-term split MFMA (64) + ns2 (48) ----
__global__ __launch_bounds__(256) void k_mid(const _Float16* __restrict__ xt, const _Float16* __restrict__ wt,
                                             const float* __restrict__ bias, _Float16* __restrict__ hThi,
                                             const _Float16* __restrict__ inc16, const _Float16* __restrict__ w2shi,
                                             const _Float16* __restrict__ w2slo, float* __restrict__ M32,
                                             _Float16* __restrict__ M16, const float* __restrict__ x,
                                             const float* __restrict__ m, const float* __restrict__ hid,
                                             const float* __restrict__ wa, float* __restrict__ node_sc,
                                             float* __restrict__ g1, float* __restrict__ g2) {
  __shared__ _Float16 smA[64 * 64];
  __shared__ _Float16 smB[64 * 64];
  __shared__ _Float16 smB2[64 * 64];
  int bid = blockIdx.x;
  int t = threadIdx.x;
  if (bid < 768) {  // h16
    int xcd = bid & 7, il = bid >> 3;
    int ntile = il & 3, dtile = (il >> 2) & 3, bl = il >> 4;
    int b = xcd * 6 + bl;
    int n0 = ntile * 64, d0 = dtile * 64;
    int w = t >> 6, l = t & 63;
    int wm = w >> 1, wn = w & 1;
    int lr = l & 15;
    const _Float16* A = xt + ((size_t)b * NN + n0) * CIN;
    const _Float16* Bp = wt + (size_t)d0 * CIN;
    int lrow = l >> 3;
    int scol = 8 * ((l & 7) ^ (lrow & 7));
    f32x4 acc[2][2];
    f32x4 z = {0.f, 0.f, 0.f, 0.f};
#pragma unroll
    for (int i = 0; i < 2; ++i)
#pragma unroll
      for (int j = 0; j < 2; ++j) acc[i][j] = z;
    for (int kk = 0; kk < CIN; kk += 64) {
#pragma unroll
      for (int q = 0; q < 2; ++q) {
        int row = q * 32 + w * 8 + lrow;
        int lb = (q * 32 + w * 8) * 64;
        gload16(A + (size_t)row * CIN + kk + scol, smA + lb);
        gload16(Bp + (size_t)row * CIN + kk + scol, smB + lb);
      }
      __syncthreads();
      f16x8 af[2][2], bf[2][2];
#pragma unroll
      for (int i = 0; i < 2; ++i)
#pragma unroll
        for (int ks = 0; ks < 2; ++ks) {
          int ra = wm * 32 + i * 16 + lr;
          af[i][ks] = *(const f16x8*)&smA[ra * 64 + ((ks * 32 + (l >> 4) * 8) ^ ((ra & 7) << 3))];
          int rb = wn * 32 + i * 16 + lr;
          bf[i][ks] = *(const f16x8*)&smB[rb * 64 + ((ks * 32 + (l >> 4) * 8) ^ ((rb & 7) << 3))];
        }
#pragma unroll
      for (int ks = 0; ks < 2; ++ks)
#pragma unroll
        for (int i = 0; i < 2; ++i)
#pragma unroll
          for (int j = 0; j < 2; ++j)
            acc[i][j] = __builtin_amdgcn_mfma_f32_16x16x32_f16(af[i][ks], bf[j][ks], acc[i][j], 0, 0, 0);
      __syncthreads();
    }
#pragma unroll
    for (int i = 0; i < 2; ++i)
#pragma unroll
      for (int j = 0; j < 2; ++j) {
        int nb = n0 + wm * 32 + i * 16 + (l >> 4) * 4;
        int d = d0 + wn * 32 + j * 16 + lr;
        float4 bv = *(const float4*)&bias[nb];
        f16x4 vh;
        vh[0] = (_Float16)(acc[i][j][0] + bv.x);
        vh[1] = (_Float16)(acc[i][j][1] + bv.y);
        vh[2] = (_Float16)(acc[i][j][2] + bv.z);
        vh[3] = (_Float16)(acc[i][j][3] + bv.w);
        *(f16x4*)&hThi[((size_t)b * DD + d) * NN + nb] = vh;
      }
  } else if (bid < 832) {  // M32/M16[e,n] = sum_f inc16[n,f]*(w2shi+w2slo)[e,f]; 64 blocks
    int mb = bid - 768;
    int np = mb & 3, ep = mb >> 2;
    int m0 = np * 64;
    int n0 = ep * 64;
    int w = t >> 6, l = t & 63;
    int wm = w >> 1, wn = w & 1;
    int lr = l & 15;
    const _Float16* A = inc16 + (size_t)m0 * EE;
    const _Float16* Bh = w2shi + (size_t)n0 * EE;
    const _Float16* Bl = w2slo + (size_t)n0 * EE;
    int lrow = l >> 3;
    int scol = 8 * ((l & 7) ^ (lrow & 7));
    f32x4 acc[2][2];
    f32x4 z = {0.f, 0.f, 0.f, 0.f};
#pragma unroll
    for (int i = 0; i < 2; ++i)
#pragma unroll
      for (int j = 0; j < 2; ++j) acc[i][j] = z;
    for (int kk = 0; kk < EE; kk += 64) {
#pragma unroll
      for (int q = 0; q < 2; ++q) {
        int row = q * 32 + w * 8 + lrow;
        int lb = (q * 32 + w * 8) * 64;
        gload16(A + (size_t)row * EE + kk + scol, smA + lb);
        gload16(Bh + (size_t)row * EE + kk + scol, smB + lb);
        gload16(Bl + (size_t)row * EE + kk + scol, smB2 + lb);
      }
      __syncthreads();
      f16x8 af[2][2], bfh[2][2], bfl[2][2];
#pragma unroll
      for (int i = 0; i < 2; ++i)
#pragma unroll
        for (int ks = 0; ks < 2; ++ks) {
          int ra = wm * 32 + i * 16 + lr;
          int off_a = ra * 64 + ((ks * 32 + (l >> 4) * 8) ^ ((ra & 7) << 3));
          af[i][ks] = *(const f16x8*)&smA[off_a];
          int rb = wn * 32 + i * 16 + lr;
          int off_b = rb * 64 + ((ks * 32 + (l >> 4) * 8) ^ ((rb & 7) << 3));
          bfh[i][ks] = *(const f16x8*)&smB[off_b];
          bfl[i][ks] = *(const f16x8*)&smB2[off_b];
        }
#pragma unroll
      for (int ks = 0; ks < 2; ++ks)
#pragma unroll
        for (int i = 0; i < 2; ++i)
#pragma unroll
          for (int j = 0; j < 2; ++j) {
            acc[i][j] = __builtin_amdgcn_mfma_f32_16x16x32_f16(af[i][ks], bfh[j][ks], acc[i][j], 0, 0, 0);
            acc[i][j] = __builtin_amdgcn_mfma_f32_16x16x32_f16(af[i][ks], bfl[j][ks], acc[i][j], 0, 0, 0);
          }
      __syncthreads();
    }
#pragma unroll
    for (int i = 0; i < 2; ++i)
#pragma unroll
      for (int j = 0; j < 2; ++j) {
        int n = m0 + wm * 32 + i * 16 + (l >> 4) * 4;
        int e = n0 + wn * 32 + j * 16 + lr;
        *(f32x4*)&M32[(size_t)e * NN + n] = acc[i][j];
        f16x4 v;
#pragma unroll
        for (int r = 0; r < 4; ++r) v[r] = (_Float16)acc[i][j][r];
        *(f16x4*)&M16[(size_t)e * NN + n] = v;
      }
  } else {  // ns2: b = bid - 832
    float* s0a = (float*)smA;
    float* s1a = s0a + 256;
    float* s2a = s0a + 512;
    int b = bid - 832;
    s0a[t] = wa[t];
    s1a[t] = wa[256 + t];
    s2a[t] = wa[512 + t];
    __syncthreads();
    float s0 = 0.f, s1 = 0.f, s2 = 0.f;
#pragma unroll 4
    for (int c = 0; c < 256; ++c) {
      const float* row;
      if (c < 96) row = x + ((size_t)b * 96 + c) * NN;
      else if (c < 192) row = m + ((size_t)b * 96 + (c - 96)) * NN;
      else row = hid + ((size_t)b * 64 + (c - 192)) * NN;
      float v = row[t];
      s0 += v * s0a[c];
      s1 += v * s1a[c];
      s2 += v * s2a[c];
    }
    float bv = bias[t];
    int idx = b * NN + t;
    node_sc[idx] = s0 + bv * wa[768];
    g1[idx] = s1 + bv * wa[769];
    g2[idx] = s2 + bv * wa[770];
  }
}

// ---- k_out1s: score/att16 (768 blocks FIRST) + out1/out1T16 GEMM (3072 blocks) ----
// att16/out1T16 are PANEL-BLOCKED: [b][ep][n or d][64e] — contiguous per-block writes
__global__ __launch_bounds__(256) void k_out1s(const _Float16* __restrict__ M16, const _Float16* __restrict__ hThi,
                                               float* __restrict__ out1, _Float16* __restrict__ out1T,
                                               const float* __restrict__ M32, const float* __restrict__ g1,
                                               const float* __restrict__ g2, const float* __restrict__ node_sc,
                                               const float* __restrict__ pri_e, const float* __restrict__ a2,
                                               const float* __restrict__ a3, const _Float16* __restrict__ incT,
                                               const float* __restrict__ inc, _Float16* __restrict__ att16) {
  __shared__ _Float16 smA[64 * 64];
  __shared__ _Float16 smB[64 * 64];
  int bid = blockIdx.x;
  int t = threadIdx.x;
  if (bid >= 768) {  // out1[b,e,d] = sum_n M16[e,n]*hThi[b,d,n]; 64e x 64d; b-pinned XCD
    int gb = bid - 768;
    int xcd = gb & 7, il = gb >> 3;
    int ep = il & 15, dblk = (il >> 4) & 3, bl = il >> 6;
    int b = xcd * 6 + bl;
    int e0 = ep * 64, d0 = dblk * 64;
    int w = t >> 6, l = t & 63;
    int wm = w >> 1, wn = w & 1;
    int lr = l & 15;
    const _Float16* A = M16 + (size_t)e0 * NN;
    const _Float16* Bp = hThi + ((size_t)b * DD + d0) * NN;
    int lrow = l >> 3;
    int scol = 8 * ((l & 7) ^ (lrow & 7));
    f32x4 acc[2][2];
    f32x4 z = {0.f, 0.f, 0.f, 0.f};
#pragma unroll
    for (int i = 0; i < 2; ++i)
#pragma unroll
      for (int j = 0; j < 2; ++j) acc[i][j] = z;
    for (int kk = 0; kk < NN; kk += 64) {
#pragma unroll
      for (int q = 0; q < 2; ++q) {
        int row = q * 32 + w * 8 + lrow;
        int lb = (q * 32 + w * 8) * 64;
        gload16(A + (size_t)row * NN + kk + scol, smA + lb);
        gload16(Bp + (size_t)row * NN + kk + scol, smB + lb);
      }
      __syncthreads();
      f16x8 af[2][2], bf[2][2];
#pragma unroll
      for (int i = 0; i < 2; ++i)
#pragma unroll
        for (int ks = 0; ks < 2; ++ks) {
          int ra = wm * 32 + i * 16 + lr;
          af[i][ks] = *(const f16x8*)&smA[ra * 64 + ((ks * 32 + (l >> 4) * 8) ^ ((ra & 7) << 3))];
          int rb = wn * 32 + i * 16 + lr;
          bf[i][ks] = *(const f16x8*)&smB[rb * 64 + ((ks * 32 + (l >> 4) * 8) ^ ((rb & 7) << 3))];
        }
#pragma unroll
      for (int ks = 0; ks < 2; ++ks)
#pragma unroll
        for (int i = 0; i < 2; ++i)
#pragma unroll
          for (int j = 0; j < 2; ++j)
            acc[i][j] = __builtin_amdgcn_mfma_f32_16x16x32_f16(af[i][ks], bf[j][ks], acc[i][j], 0, 0, 0);
      __syncthreads();
    }
    // out1 fp32 direct stores
#pragma unroll
    for (int i = 0; i < 2; ++i)
#pragma unroll
      for (int j = 0; j < 2; ++j) {
        int e = e0 + wm * 32 + i * 16 + (l >> 4) * 4;
        int d = d0 + wn * 32 + j * 16 + lr;
#pragma unroll
        for (int r = 0; r < 4; ++r) out1[((size_t)b * EE + e + r) * DD + d] = acc[i][j][r];
      }
    // out1T16 via LDS -> panel-blocked [b][ep][d(256)][64e]: contiguous 8KB per block
#pragma unroll
    for (int i = 0; i < 2; ++i)
#pragma unroll
      for (int j = 0; j < 2; ++j) {
        int dr = wn * 32 + j * 16 + lr;
        int er = wm * 32 + i * 16 + (l >> 4) * 4;
        f16x4 v16;
#pragma unroll
        for (int r = 0; r < 4; ++r) v16[r] = (_Float16)acc[i][j][r];
        *(f16x4*)&smA[dr * 64 + (er ^ ((dr & 7) << 3))] = v16;
      }
    __syncthreads();
    {
      int dr = t >> 2, ec = (t & 3) * 16;
      _Float16* orow = out1T + (((size_t)b * 16 + ep) * 256 + d0 + dr) * 64;
#pragma unroll
      for (int g = 0; g < 2; ++g) {
        int e8 = ec + g * 8;
        f16x8 v = *(const f16x8*)&smA[dr * 64 + (e8 ^ ((dr & 7) << 3))];
        *(f16x8*)&orow[e8] = v;
      }
    }
  } else {  // score + att16 (dispatched first)
    float* sg1 = (float*)smA;                  // 256
    float* sg2 = sg1 + 256;                    // 256
    float* snc = sg2 + 256;                    // 256
    float(*r1)[4] = (float(*)[4])(snc + 256);  // 64*4
    float(*r2)[4] = r1 + 64;                   // 64*4
    float* sesc = (float*)(r2 + 64);           // 64
    float* steA = sesc + 64;                   // 64
    float* srm = steA + 64;                    // 64
    float* sri = srm + 64;                     // 64
    int sb = bid;
    int sep = sb & 15;
    int e0p = sep * 64, b = sb >> 4;
    float a30 = a3[0], a31 = a3[1];
    sg1[t] = g1[b * NN + t];
    sg2[t] = g2[b * NN + t];
    snc[t] = node_sc[b * NN + t];
    __syncthreads();
    {  // phase 1: esc/te for 64 e's (fp32-exact via M32)
      int ei = t >> 2, part = t & 3;
      const float* Mr = M32 + (size_t)(e0p + ei) * NN + part * 64;
      const float* pg1 = sg1 + part * 64;
      const float* pg2 = sg2 + part * 64;
      float s1 = 0.f, s2 = 0.f;
      for (int i = 0; i < 64; i += 4) {
        f32x4 mv = *(const f32x4*)&Mr[i];
        f32x4 v1 = *(const f32x4*)&pg1[i];
        f32x4 v2 = *(const f32x4*)&pg2[i];
        s1 += mv[0] * v1[0] + mv[1] * v1[1] + mv[2] * v1[2] + mv[3] * v1[3];
        s2 += mv[0] * v2[0] + mv[1] * v2[1] + mv[2] * v2[2] + mv[3] * v2[3];
      }
      r1[ei][part] = s1;
      r2[ei][part] = s2;
    }
    __syncthreads();
    if (t < 64) {
      int row = b * EE + e0p + t;
      float es = r1[t][0] + r1[t][1] + r1[t][2] + r1[t][3];
      float te = lrelu(r2[t][0] + r2[t][1] + r2[t][2] + r2[t][3] + pri_e[row] * a2[DD]);
      sesc[t] = es;
      steA[t] = te * a30;
    }
    __syncthreads();
    {  // phase 2: masked max + exp-sum per e (wave per row)
      int w = t >> 6, l = t & 63;
      for (int rr = 0; rr < 16; ++rr) {
        int er = w * 16 + rr;
        int e = e0p + er;
        float es = sesc[er], ta = steA[er];
        f16x4 ic = *(const f16x4*)&incT[(size_t)e * NN + l * 4];
        float s2v[4];
        bool msk[4];
        float vmax = -3.0e38f;
#pragma unroll
        for (int q = 0; q < 4; ++q) {
          float s1 = lrelu(snc[l * 4 + q] + es);
          float s2 = lrelu(ta + s1 * a31);
          msk[q] = (float)ic[q] > 0.f;
          s2v[q] = s2;
          if (msk[q]) vmax = fmaxf(vmax, s2);
        }
#pragma unroll
        for (int off = 32; off > 0; off >>= 1) vmax = fmaxf(vmax, __shfl_xor(vmax, off));
        float ss = 0.f;
#pragma unroll
        for (int q = 0; q < 4; ++q)
          if (msk[q]) ss += __expf(s2v[q] - vmax);
#pragma unroll
        for (int off = 32; off > 0; off >>= 1) ss += __shfl_xor(ss, off);
        if (l == 0) {
          srm[er] = vmax;
          sri[er] = 1.0f / ss;
        }
      }
    }
    __syncthreads();
    {  // phase 3: emit att16 panel-blocked [b][ep][n(256)][64e] — fully contiguous 32KB
      _Float16* ab = att16 + ((size_t)b * 16 + sep) * 256 * 64;
      int nb = t >> 3, el = (t & 7) * 8;
#pragma unroll
      for (int rep = 0; rep < 8; ++rep) {
        int n = nb + rep * 32;
        float ns = snc[n];
        float4 icv0 = *(const float4*)&inc[(size_t)n * EE + e0p + el];
        float4 icv1 = *(const float4*)&inc[(size_t)n * EE + e0p + el + 4];
        float ica[8] = {icv0.x, icv0.y, icv0.z, icv0.w, icv1.x, icv1.y, icv1.z, icv1.w};
        f16x8 o;
#pragma unroll
        for (int qq = 0; qq < 8; ++qq) {
          float att = 0.f;
          if (ica[qq] > 0.f) {
            float s1v = lrelu(ns + sesc[el + qq]);
            float s2v = lrelu(steA[el + qq] + s1v * a31);
            att = __expf(s2v - srm[el + qq]) * sri[el + qq];
          }
          o[qq] = (_Float16)att;
        }
        *(f16x8*)&ab[(size_t)n * 64 + el] = o;
      }
    }
  }
}

// out0[b,d,n] = sum_e att16[n,e]*out1T16[d,e]; panel-blocked operands; b-pinned XCD
__global__ __launch_bounds__(256) void k_fgemm(const _Float16* __restrict__ att16, const _Float16* __restrict__ out1T,
                                               float* __restrict__ out0) {
  __shared__ _Float16 smA[64 * 64];
  __shared__ _Float16 smB[64 * 64];
  int bid = blockIdx.x;
  int xcd = bid & 7, il = bid >> 3;  // 96 per XCD
  int ntile = il & 3, dtile = (il >> 2) & 3, bl = il >> 4;
  int b = xcd * 6 + bl;
  int n0 = ntile * 64, d0 = dtile * 64;
  int t = threadIdx.x, w = t >> 6, l = t & 63;
  int wm = w >> 1, wn = w & 1;
  int lr = l & 15;
  int lrow = l >> 3;
  int scol = 8 * ((l & 7) ^ (lrow & 7));
  f32x4 acc[2][2];
  f32x4 z = {0.f, 0.f, 0.f, 0.f};
#pragma unroll
  for (int i = 0; i < 2; ++i)
#pragma unroll
    for (int j = 0; j < 2; ++j) acc[i][j] = z;
  for (int kk = 0; kk < EE; kk += 64) {
    int ep = kk >> 6;
    const _Float16* Ak = att16 + (((size_t)b * 16 + ep) * 256 + n0) * 64;
    const _Float16* Bk = out1T + (((size_t)b * 16 + ep) * 256 + d0) * 64;
#pragma unroll
    for (int q = 0; q < 2; ++q) {
      int row = q * 32 + w * 8 + lrow;
      int lb = (q * 32 + w * 8) * 64;
      gload16(Ak + (size_t)row * 64 + scol, smA + lb);
      gload16(Bk + (size_t)row * 64 + scol, smB + lb);
    }
    __syncthreads();
    f16x8 af[2][2], bf[2][2];
#pragma unroll
    for (int i = 0; i < 2; ++i)
#pragma unroll
      for (int ks = 0; ks < 2; ++ks) {
        int ra = wm * 32 + i * 16 + lr;
        af[i][ks] = *(const f16x8*)&smA[ra * 64 + ((ks * 32 + (l >> 4) * 8) ^ ((ra & 7) << 3))];
        int rb = wn * 32 + i * 16 + lr;
        bf[i][ks] = *(const f16x8*)&smB[rb * 64 + ((ks * 32 + (l >> 4) * 8) ^ ((rb & 7) << 3))];
      }
#pragma unroll
    for (int ks = 0; ks < 2; ++ks)
#pragma unroll
      for (int i = 0; i < 2; ++i)
#pragma unroll
        for (int j = 0; j < 2; ++j)
          acc[i][j] = __builtin_amdgcn_mfma_f32_16x16x32_f16(af[i][ks], bf[j][ks], acc[i][j], 0, 0, 0);
    __syncthreads();
  }
  float* ob = out0 + (size_t)b * DD * NN;
#pragma unroll
  for (int i = 0; i < 2; ++i)
#pragma unroll
    for (int j = 0; j < 2; ++j) {
      int n = n0 + wm * 32 + i * 16 + (l >> 4) * 4;
      int d = d0 + wn * 32 + j * 16 + lr;
      *(float4*)&ob[(size_t)d * NN + n] =
          make_float4(acc[i][j][0], acc[i][j][1], acc[i][j][2], acc[i][j][3]);
    }
}

extern "C" void kernel_launch(void* const* d_in, const int* in_sizes, int n_in, void* d_out, int out_size,
                              void* d_ws, size_t ws_size, hipStream_t stream) {
  (void)in_sizes;
  (void)n_in;
  (void)out_size;
  (void)ws_size;
  const float* x = (const float*)d_in[0];
  const float* m = (const float*)d_in[1];
  const float* hid = (const float*)d_in[2];
  const float* pri_e = (const float*)d_in[3];
  const float* inc = (const float*)d_in[5];
  const float* W = (const float*)d_in[6];
  const float* bias = (const float*)d_in[7];
  const float* W2 = (const float*)d_in[8];
  const float* a = (const float*)d_in[9];
  const float* a2 = (const float*)d_in[10];
  const float* a3 = (const float*)d_in[11];

  float* out0 = (float*)d_out;                // [B,D,N]
  float* out1 = out0 + (size_t)BB * DD * NN;  // [B,E,D] fp32 (written by k_out1s)
  _Float16* xt16 = (_Float16*)out1;           // [B,N,CIN] fp16 — dead after k_mid, before out1 written

  _Float16* out1T16 = (_Float16*)d_ws;                 // [B][16][256][64] panel-blocked
  _Float16* hThi = out1T16 + (size_t)BB * DD * EE;     // [B,D,N]
  _Float16* incT = hThi + (size_t)BB * DD * NN;        // [E,N]
  _Float16* w2shi = incT + (size_t)EE * NN;            // [E,E]
  _Float16* w2slo = w2shi + (size_t)EE * EE;           // [E,E]
  _Float16* inc16 = w2slo + (size_t)EE * EE;           // [N,E]
  _Float16* M16 = inc16 + (size_t)NN * EE;             // [E,N]
  _Float16* wt16 = M16 + (size_t)EE * NN;              // [D,CIN]
  _Float16* att16 = wt16 + (size_t)DD * CIN;           // [B][16][256][64] panel-blocked
  float* M32 = (float*)(att16 + (size_t)BB * NN * EE); // [E,N] fp32
  float* node_sc = M32 + (size_t)EE * NN;              // B*N
  float* g1 = node_sc + (size_t)BB * NN;               // B*N
  float* g2 = g1 + (size_t)BB * NN;                    // B*N
  float* wa = g2 + (size_t)BB * NN;                    // 1024

  k_prep<<<dim3(1376), 256, 0, stream>>>(inc, W2, W, x, m, hid, a, a2, incT, w2shi, w2slo, wt16, inc16, wa, xt16);
  k_mid<<<dim3(880), 256, 0, stream>>>(xt16, wt16, bias, hThi, inc16, w2shi, w2slo, M32, M16, x, m, hid, wa,
                                       node_sc, g1, g2);
  k_out1s<<<dim3(768 + 3072), 256, 0, stream>>>(M16, hThi, out1, out1T16, M32, g1, g2, node_sc, pri_e, a2, a3,
                                                incT, inc, att16);
  k_fgemm<<<dim3(8 * 96), 256, 0, stream>>>(att16, out1T16, out0);
}